// Round 1
// baseline (2182.462 us; speedup 1.0000x reference)
//
#include <hip/hip_runtime.h>
#include <math.h>

#define LATN 512
#define DN 256
#define DKN 128
#define TTOT 4096   // B*LAT
#define NEXP 10
#define DFFN 1024

// ---------------- reduction helpers (256-thread blocks) ----------------
__device__ __forceinline__ float block_reduce_sum(float v, float* red) {
    #pragma unroll
    for (int off = 32; off; off >>= 1) v += __shfl_down(v, off, 64);
    int lane = threadIdx.x & 63, wid = threadIdx.x >> 6;
    if (lane == 0) red[wid] = v;
    __syncthreads();
    float r = red[0] + red[1] + red[2] + red[3];
    __syncthreads();
    return r;
}

__device__ __forceinline__ float block_reduce_max(float v, float* red) {
    #pragma unroll
    for (int off = 32; off; off >>= 1) v = fmaxf(v, __shfl_down(v, off, 64));
    int lane = threadIdx.x & 63, wid = threadIdx.x >> 6;
    if (lane == 0) red[wid] = v;
    __syncthreads();
    float r = fmaxf(fmaxf(red[0], red[1]), fmaxf(red[2], red[3]));
    __syncthreads();
    return r;
}

// ---------------- zero init ----------------
__global__ void zero_kernel(float* counts, float* rprob, int* ec) {
    int i = threadIdx.x;
    if (i < 20) { counts[i] = 0.f; rprob[i] = 0.f; ec[i] = 0; }
}

// ---------------- tokenizer: conv5 + LPpool2 + PE + LN ----------------
__global__ void tokenizer_kernel(const float* __restrict__ x, const float* __restrict__ cw,
                                 const float* __restrict__ cb, const float* __restrict__ pe,
                                 const float* __restrict__ g, const float* __restrict__ bb,
                                 float* __restrict__ z) {
    int blk = blockIdx.x;
    int l = blk & (LATN - 1);
    int b = blk >> 9;
    int d = threadIdx.x;
    __shared__ float red[8];
    const float* xb = x + (size_t)b * 1024;
    float w0 = cw[d*5+0], w1 = cw[d*5+1], w2 = cw[d*5+2], w3 = cw[d*5+3], w4 = cw[d*5+4];
    float bv = cb[d];
    int p0 = 2 * l;
    auto xc = [&](int i) { return xb[min(max(i, 0), 1023)]; };
    float h0 = bv + w0*xc(p0-2) + w1*xc(p0-1) + w2*xc(p0)   + w3*xc(p0+1) + w4*xc(p0+2);
    float h1 = bv + w0*xc(p0-1) + w1*xc(p0)   + w2*xc(p0+1) + w3*xc(p0+2) + w4*xc(p0+3);
    float pool = sqrtf(h0*h0 + h1*h1);
    float val = pool + pe[l*DN + d];
    float s = block_reduce_sum(val, red);
    float mu = s * (1.0f/DN);
    float dv = val - mu;
    float s2 = block_reduce_sum(dv*dv, red);
    float r = rsqrtf(s2 * (1.0f/DN) + 1e-5f);
    z[((size_t)b*LATN + l)*DN + d] = dv*r*g[d] + bb[d];
}

// ---------------- row-tiled GEMM: out[t,i] = sum_j A[t,j]*W[i,j] + bias[i] --------
__global__ void gemm_rw8(const float* __restrict__ A, const float* __restrict__ W,
                         const float* __restrict__ bias, float* __restrict__ out) {
    __shared__ float as[8][DN];
    int t0 = blockIdx.x * 8;
    int tid = threadIdx.x;
    #pragma unroll
    for (int m = 0; m < 8; ++m) as[m][tid] = A[(size_t)(t0+m)*DN + tid];
    __syncthreads();
    const float* wr = &W[(size_t)tid * DN];
    float acc[8] = {0,0,0,0,0,0,0,0};
    #pragma unroll 4
    for (int j = 0; j < DN; ++j) {
        float w = wr[j];
        #pragma unroll
        for (int m = 0; m < 8; ++m) acc[m] += as[m][j] * w;
    }
    float bv = bias[tid];
    #pragma unroll
    for (int m = 0; m < 8; ++m) out[(size_t)(t0+m)*DN + tid] = acc[m] + bv;
}

// ---------------- fused attention: scores + softmax + PV, 4 q-rows/block ----------
__global__ void attn_kernel(const float* __restrict__ q, const float* __restrict__ k,
                            const float* __restrict__ v, float* __restrict__ a) {
    int blk = blockIdx.x;
    int qt = blk & 127;          // 512/4 tiles
    int h  = (blk >> 7) & 1;
    int b  = blk >> 8;
    int tid = threadIdx.x;
    __shared__ float qs[4][DKN];
    __shared__ float ps[4][LATN];
    __shared__ float pv[2][4][DKN];
    __shared__ float red[8];
    int q0 = qt * 4;
    for (int i = tid; i < 4*DKN; i += 256) {
        int qi = i >> 7, d = i & 127;
        qs[qi][d] = q[((size_t)(b*LATN + q0 + qi))*DN + h*DKN + d];
    }
    __syncthreads();
    const float scale = 0.08838834764831844f;  // 1/sqrt(128)
    #pragma unroll
    for (int part = 0; part < 2; ++part) {
        int kk = part*256 + tid;
        const float* krow = &k[((size_t)(b*LATN + kk))*DN + h*DKN];
        float a0 = 0, a1 = 0, a2 = 0, a3 = 0;
        for (int d = 0; d < DKN; ++d) {
            float kv = krow[d];
            a0 += kv*qs[0][d]; a1 += kv*qs[1][d]; a2 += kv*qs[2][d]; a3 += kv*qs[3][d];
        }
        ps[0][kk] = a0*scale; ps[1][kk] = a1*scale; ps[2][kk] = a2*scale; ps[3][kk] = a3*scale;
    }
    __syncthreads();
    #pragma unroll
    for (int qi = 0; qi < 4; ++qi) {
        float m = fmaxf(ps[qi][tid], ps[qi][tid+256]);
        m = block_reduce_max(m, red);
        float e0 = expf(ps[qi][tid] - m), e1 = expf(ps[qi][tid+256] - m);
        float s = block_reduce_sum(e0 + e1, red);
        float inv = 1.0f / s;
        ps[qi][tid] = e0*inv; ps[qi][tid+256] = e1*inv;
    }
    __syncthreads();
    int d = tid & 127, part = tid >> 7;
    float a0 = 0, a1 = 0, a2 = 0, a3 = 0;
    for (int kk = part*256; kk < part*256 + 256; ++kk) {
        float vv = v[((size_t)(b*LATN + kk))*DN + h*DKN + d];
        a0 += ps[0][kk]*vv; a1 += ps[1][kk]*vv; a2 += ps[2][kk]*vv; a3 += ps[3][kk]*vv;
    }
    pv[part][0][d] = a0; pv[part][1][d] = a1; pv[part][2][d] = a2; pv[part][3][d] = a3;
    __syncthreads();
    if (part == 0) {
        #pragma unroll
        for (int qi = 0; qi < 4; ++qi)
            a[((size_t)(b*LATN + q0 + qi))*DN + h*DKN + d] = pv[0][qi][d] + pv[1][qi][d];
    }
}

// ---------------- residual + LN (in-place on z) ----------------
__global__ void ln_residual(float* __restrict__ z, const float* __restrict__ y,
                            const float* __restrict__ g, const float* __restrict__ b) {
    int t = blockIdx.x, tid = threadIdx.x;
    __shared__ float red[8];
    float val = z[(size_t)t*DN + tid] + y[(size_t)t*DN + tid];
    float s = block_reduce_sum(val, red);
    float mu = s * (1.0f/DN);
    float dv = val - mu;
    float s2 = block_reduce_sum(dv*dv, red);
    float r = rsqrtf(s2 * (1.0f/DN) + 1e-5f);
    z[(size_t)t*DN + tid] = dv*r*g[tid] + b[tid];
}

// ---------------- router: logits, softmax, argmax, counts/rprob, expert lists ----
__global__ void router_kernel(const float* __restrict__ z, const float* __restrict__ rw,
                              const float* __restrict__ rb, int* __restrict__ routes,
                              float* __restrict__ rmaxv, float* __restrict__ counts,
                              float* __restrict__ rprob, int* __restrict__ ec,
                              int* __restrict__ elist) {
    int t = blockIdx.x, tid = threadIdx.x;
    __shared__ float red[8];
    __shared__ float logits[16];
    float zv = z[(size_t)t*DN + tid];
    for (int e = 0; e < NEXP; ++e) {
        float p = zv * rw[e*DN + tid];
        float s = block_reduce_sum(p, red);
        if (tid == 0) logits[e] = s + rb[e];
    }
    __syncthreads();
    if (tid == 0) {
        float m = logits[0]; int am = 0;
        for (int e = 1; e < NEXP; ++e) if (logits[e] > m) { m = logits[e]; am = e; }
        float p[NEXP]; float s = 0;
        for (int e = 0; e < NEXP; ++e) { p[e] = expf(logits[e] - m); s += p[e]; }
        float inv = 1.0f / s;
        routes[t] = am;
        rmaxv[t] = p[am] * inv;
        atomicAdd(&counts[am], 1.0f);
        for (int e = 0; e < NEXP; ++e) atomicAdd(&rprob[e], p[e] * inv);
        int pos = atomicAdd(&ec[am], 1);
        elist[am*TTOT + pos] = t;
    }
}

// ---------------- grouped MoE FFN + residual LN (in-place on z) ----------------
#define TM 16
__global__ void moe_kernel(float* __restrict__ z, const int* __restrict__ elist,
                           const int* __restrict__ ec, const float* __restrict__ rmaxv,
                           const float* __restrict__ w1, const float* __restrict__ b1,
                           const float* __restrict__ w2, const float* __restrict__ b2,
                           const float* __restrict__ g, const float* __restrict__ bb) {
    int e = blockIdx.y;
    int tile = blockIdx.x;
    int cnt = ec[e];
    int base = tile * TM;
    if (base >= cnt) return;
    int n = min(TM, cnt - base);
    __shared__ float ts[TM][DN];
    __shared__ float h1c[TM][256];
    __shared__ int toks[TM];
    __shared__ float red[8];
    int tid = threadIdx.x;
    if (tid < TM) toks[tid] = (tid < n) ? elist[e*TTOT + base + tid] : 0;
    __syncthreads();
    for (int m = 0; m < TM; ++m)
        ts[m][tid] = (m < n) ? z[(size_t)toks[m]*DN + tid] : 0.0f;
    __syncthreads();
    const float* w1e = w1 + (size_t)e * DN * DFFN;
    const float* w2e = w2 + (size_t)e * DFFN * DN;
    float accy[TM];
    #pragma unroll
    for (int m = 0; m < TM; ++m) accy[m] = 0.f;
    for (int fc = 0; fc < 4; ++fc) {
        int f = fc*256 + tid;
        float acc[TM];
        #pragma unroll
        for (int m = 0; m < TM; ++m) acc[m] = 0.f;
        for (int d = 0; d < DN; ++d) {
            float w = w1e[(size_t)d*DFFN + f];
            #pragma unroll
            for (int m = 0; m < TM; ++m) acc[m] += ts[m][d] * w;
        }
        float bv = b1[f];
        __syncthreads();  // protect h1c from previous chunk's readers
        #pragma unroll
        for (int m = 0; m < TM; ++m) h1c[m][tid] = fmaxf(acc[m] + bv, 0.0f);
        __syncthreads();
        for (int ff = 0; ff < 256; ++ff) {
            float w = w2e[(size_t)(fc*256 + ff)*DN + tid];
            #pragma unroll
            for (int m = 0; m < TM; ++m) accy[m] += h1c[m][ff] * w;
        }
    }
    float bv = b2[tid];
    for (int m = 0; m < n; ++m) {
        int t = toks[m];
        float y = (accy[m] + bv) * rmaxv[t];
        float val = z[(size_t)t*DN + tid] + y;
        float s = block_reduce_sum(val, red);
        float mu = s * (1.0f/DN);
        float dv = val - mu;
        float s2 = block_reduce_sum(dv*dv, red);
        float r = rsqrtf(s2 * (1.0f/DN) + 1e-5f);
        z[(size_t)t*DN + tid] = dv*r*g[tid] + bb[tid];
    }
}

// ---------------- deconv weight repack: wt[t][din][dout] = w[din][dout][t] --------
__global__ void repack_deconv(const float* __restrict__ w, float* __restrict__ wt) {
    int idx = blockIdx.x*256 + threadIdx.x;   // 4*256*256 total
    int dout = idx & 255;
    int din = (idx >> 8) & 255;
    int t = idx >> 16;
    wt[idx] = w[((size_t)din*DN + dout)*4 + t];
}

// ---------------- deconv (ConvTranspose1d k=4 s=2 p=1) + bias -> u[b][w][dout] ----
__global__ void deconv_kernel(const float* __restrict__ z, const float* __restrict__ dwT,
                              const float* __restrict__ db, float* __restrict__ u) {
    int blk = blockIdx.x;
    int tile = blk & 63;       // 1024/16 tiles per b
    int b = blk >> 6;
    int tid = threadIdx.x;
    int w0 = tile * 16;
    int lbase = tile*8 - 1;
    __shared__ float zs[10][DN];
    for (int i = tid; i < 10*DN; i += 256) {
        int rr = i >> 8, dd = i & 255;
        int l = lbase + rr;
        zs[rr][dd] = (l >= 0 && l < LATN) ? z[((size_t)b*LATN + l)*DN + dd] : 0.0f;
    }
    __syncthreads();
    float acc[16];
    #pragma unroll
    for (int i = 0; i < 16; ++i) acc[i] = 0.f;
    // out[w] contributions: (l,t) with 2l + t - 1 = w.
    // t=0 -> w odd,  zs row j+2 ; t=1 -> w even, row j+1 ; t=2 -> w odd, row j+1 ; t=3 -> w even, row j
    #pragma unroll
    for (int t = 0; t < 4; ++t) {
        const int c = (t == 0) ? 2 : (t == 3) ? 0 : 1;
        const int wi0 = (t + 1) & 1;
        const float* wp = &dwT[t*65536 + tid];
        for (int din = 0; din < DN; ++din) {
            float wv = wp[din*DN];
            #pragma unroll
            for (int j = 0; j < 8; ++j) acc[wi0 + 2*j] += zs[j + c][din] * wv;
        }
    }
    float bv = db[tid];
    #pragma unroll
    for (int wi = 0; wi < 16; ++wi)
        u[((size_t)b*1024 + w0 + wi)*DN + tid] = acc[wi] + bv;
}

// ---------------- head: lin1 + tanh + lin2 ----------------
__global__ void head_kernel(const float* __restrict__ u, const float* __restrict__ w1,
                            const float* __restrict__ b1, const float* __restrict__ w2,
                            const float* __restrict__ b2, float* __restrict__ out) {
    __shared__ float us[8][DN];
    __shared__ float v1[8][128];
    int r0 = blockIdx.x * 8;
    int tid = threadIdx.x;   // 128 threads
    for (int i = tid; i < 8*DN; i += 128)
        us[i >> 8][i & 255] = u[(size_t)r0*DN + i];
    __syncthreads();
    const float* wr = &w1[tid*DN];
    float acc[8] = {0,0,0,0,0,0,0,0};
    #pragma unroll 4
    for (int d = 0; d < DN; ++d) {
        float w = wr[d];
        #pragma unroll
        for (int m = 0; m < 8; ++m) acc[m] += us[m][d] * w;
    }
    float bv = b1[tid];
    #pragma unroll
    for (int m = 0; m < 8; ++m) v1[m][tid] = tanhf(acc[m] + bv);
    __syncthreads();
    if (tid < 8) {
        float s = b2[0];
        for (int j = 0; j < 128; ++j) s += v1[tid][j] * w2[j];
        out[r0 + tid] = s;
    }
}

// ---------------- loss ----------------
__global__ void loss_kernel(const float* __restrict__ counts, const float* __restrict__ rprob,
                            float* __restrict__ out) {
    if (threadIdx.x == 0) {
        float s = 0;
        for (int i = 0; i < 20; ++i) s += counts[i] * rprob[i];
        out[8192] = 10.0f * s / (4096.0f * 4096.0f);
    }
}

extern "C" void kernel_launch(void* const* d_in, const int* in_sizes, int n_in,
                              void* d_out, int out_size, void* d_ws, size_t ws_size,
                              hipStream_t stream) {
    const float* x        = (const float*)d_in[0];
    const float* conv_w   = (const float*)d_in[1];
    const float* conv_b   = (const float*)d_in[2];
    const float* pe       = (const float*)d_in[3];
    const float* ln0_g    = (const float*)d_in[4];
    const float* ln0_b    = (const float*)d_in[5];
    const float* wq       = (const float*)d_in[6];
    const float* bq       = (const float*)d_in[7];
    const float* wk       = (const float*)d_in[8];
    const float* bk       = (const float*)d_in[9];
    const float* wv       = (const float*)d_in[10];
    const float* bv       = (const float*)d_in[11];
    const float* wo       = (const float*)d_in[12];
    const float* bo       = (const float*)d_in[13];
    const float* ln1_g    = (const float*)d_in[14];
    const float* ln1_b    = (const float*)d_in[15];
    const float* ln2_g    = (const float*)d_in[16];
    const float* ln2_b    = (const float*)d_in[17];
    const float* router_w = (const float*)d_in[18];
    const float* router_b = (const float*)d_in[19];
    const float* e_w1     = (const float*)d_in[20];
    const float* e_b1     = (const float*)d_in[21];
    const float* e_w2     = (const float*)d_in[22];
    const float* e_b2     = (const float*)d_in[23];
    const float* deconv_w = (const float*)d_in[24];
    const float* deconv_b = (const float*)d_in[25];
    const float* lin1_w   = (const float*)d_in[26];
    const float* lin1_b   = (const float*)d_in[27];
    const float* lin2_w   = (const float*)d_in[28];
    const float* lin2_b   = (const float*)d_in[29];

    float* ws = (float*)d_ws;
    const size_t M = 1048576;
    float* z    = ws;            // [4096,256]
    float* q    = ws + 1*M;
    float* k    = ws + 2*M;
    float* v    = ws + 3*M;
    float* a    = ws + 4*M;
    float* y    = ws + 5*M;
    float* rmax = ws + 6*M;      // 4096
    float* counts = rmax + 4096;  // 20
    float* rprob  = counts + 32;  // 20
    int* routes = (int*)(rprob + 32);         // 4096
    int* ec     = routes + 4096;              // 20
    int* elist  = ec + 32;                    // 2*10*4096
    float* u    = ws + 1*M;      // overlaps q,k (safe: used after attn layers)
    float* dwT  = ws + 3*M;      // overlaps v  (safe)
    float* out  = (float*)d_out;

    zero_kernel<<<1, 64, 0, stream>>>(counts, rprob, ec);
    tokenizer_kernel<<<TTOT, 256, 0, stream>>>(x, conv_w, conv_b, pe, ln0_g, ln0_b, z);

    for (int l = 0; l < 2; ++l) {
        gemm_rw8<<<TTOT/8, 256, 0, stream>>>(z, wq + l*65536, bq + l*256, q);
        gemm_rw8<<<TTOT/8, 256, 0, stream>>>(z, wk + l*65536, bk + l*256, k);
        gemm_rw8<<<TTOT/8, 256, 0, stream>>>(z, wv + l*65536, bv + l*256, v);
        attn_kernel<<<2048, 256, 0, stream>>>(q, k, v, a);
        gemm_rw8<<<TTOT/8, 256, 0, stream>>>(a, wo + l*65536, bo + l*256, y);
        ln_residual<<<TTOT, 256, 0, stream>>>(z, y, ln1_g + l*256, ln1_b + l*256);
        router_kernel<<<TTOT, 256, 0, stream>>>(z, router_w + l*2560, router_b + l*10,
                                                routes, rmax, counts + l*10, rprob + l*10,
                                                ec + l*10, elist + l*10*TTOT);
        dim3 mg(TTOT/TM, NEXP);
        moe_kernel<<<mg, 256, 0, stream>>>(z, elist + l*10*TTOT, ec + l*10, rmax,
                                           e_w1 + (size_t)l*2621440, e_b1 + l*10240,
                                           e_w2 + (size_t)l*2621440, e_b2 + l*2560,
                                           ln2_g + l*256, ln2_b + l*256);
    }

    repack_deconv<<<1024, 256, 0, stream>>>(deconv_w, dwT);
    deconv_kernel<<<512, 256, 0, stream>>>(z, dwT, deconv_b, u);
    head_kernel<<<1024, 128, 0, stream>>>(u, lin1_w, lin1_b, lin2_w, lin2_b, out);
    loss_kernel<<<1, 64, 0, stream>>>(counts, rprob, out);
}

// Round 2
// 1620.446 us; speedup vs baseline: 1.3468x; 1.3468x over previous
//
#include <hip/hip_runtime.h>
#include <math.h>

#define LATN 512
#define DN 256
#define DKN 128
#define TTOT 4096   // B*LAT
#define NEXP 10
#define DFFN 1024

__device__ __forceinline__ float dot4(float4 a, float4 b) {
    return a.x*b.x + a.y*b.y + a.z*b.z + a.w*b.w;
}

// ---------------- reduction helper (256-thread blocks) ----------------
__device__ __forceinline__ float block_reduce_sum(float v, float* red) {
    #pragma unroll
    for (int off = 32; off; off >>= 1) v += __shfl_down(v, off, 64);
    int lane = threadIdx.x & 63, wid = threadIdx.x >> 6;
    if (lane == 0) red[wid] = v;
    __syncthreads();
    float r = red[0] + red[1] + red[2] + red[3];
    __syncthreads();
    return r;
}

// ---------------- zero init ----------------
__global__ void zero_kernel(float* counts, float* rprob, int* ec) {
    int i = threadIdx.x;
    if (i < 20) { counts[i] = 0.f; rprob[i] = 0.f; ec[i] = 0; }
}

// ---------------- tokenizer: conv5 + LPpool2 + PE + LN ----------------
__global__ void tokenizer_kernel(const float* __restrict__ x, const float* __restrict__ cw,
                                 const float* __restrict__ cb, const float* __restrict__ pe,
                                 const float* __restrict__ g, const float* __restrict__ bb,
                                 float* __restrict__ z) {
    int blk = blockIdx.x;
    int l = blk & (LATN - 1);
    int b = blk >> 9;
    int d = threadIdx.x;
    __shared__ float red[8];
    const float* xb = x + (size_t)b * 1024;
    float w0 = cw[d*5+0], w1 = cw[d*5+1], w2 = cw[d*5+2], w3 = cw[d*5+3], w4 = cw[d*5+4];
    float bv = cb[d];
    int p0 = 2 * l;
    auto xc = [&](int i) { return xb[min(max(i, 0), 1023)]; };
    float h0 = bv + w0*xc(p0-2) + w1*xc(p0-1) + w2*xc(p0)   + w3*xc(p0+1) + w4*xc(p0+2);
    float h1 = bv + w0*xc(p0-1) + w1*xc(p0)   + w2*xc(p0+1) + w3*xc(p0+2) + w4*xc(p0+3);
    float pool = sqrtf(h0*h0 + h1*h1);
    float val = pool + pe[l*DN + d];
    float s = block_reduce_sum(val, red);
    float mu = s * (1.0f/DN);
    float dv = val - mu;
    float s2 = block_reduce_sum(dv*dv, red);
    float r = rsqrtf(s2 * (1.0f/DN) + 1e-5f);
    z[((size_t)b*LATN + l)*DN + d] = dv*r*g[d] + bb[d];
}

// ---------------- GEMM core: 16 tokens/block, thread owns 2 cols x 8 tokens -------
__device__ __forceinline__ void gemm16_body(const float* __restrict__ A,
                                            const float* __restrict__ W,
                                            const float* __restrict__ bias,
                                            float* __restrict__ out, int t0,
                                            float as[16][DN]) {
    int tid = threadIdx.x;
    #pragma unroll
    for (int m = 0; m < 16; ++m) as[m][tid] = A[(size_t)(t0+m)*DN + tid];
    __syncthreads();
    int c = tid & 127, hh = tid >> 7;
    int m0 = hh * 8;
    const float4* wa = (const float4*)&W[(size_t)c * DN];
    const float4* wb = (const float4*)&W[(size_t)(c+128) * DN];
    float acc0[8] = {0,0,0,0,0,0,0,0};
    float acc1[8] = {0,0,0,0,0,0,0,0};
    for (int j4 = 0; j4 < 64; ++j4) {
        float4 w0 = wa[j4];
        float4 w1 = wb[j4];
        #pragma unroll
        for (int m = 0; m < 8; ++m) {
            float4 a = *(const float4*)&as[m0+m][j4*4];
            acc0[m] += dot4(a, w0);
            acc1[m] += dot4(a, w1);
        }
    }
    float b0 = bias[c], b1 = bias[c+128];
    #pragma unroll
    for (int m = 0; m < 8; ++m) {
        out[(size_t)(t0+m0+m)*DN + c]       = acc0[m] + b0;
        out[(size_t)(t0+m0+m)*DN + c + 128] = acc1[m] + b1;
    }
}

__global__ void gemm_qkv(const float* __restrict__ z,
                         const float* __restrict__ wq, const float* __restrict__ bq,
                         const float* __restrict__ wk, const float* __restrict__ bk,
                         const float* __restrict__ wv, const float* __restrict__ bv,
                         float* __restrict__ q, float* __restrict__ k, float* __restrict__ v) {
    __shared__ float as[16][DN];
    const float* W; const float* bias; float* out;
    if (blockIdx.y == 0)      { W = wq; bias = bq; out = q; }
    else if (blockIdx.y == 1) { W = wk; bias = bk; out = k; }
    else                      { W = wv; bias = bv; out = v; }
    gemm16_body(z, W, bias, out, blockIdx.x * 16, as);
}

__global__ void gemm16(const float* __restrict__ A, const float* __restrict__ W,
                       const float* __restrict__ bias, float* __restrict__ out) {
    __shared__ float as[16][DN];
    gemm16_body(A, W, bias, out, blockIdx.x * 16, as);
}

// ---------------- fused attention: 4 q-rows/block ----------------
__global__ void attn_kernel(const float* __restrict__ q, const float* __restrict__ k,
                            const float* __restrict__ v, float* __restrict__ a) {
    int blk = blockIdx.x;
    int qt = blk & 127;
    int h  = (blk >> 7) & 1;
    int b  = blk >> 8;
    int tid = threadIdx.x;
    __shared__ float qs[4][DKN];
    __shared__ float ps[4][LATN];
    __shared__ float pq[4][4][DKN];   // [quarter][qi][d]
    int q0 = qt * 4;
    for (int i = tid; i < 4*DKN; i += 256) {
        int qi = i >> 7, d = i & 127;
        qs[qi][d] = q[((size_t)(b*LATN + q0 + qi))*DN + h*DKN + d];
    }
    __syncthreads();
    const float scale = 0.08838834764831844f;  // 1/sqrt(128)
    #pragma unroll
    for (int part = 0; part < 2; ++part) {
        int kk = part*256 + tid;
        const float4* kr = (const float4*)&k[((size_t)(b*LATN + kk))*DN + h*DKN];
        float a0 = 0, a1 = 0, a2 = 0, a3 = 0;
        for (int d4 = 0; d4 < 32; ++d4) {
            float4 kv = kr[d4];
            a0 += dot4(kv, *(const float4*)&qs[0][d4*4]);
            a1 += dot4(kv, *(const float4*)&qs[1][d4*4]);
            a2 += dot4(kv, *(const float4*)&qs[2][d4*4]);
            a3 += dot4(kv, *(const float4*)&qs[3][d4*4]);
        }
        ps[0][kk] = a0*scale; ps[1][kk] = a1*scale; ps[2][kk] = a2*scale; ps[3][kk] = a3*scale;
    }
    __syncthreads();
    // softmax: wave w owns row w (no cross-wave sync needed)
    {
        int wv = tid >> 6, lane = tid & 63;
        float* row = ps[wv];
        float e[8]; float mx = -1e30f;
        #pragma unroll
        for (int r = 0; r < 8; ++r) { e[r] = row[lane + 64*r]; mx = fmaxf(mx, e[r]); }
        #pragma unroll
        for (int off = 32; off; off >>= 1) mx = fmaxf(mx, __shfl_xor(mx, off, 64));
        float s = 0;
        #pragma unroll
        for (int r = 0; r < 8; ++r) { e[r] = expf(e[r] - mx); s += e[r]; }
        #pragma unroll
        for (int off = 32; off; off >>= 1) s += __shfl_xor(s, off, 64);
        float inv = 1.0f / s;
        #pragma unroll
        for (int r = 0; r < 8; ++r) row[lane + 64*r] = e[r]*inv;
    }
    __syncthreads();
    // PV: thread owns 2 d's over a 128-k quarter
    int d2 = (tid & 63)*2, qtr = tid >> 6;
    float ax[4] = {0,0,0,0}, ay[4] = {0,0,0,0};
    for (int kk = qtr*128; kk < qtr*128 + 128; ++kk) {
        float2 vv = *(const float2*)&v[((size_t)(b*LATN + kk))*DN + h*DKN + d2];
        float p0 = ps[0][kk], p1 = ps[1][kk], p2 = ps[2][kk], p3 = ps[3][kk];
        ax[0] += p0*vv.x; ay[0] += p0*vv.y;
        ax[1] += p1*vv.x; ay[1] += p1*vv.y;
        ax[2] += p2*vv.x; ay[2] += p2*vv.y;
        ax[3] += p3*vv.x; ay[3] += p3*vv.y;
    }
    #pragma unroll
    for (int qi = 0; qi < 4; ++qi) {
        pq[qtr][qi][d2] = ax[qi]; pq[qtr][qi][d2+1] = ay[qi];
    }
    __syncthreads();
    for (int i = tid; i < 4*DKN; i += 256) {
        int qi = i >> 7, d = i & 127;
        float s = pq[0][qi][d] + pq[1][qi][d] + pq[2][qi][d] + pq[3][qi][d];
        a[((size_t)(b*LATN + q0 + qi))*DN + h*DKN + d] = s;
    }
}

// ---------------- residual + LN (in-place on z) ----------------
__global__ void ln_residual(float* __restrict__ z, const float* __restrict__ y,
                            const float* __restrict__ g, const float* __restrict__ b) {
    int t = blockIdx.x, tid = threadIdx.x;
    __shared__ float red[8];
    float val = z[(size_t)t*DN + tid] + y[(size_t)t*DN + tid];
    float s = block_reduce_sum(val, red);
    float mu = s * (1.0f/DN);
    float dv = val - mu;
    float s2 = block_reduce_sum(dv*dv, red);
    float r = rsqrtf(s2 * (1.0f/DN) + 1e-5f);
    z[(size_t)t*DN + tid] = dv*r*g[tid] + b[tid];
}

// ---------------- router v2: 64 tokens/block, 4 lanes/token ----------------
__global__ void router_kernel(const float* __restrict__ z, const float* __restrict__ rw,
                              const float* __restrict__ rb, float* __restrict__ rmaxv,
                              float* __restrict__ counts, float* __restrict__ rprob,
                              int* __restrict__ ec, int* __restrict__ elist) {
    __shared__ float rws[NEXP*DN];
    __shared__ float scnt[NEXP], sprob[NEXP];
    int tid = threadIdx.x;
    for (int i = tid; i < NEXP*DN; i += 256) rws[i] = rw[i];
    if (tid < NEXP) { scnt[tid] = 0.f; sprob[tid] = 0.f; }
    __syncthreads();
    int g = tid >> 2, j = tid & 3;
    int t = blockIdx.x * 64 + g;
    const float4* z4 = (const float4*)&z[(size_t)t*DN + j*64];
    float acc[NEXP];
    #pragma unroll
    for (int e = 0; e < NEXP; ++e) acc[e] = 0.f;
    #pragma unroll 4
    for (int k4 = 0; k4 < 16; ++k4) {
        float4 zv = z4[k4];
        #pragma unroll
        for (int e = 0; e < NEXP; ++e)
            acc[e] += dot4(zv, *(const float4*)&rws[e*DN + j*64 + k4*4]);
    }
    #pragma unroll
    for (int e = 0; e < NEXP; ++e) {
        acc[e] += __shfl_xor(acc[e], 1, 64);
        acc[e] += __shfl_xor(acc[e], 2, 64);
    }
    if (j == 0) {
        float lg[NEXP];
        float m = acc[0] + rb[0]; int am = 0;
        lg[0] = m;
        #pragma unroll
        for (int e = 1; e < NEXP; ++e) {
            lg[e] = acc[e] + rb[e];
            if (lg[e] > m) { m = lg[e]; am = e; }
        }
        float p[NEXP], s = 0.f;
        #pragma unroll
        for (int e = 0; e < NEXP; ++e) { p[e] = expf(lg[e] - m); s += p[e]; }
        float inv = 1.0f / s;
        rmaxv[t] = p[am] * inv;
        atomicAdd(&scnt[am], 1.0f);
        #pragma unroll
        for (int e = 0; e < NEXP; ++e) atomicAdd(&sprob[e], p[e] * inv);
        int pos = atomicAdd(&ec[am], 1);
        elist[am*TTOT + pos] = t;
    }
    __syncthreads();
    if (tid < NEXP) {
        atomicAdd(&counts[tid], scnt[tid]);
        atomicAdd(&rprob[tid], sprob[tid]);
    }
}

// ---------------- grouped MoE FFN + residual LN (in-place on z) ----------------
#define TM 16
__global__ void moe_kernel(float* __restrict__ z, const int* __restrict__ elist,
                           const int* __restrict__ ec, const float* __restrict__ rmaxv,
                           const float* __restrict__ w1, const float* __restrict__ b1,
                           const float* __restrict__ w2, const float* __restrict__ b2,
                           const float* __restrict__ g, const float* __restrict__ bb) {
    int e = blockIdx.y;
    int tile = blockIdx.x;
    int cnt = ec[e];
    int base = tile * TM;
    if (base >= cnt) return;
    int n = min(TM, cnt - base);
    __shared__ float ts[TM][DN];
    __shared__ float h1c[TM][256];
    __shared__ int toks[TM];
    __shared__ float red[8];
    int tid = threadIdx.x;
    if (tid < TM) toks[tid] = (tid < n) ? elist[e*TTOT + base + tid] : 0;
    __syncthreads();
    for (int m = 0; m < TM; ++m)
        ts[m][tid] = (m < n) ? z[(size_t)toks[m]*DN + tid] : 0.0f;
    __syncthreads();
    const float* w1e = w1 + (size_t)e * DN * DFFN;
    const float* w2e = w2 + (size_t)e * DFFN * DN;
    float accy[TM];
    #pragma unroll
    for (int m = 0; m < TM; ++m) accy[m] = 0.f;
    for (int fc = 0; fc < 4; ++fc) {
        int f = fc*256 + tid;
        float acc[TM];
        #pragma unroll
        for (int m = 0; m < TM; ++m) acc[m] = 0.f;
        for (int d4 = 0; d4 < 64; ++d4) {
            float wv0 = w1e[(size_t)(d4*4+0)*DFFN + f];
            float wv1 = w1e[(size_t)(d4*4+1)*DFFN + f];
            float wv2 = w1e[(size_t)(d4*4+2)*DFFN + f];
            float wv3 = w1e[(size_t)(d4*4+3)*DFFN + f];
            #pragma unroll
            for (int m = 0; m < TM; ++m) {
                float4 a = *(const float4*)&ts[m][d4*4];
                acc[m] += a.x*wv0 + a.y*wv1 + a.z*wv2 + a.w*wv3;
            }
        }
        float bv = b1[f];
        __syncthreads();
        #pragma unroll
        for (int m = 0; m < TM; ++m) h1c[m][tid] = fmaxf(acc[m] + bv, 0.0f);
        __syncthreads();
        for (int ff4 = 0; ff4 < 64; ++ff4) {
            float wv0 = w2e[(size_t)(fc*256 + ff4*4+0)*DN + tid];
            float wv1 = w2e[(size_t)(fc*256 + ff4*4+1)*DN + tid];
            float wv2 = w2e[(size_t)(fc*256 + ff4*4+2)*DN + tid];
            float wv3 = w2e[(size_t)(fc*256 + ff4*4+3)*DN + tid];
            #pragma unroll
            for (int m = 0; m < TM; ++m) {
                float4 hh = *(const float4*)&h1c[m][ff4*4];
                accy[m] += hh.x*wv0 + hh.y*wv1 + hh.z*wv2 + hh.w*wv3;
            }
        }
    }
    float bv = b2[tid];
    for (int m = 0; m < n; ++m) {
        int t = toks[m];
        float y = (accy[m] + bv) * rmaxv[t];
        float val = z[(size_t)t*DN + tid] + y;
        float s = block_reduce_sum(val, red);
        float mu = s * (1.0f/DN);
        float dv = val - mu;
        float s2 = block_reduce_sum(dv*dv, red);
        float r = rsqrtf(s2 * (1.0f/DN) + 1e-5f);
        z[(size_t)t*DN + tid] = dv*r*g[tid] + bb[tid];
    }
}

// ---------------- deconv weight repack: wt[t][din][dout] = w[din][dout][t] --------
__global__ void repack_deconv(const float* __restrict__ w, float* __restrict__ wt) {
    int idx = blockIdx.x*256 + threadIdx.x;
    int dout = idx & 255;
    int din = (idx >> 8) & 255;
    int t = idx >> 16;
    wt[idx] = w[((size_t)din*DN + dout)*4 + t];
}

// ---------------- deconv (ConvTranspose1d k=4 s=2 p=1) + bias -> u[b][w][dout] ----
__global__ void deconv_kernel(const float* __restrict__ z, const float* __restrict__ dwT,
                              const float* __restrict__ db, float* __restrict__ u) {
    int blk = blockIdx.x;
    int tile = blk & 63;
    int b = blk >> 6;
    int tid = threadIdx.x;
    int w0 = tile * 16;
    int lbase = tile*8 - 1;
    __shared__ float zst[DN][12];   // transposed, padded to 12 (16B-aligned rows)
    for (int i = tid; i < 10*DN; i += 256) {
        int rr = i >> 8, dd = i & 255;
        int l = lbase + rr;
        zst[dd][rr] = (l >= 0 && l < LATN) ? z[((size_t)b*LATN + l)*DN + dd] : 0.0f;
    }
    if (tid < DN) { zst[tid][10] = 0.f; zst[tid][11] = 0.f; }
    __syncthreads();
    float acc[16];
    #pragma unroll
    for (int i = 0; i < 16; ++i) acc[i] = 0.f;
    const float* wp0 = &dwT[0*65536 + tid];
    const float* wp1 = &dwT[1*65536 + tid];
    const float* wp2 = &dwT[2*65536 + tid];
    const float* wp3 = &dwT[3*65536 + tid];
    for (int din = 0; din < DN; ++din) {
        float4 A  = *(const float4*)&zst[din][0];
        float4 Bq = *(const float4*)&zst[din][4];
        float4 Cq = *(const float4*)&zst[din][8];
        float r0 = A.x, r1 = A.y, r2 = A.z, r3 = A.w;
        float r4 = Bq.x, r5 = Bq.y, r6 = Bq.z, r7 = Bq.w;
        float r8 = Cq.x, r9 = Cq.y;
        float rr[10] = {r0,r1,r2,r3,r4,r5,r6,r7,r8,r9};
        float wv0 = wp0[din*DN];   // tap0: rows j+2 -> acc[1+2j]
        float wv1 = wp1[din*DN];   // tap1: rows j+1 -> acc[2j]
        float wv2 = wp2[din*DN];   // tap2: rows j+1 -> acc[1+2j]
        float wv3 = wp3[din*DN];   // tap3: rows j   -> acc[2j]
        #pragma unroll
        for (int jj = 0; jj < 8; ++jj) {
            acc[1+2*jj] += rr[jj+2]*wv0 + rr[jj+1]*wv2;
            acc[2*jj]   += rr[jj+1]*wv1 + rr[jj]*wv3;
        }
    }
    float bv = db[tid];
    #pragma unroll
    for (int wi = 0; wi < 16; ++wi)
        u[((size_t)b*1024 + w0 + wi)*DN + tid] = acc[wi] + bv;
}

// ---------------- head: lin1 + tanh + lin2 ----------------
__global__ void head_kernel(const float* __restrict__ u, const float* __restrict__ w1,
                            const float* __restrict__ b1, const float* __restrict__ w2,
                            const float* __restrict__ b2, float* __restrict__ out) {
    __shared__ float us[8][DN];
    __shared__ float v1[8][128];
    int r0 = blockIdx.x * 8;
    int tid = threadIdx.x;   // 128 threads
    for (int i = tid; i < 8*DN; i += 128)
        us[i >> 8][i & 255] = u[(size_t)r0*DN + i];
    __syncthreads();
    const float4* wr = (const float4*)&w1[tid*DN];
    float acc[8] = {0,0,0,0,0,0,0,0};
    for (int d4 = 0; d4 < 64; ++d4) {
        float4 w = wr[d4];
        #pragma unroll
        for (int m = 0; m < 8; ++m)
            acc[m] += dot4(w, *(const float4*)&us[m][d4*4]);
    }
    float bv = b1[tid];
    #pragma unroll
    for (int m = 0; m < 8; ++m) v1[m][tid] = tanhf(acc[m] + bv);
    __syncthreads();
    if (tid < 8) {
        float s = b2[0];
        for (int j = 0; j < 128; ++j) s += v1[tid][j] * w2[j];
        out[r0 + tid] = s;
    }
}

// ---------------- loss ----------------
__global__ void loss_kernel(const float* __restrict__ counts, const float* __restrict__ rprob,
                            float* __restrict__ out) {
    if (threadIdx.x == 0) {
        float s = 0;
        for (int i = 0; i < 20; ++i) s += counts[i] * rprob[i];
        out[8192] = 10.0f * s / (4096.0f * 4096.0f);
    }
}

extern "C" void kernel_launch(void* const* d_in, const int* in_sizes, int n_in,
                              void* d_out, int out_size, void* d_ws, size_t ws_size,
                              hipStream_t stream) {
    const float* x        = (const float*)d_in[0];
    const float* conv_w   = (const float*)d_in[1];
    const float* conv_b   = (const float*)d_in[2];
    const float* pe       = (const float*)d_in[3];
    const float* ln0_g    = (const float*)d_in[4];
    const float* ln0_b    = (const float*)d_in[5];
    const float* wq       = (const float*)d_in[6];
    const float* bq       = (const float*)d_in[7];
    const float* wk       = (const float*)d_in[8];
    const float* bk       = (const float*)d_in[9];
    const float* wv       = (const float*)d_in[10];
    const float* bv       = (const float*)d_in[11];
    const float* wo       = (const float*)d_in[12];
    const float* bo       = (const float*)d_in[13];
    const float* ln1_g    = (const float*)d_in[14];
    const float* ln1_b    = (const float*)d_in[15];
    const float* ln2_g    = (const float*)d_in[16];
    const float* ln2_b    = (const float*)d_in[17];
    const float* router_w = (const float*)d_in[18];
    const float* router_b = (const float*)d_in[19];
    const float* e_w1     = (const float*)d_in[20];
    const float* e_b1     = (const float*)d_in[21];
    const float* e_w2     = (const float*)d_in[22];
    const float* e_b2     = (const float*)d_in[23];
    const float* deconv_w = (const float*)d_in[24];
    const float* deconv_b = (const float*)d_in[25];
    const float* lin1_w   = (const float*)d_in[26];
    const float* lin1_b   = (const float*)d_in[27];
    const float* lin2_w   = (const float*)d_in[28];
    const float* lin2_b   = (const float*)d_in[29];

    float* ws = (float*)d_ws;
    const size_t M = 1048576;
    float* z    = ws;
    float* q    = ws + 1*M;
    float* k    = ws + 2*M;
    float* v    = ws + 3*M;
    float* a    = ws + 4*M;
    float* y    = ws + 5*M;
    float* rmax = ws + 6*M;
    float* counts = rmax + 4096;
    float* rprob  = counts + 32;
    int* ec     = (int*)(rprob + 32);
    int* elist  = ec + 32;                    // 2*10*4096
    float* u    = ws + 1*M;      // overlaps q,k (safe after attn)
    float* dwT  = ws + 3*M;      // overlaps v (safe)
    float* out  = (float*)d_out;

    zero_kernel<<<1, 64, 0, stream>>>(counts, rprob, ec);
    tokenizer_kernel<<<TTOT, 256, 0, stream>>>(x, conv_w, conv_b, pe, ln0_g, ln0_b, z);

    for (int l = 0; l < 2; ++l) {
        dim3 qkvg(TTOT/16, 3);
        gemm_qkv<<<qkvg, 256, 0, stream>>>(z, wq + l*65536, bq + l*256,
                                           wk + l*65536, bk + l*256,
                                           wv + l*65536, bv + l*256, q, k, v);
        attn_kernel<<<2048, 256, 0, stream>>>(q, k, v, a);
        gemm16<<<TTOT/16, 256, 0, stream>>>(a, wo + l*65536, bo + l*256, y);
        ln_residual<<<TTOT, 256, 0, stream>>>(z, y, ln1_g + l*256, ln1_b + l*256);
        router_kernel<<<TTOT/64, 256, 0, stream>>>(z, router_w + l*2560, router_b + l*10,
                                                   rmax, counts + l*10, rprob + l*10,
                                                   ec + l*10, elist + l*10*TTOT);
        dim3 mg(TTOT/TM, NEXP);
        moe_kernel<<<mg, 256, 0, stream>>>(z, elist + l*10*TTOT, ec + l*10, rmax,
                                           e_w1 + (size_t)l*2621440, e_b1 + l*10240,
                                           e_w2 + (size_t)l*2621440, e_b2 + l*2560,
                                           ln2_g + l*256, ln2_b + l*256);
    }

    repack_deconv<<<1024, 256, 0, stream>>>(deconv_w, dwT);
    deconv_kernel<<<512, 256, 0, stream>>>(z, dwT, deconv_b, u);
    head_kernel<<<1024, 128, 0, stream>>>(u, lin1_w, lin1_b, lin2_w, lin2_b, out);
    loss_kernel<<<1, 64, 0, stream>>>(counts, rprob, out);
}

// Round 3
// 935.089 us; speedup vs baseline: 2.3340x; 1.7329x over previous
//
#include <hip/hip_runtime.h>
#include <math.h>

#define LATN 512
#define DN 256
#define DKN 128
#define TTOT 4096   // B*LAT
#define NEXP 10
#define DFFN 1024

using bf16x8 = __attribute__((ext_vector_type(8))) short;
using f32x4  = __attribute__((ext_vector_type(4))) float;

__device__ __forceinline__ float dot4(float4 a, float4 b) {
    return a.x*b.x + a.y*b.y + a.z*b.z + a.w*b.w;
}

__device__ __forceinline__ unsigned short f2bf(float f) {
    union { float f; unsigned int u; } v; v.f = f;
    unsigned int u = v.u + 0x7FFFu + ((v.u >> 16) & 1u);
    return (unsigned short)(u >> 16);
}

// ---------------- reduction helper (256-thread blocks) ----------------
__device__ __forceinline__ float block_reduce_sum(float v, float* red) {
    #pragma unroll
    for (int off = 32; off; off >>= 1) v += __shfl_down(v, off, 64);
    int lane = threadIdx.x & 63, wid = threadIdx.x >> 6;
    if (lane == 0) red[wid] = v;
    __syncthreads();
    float r = red[0] + red[1] + red[2] + red[3];
    __syncthreads();
    return r;
}

__device__ __forceinline__ float wave_sum(float x) {
    #pragma unroll
    for (int off = 32; off; off >>= 1) x += __shfl_xor(x, off, 64);
    return x;
}

// ---------------- zero init ----------------
__global__ void zero_kernel(float* counts, float* rprob, int* ec) {
    int i = threadIdx.x;
    if (i < 20) { counts[i] = 0.f; rprob[i] = 0.f; ec[i] = 0; }
}

// ---------------- tokenizer: conv5 + LPpool2 + PE + LN ----------------
__global__ void tokenizer_kernel(const float* __restrict__ x, const float* __restrict__ cw,
                                 const float* __restrict__ cb, const float* __restrict__ pe,
                                 const float* __restrict__ g, const float* __restrict__ bb,
                                 float* __restrict__ z) {
    int blk = blockIdx.x;
    int l = blk & (LATN - 1);
    int b = blk >> 9;
    int d = threadIdx.x;
    __shared__ float red[8];
    const float* xb = x + (size_t)b * 1024;
    float w0 = cw[d*5+0], w1 = cw[d*5+1], w2 = cw[d*5+2], w3 = cw[d*5+3], w4 = cw[d*5+4];
    float bv = cb[d];
    int p0 = 2 * l;
    auto xc = [&](int i) { return xb[min(max(i, 0), 1023)]; };
    float h0 = bv + w0*xc(p0-2) + w1*xc(p0-1) + w2*xc(p0)   + w3*xc(p0+1) + w4*xc(p0+2);
    float h1 = bv + w0*xc(p0-1) + w1*xc(p0)   + w2*xc(p0+1) + w3*xc(p0+2) + w4*xc(p0+3);
    float pool = sqrtf(h0*h0 + h1*h1);
    float val = pool + pe[l*DN + d];
    float s = block_reduce_sum(val, red);
    float mu = s * (1.0f/DN);
    float dv = val - mu;
    float s2 = block_reduce_sum(dv*dv, red);
    float r = rsqrtf(s2 * (1.0f/DN) + 1e-5f);
    z[((size_t)b*LATN + l)*DN + d] = dv*r*g[d] + bb[d];
}

// ---------------- GEMM core: 16 tokens/block, thread owns 2 cols x 8 tokens -------
__device__ __forceinline__ void gemm16_body(const float* __restrict__ A,
                                            const float* __restrict__ W,
                                            const float* __restrict__ bias,
                                            float* __restrict__ out, int t0,
                                            float as[16][DN]) {
    int tid = threadIdx.x;
    #pragma unroll
    for (int m = 0; m < 16; ++m) as[m][tid] = A[(size_t)(t0+m)*DN + tid];
    __syncthreads();
    int c = tid & 127, hh = tid >> 7;
    int m0 = hh * 8;
    const float4* wa = (const float4*)&W[(size_t)c * DN];
    const float4* wb = (const float4*)&W[(size_t)(c+128) * DN];
    float acc0[8] = {0,0,0,0,0,0,0,0};
    float acc1[8] = {0,0,0,0,0,0,0,0};
    for (int j4 = 0; j4 < 64; ++j4) {
        float4 w0 = wa[j4];
        float4 w1 = wb[j4];
        #pragma unroll
        for (int m = 0; m < 8; ++m) {
            float4 a = *(const float4*)&as[m0+m][j4*4];
            acc0[m] += dot4(a, w0);
            acc1[m] += dot4(a, w1);
        }
    }
    float b0 = bias[c], b1 = bias[c+128];
    #pragma unroll
    for (int m = 0; m < 8; ++m) {
        out[(size_t)(t0+m0+m)*DN + c]       = acc0[m] + b0;
        out[(size_t)(t0+m0+m)*DN + c + 128] = acc1[m] + b1;
    }
}

__global__ void gemm_qkv(const float* __restrict__ z,
                         const float* __restrict__ wq, const float* __restrict__ bq,
                         const float* __restrict__ wk, const float* __restrict__ bk,
                         const float* __restrict__ wv, const float* __restrict__ bv,
                         float* __restrict__ q, float* __restrict__ k, float* __restrict__ v) {
    __shared__ float as[16][DN];
    const float* W; const float* bias; float* out;
    if (blockIdx.y == 0)      { W = wq; bias = bq; out = q; }
    else if (blockIdx.y == 1) { W = wk; bias = bk; out = k; }
    else                      { W = wv; bias = bv; out = v; }
    gemm16_body(z, W, bias, out, blockIdx.x * 16, as);
}

__global__ void gemm16(const float* __restrict__ A, const float* __restrict__ W,
                       const float* __restrict__ bias, float* __restrict__ out) {
    __shared__ float as[16][DN];
    gemm16_body(A, W, bias, out, blockIdx.x * 16, as);
}

// ---------------- fused attention: 4 q-rows/block ----------------
__global__ void attn_kernel(const float* __restrict__ q, const float* __restrict__ k,
                            const float* __restrict__ v, float* __restrict__ a) {
    int blk = blockIdx.x;
    int qt = blk & 127;
    int h  = (blk >> 7) & 1;
    int b  = blk >> 8;
    int tid = threadIdx.x;
    __shared__ float qs[4][DKN];
    __shared__ float ps[4][LATN];
    __shared__ float pq[4][4][DKN];
    int q0 = qt * 4;
    for (int i = tid; i < 4*DKN; i += 256) {
        int qi = i >> 7, d = i & 127;
        qs[qi][d] = q[((size_t)(b*LATN + q0 + qi))*DN + h*DKN + d];
    }
    __syncthreads();
    const float scale = 0.08838834764831844f;  // 1/sqrt(128)
    #pragma unroll
    for (int part = 0; part < 2; ++part) {
        int kk = part*256 + tid;
        const float4* kr = (const float4*)&k[((size_t)(b*LATN + kk))*DN + h*DKN];
        float a0 = 0, a1 = 0, a2 = 0, a3 = 0;
        for (int d4 = 0; d4 < 32; ++d4) {
            float4 kv = kr[d4];
            a0 += dot4(kv, *(const float4*)&qs[0][d4*4]);
            a1 += dot4(kv, *(const float4*)&qs[1][d4*4]);
            a2 += dot4(kv, *(const float4*)&qs[2][d4*4]);
            a3 += dot4(kv, *(const float4*)&qs[3][d4*4]);
        }
        ps[0][kk] = a0*scale; ps[1][kk] = a1*scale; ps[2][kk] = a2*scale; ps[3][kk] = a3*scale;
    }
    __syncthreads();
    {
        int wv = tid >> 6, lane = tid & 63;
        float* row = ps[wv];
        float e[8]; float mx = -1e30f;
        #pragma unroll
        for (int r = 0; r < 8; ++r) { e[r] = row[lane + 64*r]; mx = fmaxf(mx, e[r]); }
        #pragma unroll
        for (int off = 32; off; off >>= 1) mx = fmaxf(mx, __shfl_xor(mx, off, 64));
        float s = 0;
        #pragma unroll
        for (int r = 0; r < 8; ++r) { e[r] = expf(e[r] - mx); s += e[r]; }
        #pragma unroll
        for (int off = 32; off; off >>= 1) s += __shfl_xor(s, off, 64);
        float inv = 1.0f / s;
        #pragma unroll
        for (int r = 0; r < 8; ++r) row[lane + 64*r] = e[r]*inv;
    }
    __syncthreads();
    int d2 = (tid & 63)*2, qtr = tid >> 6;
    float ax[4] = {0,0,0,0}, ay[4] = {0,0,0,0};
    for (int kk = qtr*128; kk < qtr*128 + 128; ++kk) {
        float2 vv = *(const float2*)&v[((size_t)(b*LATN + kk))*DN + h*DKN + d2];
        float p0 = ps[0][kk], p1 = ps[1][kk], p2 = ps[2][kk], p3 = ps[3][kk];
        ax[0] += p0*vv.x; ay[0] += p0*vv.y;
        ax[1] += p1*vv.x; ay[1] += p1*vv.y;
        ax[2] += p2*vv.x; ay[2] += p2*vv.y;
        ax[3] += p3*vv.x; ay[3] += p3*vv.y;
    }
    #pragma unroll
    for (int qi = 0; qi < 4; ++qi) {
        pq[qtr][qi][d2] = ax[qi]; pq[qtr][qi][d2+1] = ay[qi];
    }
    __syncthreads();
    for (int i = tid; i < 4*DKN; i += 256) {
        int qi = i >> 7, d = i & 127;
        float s = pq[0][qi][d] + pq[1][qi][d] + pq[2][qi][d] + pq[3][qi][d];
        a[((size_t)(b*LATN + q0 + qi))*DN + h*DKN + d] = s;
    }
}

// ---------------- residual + LN (in-place on z) ----------------
__global__ void ln_residual(float* __restrict__ z, const float* __restrict__ y,
                            const float* __restrict__ g, const float* __restrict__ b) {
    int t = blockIdx.x, tid = threadIdx.x;
    __shared__ float red[8];
    float val = z[(size_t)t*DN + tid] + y[(size_t)t*DN + tid];
    float s = block_reduce_sum(val, red);
    float mu = s * (1.0f/DN);
    float dv = val - mu;
    float s2 = block_reduce_sum(dv*dv, red);
    float r = rsqrtf(s2 * (1.0f/DN) + 1e-5f);
    z[(size_t)t*DN + tid] = dv*r*g[tid] + b[tid];
}

// ---------------- router: 64 tokens/block, 4 lanes/token ----------------
__global__ void router_kernel(const float* __restrict__ z, const float* __restrict__ rw,
                              const float* __restrict__ rb, float* __restrict__ rmaxv,
                              float* __restrict__ counts, float* __restrict__ rprob,
                              int* __restrict__ ec, int* __restrict__ elist) {
    __shared__ float rws[NEXP*DN];
    __shared__ float scnt[NEXP], sprob[NEXP];
    int tid = threadIdx.x;
    for (int i = tid; i < NEXP*DN; i += 256) rws[i] = rw[i];
    if (tid < NEXP) { scnt[tid] = 0.f; sprob[tid] = 0.f; }
    __syncthreads();
    int g = tid >> 2, j = tid & 3;
    int t = blockIdx.x * 64 + g;
    const float4* z4 = (const float4*)&z[(size_t)t*DN + j*64];
    float acc[NEXP];
    #pragma unroll
    for (int e = 0; e < NEXP; ++e) acc[e] = 0.f;
    #pragma unroll 4
    for (int k4 = 0; k4 < 16; ++k4) {
        float4 zv = z4[k4];
        #pragma unroll
        for (int e = 0; e < NEXP; ++e)
            acc[e] += dot4(zv, *(const float4*)&rws[e*DN + j*64 + k4*4]);
    }
    #pragma unroll
    for (int e = 0; e < NEXP; ++e) {
        acc[e] += __shfl_xor(acc[e], 1, 64);
        acc[e] += __shfl_xor(acc[e], 2, 64);
    }
    if (j == 0) {
        float lg[NEXP];
        float m = acc[0] + rb[0]; int am = 0;
        lg[0] = m;
        #pragma unroll
        for (int e = 1; e < NEXP; ++e) {
            lg[e] = acc[e] + rb[e];
            if (lg[e] > m) { m = lg[e]; am = e; }
        }
        float p[NEXP], s = 0.f;
        #pragma unroll
        for (int e = 0; e < NEXP; ++e) { p[e] = expf(lg[e] - m); s += p[e]; }
        float inv = 1.0f / s;
        rmaxv[t] = p[am] * inv;
        atomicAdd(&scnt[am], 1.0f);
        #pragma unroll
        for (int e = 0; e < NEXP; ++e) atomicAdd(&sprob[e], p[e] * inv);
        int pos = atomicAdd(&ec[am], 1);
        elist[am*TTOT + pos] = t;
    }
    __syncthreads();
    if (tid < NEXP) {
        atomicAdd(&counts[tid], scnt[tid]);
        atomicAdd(&rprob[tid], sprob[tid]);
    }
}

// ---------------- weight pack kernels: fp32 -> bf16 MFMA-B-fragment order --------
// w1p[e][nt(64)][kk(8)][lane(64)][j(8)] = w1[e][kk*32+(lane>>4)*8+j][nt*16+(lane&15)]
__global__ void pack_w1(const float* __restrict__ w1l, unsigned short* __restrict__ w1p) {
    int tid = blockIdx.x*256 + threadIdx.x;   // 327680 total
    int l = tid & 63, kk = (tid >> 6) & 7, nt = (tid >> 9) & 63, e = tid >> 15;
    const float* src = w1l + (size_t)e*262144 + (size_t)(kk*32 + (l>>4)*8)*DFFN + nt*16 + (l&15);
    unsigned short o[8];
    #pragma unroll
    for (int j = 0; j < 8; ++j) o[j] = f2bf(src[(size_t)j*DFFN]);
    ulonglong2* dst = (ulonglong2*)(w1p + (size_t)tid*8);
    *dst = *(ulonglong2*)o;
}

// w2p[e][nt(16)][kk(32)][lane(64)][j(8)] = w2[e][kk*32+(lane>>4)*8+j][nt*16+(lane&15)]
__global__ void pack_w2(const float* __restrict__ w2l, unsigned short* __restrict__ w2p) {
    int tid = blockIdx.x*256 + threadIdx.x;   // 327680 total
    int l = tid & 63, kk = (tid >> 6) & 31, nt = (tid >> 11) & 15, e = tid >> 15;
    const float* src = w2l + (size_t)e*262144 + (size_t)(kk*32 + (l>>4)*8)*DN + nt*16 + (l&15);
    unsigned short o[8];
    #pragma unroll
    for (int j = 0; j < 8; ++j) o[j] = f2bf(src[(size_t)j*DN]);
    ulonglong2* dst = (ulonglong2*)(w2p + (size_t)tid*8);
    *dst = *(ulonglong2*)o;
}

// ---------------- MoE v3: bf16 MFMA grouped expert FFN + residual LN -------------
#define TM 16
__global__ __launch_bounds__(256)
void moe_kernel(float* __restrict__ z, const int* __restrict__ elist,
                const int* __restrict__ ec, const float* __restrict__ rmaxv,
                const unsigned short* __restrict__ w1p, const float* __restrict__ b1,
                const unsigned short* __restrict__ w2p, const float* __restrict__ b2,
                const float* __restrict__ g, const float* __restrict__ bb) {
    int e = blockIdx.y;
    int cnt = ec[e];
    int base = blockIdx.x * TM;
    if (base >= cnt) return;
    int n = min(TM, cnt - base);

    __shared__ __align__(16) unsigned short ts[16*264];     // A-tile bf16, pad 8
    __shared__ __align__(16) unsigned short hbuf[16*1032];  // h bf16, pad 8
    __shared__ __align__(16) float ybuf[16*260];            // y fp32, pad 4
    __shared__ int toks[16];
    __shared__ float rm[16];

    int tid = threadIdx.x;
    int w = tid >> 6, l = tid & 63;
    if (tid < 16) {
        int tt = (tid < n) ? elist[e*TTOT + base + tid] : 0;
        toks[tid] = tt;
        rm[tid] = rmaxv[tt];
    }
    __syncthreads();
    #pragma unroll
    for (int m = 0; m < 16; ++m)
        ts[m*264 + tid] = f2bf(z[(size_t)toks[m]*DN + tid]);
    __syncthreads();

    // ---- GEMM1: h[16][1024] = relu(ts @ w1 + b1), wave w owns cols [w*256, w*256+256)
    const bf16x8* w1v = (const bf16x8*)w1p;
    const float* b1e = b1 + e*DFFN;
    f32x4 acc[16];
    #pragma unroll
    for (int i = 0; i < 16; ++i) acc[i] = (f32x4){0.f,0.f,0.f,0.f};
    #pragma unroll
    for (int kk = 0; kk < 8; ++kk) {
        bf16x8 a = *(const bf16x8*)(ts + (l&15)*264 + kk*32 + (l>>4)*8);
        const bf16x8* wbp = w1v + (((size_t)e*64 + w*16)*8 + kk)*64 + l;
        #pragma unroll
        for (int nt2 = 0; nt2 < 16; ++nt2)
            acc[nt2] = __builtin_amdgcn_mfma_f32_16x16x32_bf16(a, wbp[nt2*512], acc[nt2], 0, 0, 0);
    }
    #pragma unroll
    for (int nt2 = 0; nt2 < 16; ++nt2) {
        int col = w*256 + nt2*16 + (l&15);
        float bv = b1e[col];
        #pragma unroll
        for (int r = 0; r < 4; ++r) {
            int row = (l>>4)*4 + r;
            hbuf[row*1032 + col] = f2bf(fmaxf(acc[nt2][r] + bv, 0.f));
        }
    }
    __syncthreads();

    // ---- GEMM2: y[16][256] = relu_h @ w2 + b2, wave w owns cols [w*64, w*64+64)
    const bf16x8* w2v = (const bf16x8*)w2p;
    const float* b2e = b2 + e*DN;
    f32x4 acc2[4];
    #pragma unroll
    for (int i = 0; i < 4; ++i) acc2[i] = (f32x4){0.f,0.f,0.f,0.f};
    for (int kk = 0; kk < 32; ++kk) {
        bf16x8 a = *(const bf16x8*)(hbuf + (l&15)*1032 + kk*32 + (l>>4)*8);
        const bf16x8* wbp = w2v + (((size_t)e*16 + w*4)*32 + kk)*64 + l;
        #pragma unroll
        for (int nt2 = 0; nt2 < 4; ++nt2)
            acc2[nt2] = __builtin_amdgcn_mfma_f32_16x16x32_bf16(a, wbp[nt2*2048], acc2[nt2], 0, 0, 0);
    }
    #pragma unroll
    for (int nt2 = 0; nt2 < 4; ++nt2) {
        int col = w*64 + nt2*16 + (l&15);
        float bv = b2e[col];
        #pragma unroll
        for (int r = 0; r < 4; ++r) {
            int row = (l>>4)*4 + r;
            ybuf[row*260 + col] = (acc2[nt2][r] + bv) * rm[row];
        }
    }
    __syncthreads();

    // ---- residual + LN, wave w owns rows w*4..w*4+3
    #pragma unroll
    for (int rr = 0; rr < 4; ++rr) {
        int row = w*4 + rr;
        if (row < n) {
            int t = toks[row];
            float v[4];
            #pragma unroll
            for (int c = 0; c < 4; ++c)
                v[c] = ybuf[row*260 + l + 64*c] + z[(size_t)t*DN + l + 64*c];
            float s = wave_sum(v[0]+v[1]+v[2]+v[3]);
            float mu = s * (1.0f/DN);
            float s2 = 0.f;
            #pragma unroll
            for (int c = 0; c < 4; ++c) { v[c] -= mu; s2 += v[c]*v[c]; }
            s2 = wave_sum(s2);
            float rs = rsqrtf(s2 * (1.0f/DN) + 1e-5f);
            #pragma unroll
            for (int c = 0; c < 4; ++c) {
                int col = l + 64*c;
                z[(size_t)t*DN + col] = v[c]*rs*g[col] + bb[col];
            }
        }
    }
}

// ---------------- deconv weight repack: wt[t][din][dout] = w[din][dout][t] --------
__global__ void repack_deconv(const float* __restrict__ w, float* __restrict__ wt) {
    int idx = blockIdx.x*256 + threadIdx.x;
    int dout = idx & 255;
    int din = (idx >> 8) & 255;
    int t = idx >> 16;
    wt[idx] = w[((size_t)din*DN + dout)*4 + t];
}

// ---------------- deconv (ConvTranspose1d k=4 s=2 p=1) + bias -> u[b][w][dout] ----
__global__ void deconv_kernel(const float* __restrict__ z, const float* __restrict__ dwT,
                              const float* __restrict__ db, float* __restrict__ u) {
    int blk = blockIdx.x;
    int tile = blk & 63;
    int b = blk >> 6;
    int tid = threadIdx.x;
    int w0 = tile * 16;
    int lbase = tile*8 - 1;
    __shared__ float zst[DN][12];
    for (int i = tid; i < 10*DN; i += 256) {
        int rr = i >> 8, dd = i & 255;
        int l = lbase + rr;
        zst[dd][rr] = (l >= 0 && l < LATN) ? z[((size_t)b*LATN + l)*DN + dd] : 0.0f;
    }
    if (tid < DN) { zst[tid][10] = 0.f; zst[tid][11] = 0.f; }
    __syncthreads();
    float acc[16];
    #pragma unroll
    for (int i = 0; i < 16; ++i) acc[i] = 0.f;
    const float* wp0 = &dwT[0*65536 + tid];
    const float* wp1 = &dwT[1*65536 + tid];
    const float* wp2 = &dwT[2*65536 + tid];
    const float* wp3 = &dwT[3*65536 + tid];
    for (int din = 0; din < DN; ++din) {
        float4 A  = *(const float4*)&zst[din][0];
        float4 Bq = *(const float4*)&zst[din][4];
        float4 Cq = *(const float4*)&zst[din][8];
        float rr[10] = {A.x,A.y,A.z,A.w,Bq.x,Bq.y,Bq.z,Bq.w,Cq.x,Cq.y};
        float wv0 = wp0[din*DN];
        float wv1 = wp1[din*DN];
        float wv2 = wp2[din*DN];
        float wv3 = wp3[din*DN];
        #pragma unroll
        for (int jj = 0; jj < 8; ++jj) {
            acc[1+2*jj] += rr[jj+2]*wv0 + rr[jj+1]*wv2;
            acc[2*jj]   += rr[jj+1]*wv1 + rr[jj]*wv3;
        }
    }
    float bv = db[tid];
    #pragma unroll
    for (int wi = 0; wi < 16; ++wi)
        u[((size_t)b*1024 + w0 + wi)*DN + tid] = acc[wi] + bv;
}

// ---------------- head: lin1 + tanh + lin2 ----------------
__global__ void head_kernel(const float* __restrict__ u, const float* __restrict__ w1,
                            const float* __restrict__ b1, const float* __restrict__ w2,
                            const float* __restrict__ b2, float* __restrict__ out) {
    __shared__ float us[8][DN];
    __shared__ float v1[8][128];
    int r0 = blockIdx.x * 8;
    int tid = threadIdx.x;   // 128 threads
    for (int i = tid; i < 8*DN; i += 128)
        us[i >> 8][i & 255] = u[(size_t)r0*DN + i];
    __syncthreads();
    const float4* wr = (const float4*)&w1[tid*DN];
    float acc[8] = {0,0,0,0,0,0,0,0};
    for (int d4 = 0; d4 < 64; ++d4) {
        float4 w = wr[d4];
        #pragma unroll
        for (int m = 0; m < 8; ++m)
            acc[m] += dot4(w, *(const float4*)&us[m][d4*4]);
    }
    float bv = b1[tid];
    #pragma unroll
    for (int m = 0; m < 8; ++m) v1[m][tid] = tanhf(acc[m] + bv);
    __syncthreads();
    if (tid < 8) {
        float s = b2[0];
        for (int j = 0; j < 128; ++j) s += v1[tid][j] * w2[j];
        out[r0 + tid] = s;
    }
}

// ---------------- loss ----------------
__global__ void loss_kernel(const float* __restrict__ counts, const float* __restrict__ rprob,
                            float* __restrict__ out) {
    if (threadIdx.x == 0) {
        float s = 0;
        for (int i = 0; i < 20; ++i) s += counts[i] * rprob[i];
        out[8192] = 10.0f * s / (4096.0f * 4096.0f);
    }
}

extern "C" void kernel_launch(void* const* d_in, const int* in_sizes, int n_in,
                              void* d_out, int out_size, void* d_ws, size_t ws_size,
                              hipStream_t stream) {
    const float* x        = (const float*)d_in[0];
    const float* conv_w   = (const float*)d_in[1];
    const float* conv_b   = (const float*)d_in[2];
    const float* pe       = (const float*)d_in[3];
    const float* ln0_g    = (const float*)d_in[4];
    const float* ln0_b    = (const float*)d_in[5];
    const float* wq       = (const float*)d_in[6];
    const float* bq       = (const float*)d_in[7];
    const float* wk       = (const float*)d_in[8];
    const float* bk       = (const float*)d_in[9];
    const float* wv       = (const float*)d_in[10];
    const float* bv       = (const float*)d_in[11];
    const float* wo       = (const float*)d_in[12];
    const float* bo       = (const float*)d_in[13];
    const float* ln1_g    = (const float*)d_in[14];
    const float* ln1_b    = (const float*)d_in[15];
    const float* ln2_g    = (const float*)d_in[16];
    const float* ln2_b    = (const float*)d_in[17];
    const float* router_w = (const float*)d_in[18];
    const float* router_b = (const float*)d_in[19];
    const float* e_w1     = (const float*)d_in[20];
    const float* e_b1     = (const float*)d_in[21];
    const float* e_w2     = (const float*)d_in[22];
    const float* e_b2     = (const float*)d_in[23];
    const float* deconv_w = (const float*)d_in[24];
    const float* deconv_b = (const float*)d_in[25];
    const float* lin1_w   = (const float*)d_in[26];
    const float* lin1_b   = (const float*)d_in[27];
    const float* lin2_w   = (const float*)d_in[28];
    const float* lin2_b   = (const float*)d_in[29];

    float* ws = (float*)d_ws;
    const size_t M = 1048576;
    float* z    = ws;
    float* q    = ws + 1*M;
    float* k    = ws + 2*M;
    float* v    = ws + 3*M;
    float* a    = ws + 4*M;
    float* y    = ws + 5*M;
    float* rmax = ws + 6*M;
    float* counts = rmax + 4096;
    float* rprob  = counts + 32;
    int* ec     = (int*)(rprob + 32);
    int* elist  = ec + 32;                    // 2*10*4096
    // bf16 packed expert weights, re-packed per layer into dead q/k/v/a space
    unsigned short* w1p = (unsigned short*)(ws + 1*M);  // 5.24 MB over q+k
    unsigned short* w2p = (unsigned short*)(ws + 3*M);  // 5.24 MB over v+a
    float* u    = ws + 1*M;      // overlaps q,k (after attn layers)
    float* dwT  = ws + 3*M;      // overlaps v (after attn layers)
    float* out  = (float*)d_out;

    zero_kernel<<<1, 64, 0, stream>>>(counts, rprob, ec);
    tokenizer_kernel<<<TTOT, 256, 0, stream>>>(x, conv_w, conv_b, pe, ln0_g, ln0_b, z);

    for (int l = 0; l < 2; ++l) {
        dim3 qkvg(TTOT/16, 3);
        gemm_qkv<<<qkvg, 256, 0, stream>>>(z, wq + l*65536, bq + l*256,
                                           wk + l*65536, bk + l*256,
                                           wv + l*65536, bv + l*256, q, k, v);
        attn_kernel<<<2048, 256, 0, stream>>>(q, k, v, a);
        gemm16<<<TTOT/16, 256, 0, stream>>>(a, wo + l*65536, bo + l*256, y);
        ln_residual<<<TTOT, 256, 0, stream>>>(z, y, ln1_g + l*256, ln1_b + l*256);
        router_kernel<<<TTOT/64, 256, 0, stream>>>(z, router_w + l*2560, router_b + l*10,
                                                   rmax, counts + l*10, rprob + l*10,
                                                   ec + l*10, elist + l*10*TTOT);
        // pack this layer's expert weights to bf16 MFMA-fragment layout (q/k/v/a are dead now)
        pack_w1<<<1280, 256, 0, stream>>>(e_w1 + (size_t)l*2621440, w1p);
        pack_w2<<<1280, 256, 0, stream>>>(e_w2 + (size_t)l*2621440, w2p);
        dim3 mg(TTOT/TM, NEXP);
        moe_kernel<<<mg, 256, 0, stream>>>(z, elist + l*10*TTOT, ec + l*10, rmax,
                                           w1p, e_b1 + l*10240,
                                           w2p, e_b2 + l*2560,
                                           ln2_g + l*256, ln2_b + l*256);
    }

    repack_deconv<<<1024, 256, 0, stream>>>(deconv_w, dwT);
    deconv_kernel<<<512, 256, 0, stream>>>(z, dwT, deconv_b, u);
    head_kernel<<<1024, 128, 0, stream>>>(u, lin1_w, lin1_b, lin2_w, lin2_b, out);
    loss_kernel<<<1, 64, 0, stream>>>(counts, rprob, out);
}

// Round 4
// 586.673 us; speedup vs baseline: 3.7201x; 1.5939x over previous
//
#include <hip/hip_runtime.h>
#include <math.h>

#define LATN 512
#define DN 256
#define DKN 128
#define TTOT 4096   // B*LAT
#define NEXP 10
#define DFFN 1024

using bf16x8 = __attribute__((ext_vector_type(8))) short;
using f32x4  = __attribute__((ext_vector_type(4))) float;

__device__ __forceinline__ float dot4(float4 a, float4 b) {
    return a.x*b.x + a.y*b.y + a.z*b.z + a.w*b.w;
}

__device__ __forceinline__ unsigned short f2bf(float f) {
    union { float f; unsigned int u; } v; v.f = f;
    unsigned int u = v.u + 0x7FFFu + ((v.u >> 16) & 1u);
    return (unsigned short)(u >> 16);
}

// ---------------- reduction helper (256-thread blocks) ----------------
__device__ __forceinline__ float block_reduce_sum(float v, float* red) {
    #pragma unroll
    for (int off = 32; off; off >>= 1) v += __shfl_down(v, off, 64);
    int lane = threadIdx.x & 63, wid = threadIdx.x >> 6;
    if (lane == 0) red[wid] = v;
    __syncthreads();
    float r = red[0] + red[1] + red[2] + red[3];
    __syncthreads();
    return r;
}

__device__ __forceinline__ float wave_sum(float x) {
    #pragma unroll
    for (int off = 32; off; off >>= 1) x += __shfl_xor(x, off, 64);
    return x;
}

// ---------------- zero init ----------------
__global__ void zero_kernel(float* counts, float* rprob, int* ec) {
    int i = threadIdx.x;
    if (i < 20) { counts[i] = 0.f; rprob[i] = 0.f; ec[i] = 0; }
}

// ---------------- tokenizer: conv5 + LPpool2 + PE + LN ----------------
__global__ void tokenizer_kernel(const float* __restrict__ x, const float* __restrict__ cw,
                                 const float* __restrict__ cb, const float* __restrict__ pe,
                                 const float* __restrict__ g, const float* __restrict__ bb,
                                 float* __restrict__ z) {
    int blk = blockIdx.x;
    int l = blk & (LATN - 1);
    int b = blk >> 9;
    int d = threadIdx.x;
    __shared__ float red[8];
    const float* xb = x + (size_t)b * 1024;
    float w0 = cw[d*5+0], w1 = cw[d*5+1], w2 = cw[d*5+2], w3 = cw[d*5+3], w4 = cw[d*5+4];
    float bv = cb[d];
    int p0 = 2 * l;
    auto xc = [&](int i) { return xb[min(max(i, 0), 1023)]; };
    float h0 = bv + w0*xc(p0-2) + w1*xc(p0-1) + w2*xc(p0)   + w3*xc(p0+1) + w4*xc(p0+2);
    float h1 = bv + w0*xc(p0-1) + w1*xc(p0)   + w2*xc(p0+1) + w3*xc(p0+2) + w4*xc(p0+3);
    float pool = sqrtf(h0*h0 + h1*h1);
    float val = pool + pe[l*DN + d];
    float s = block_reduce_sum(val, red);
    float mu = s * (1.0f/DN);
    float dv = val - mu;
    float s2 = block_reduce_sum(dv*dv, red);
    float r = rsqrtf(s2 * (1.0f/DN) + 1e-5f);
    z[((size_t)b*LATN + l)*DN + d] = dv*r*g[d] + bb[d];
}

// ---------------- GEMM core: 16 tokens/block, thread owns 2 cols x 8 tokens -------
__device__ __forceinline__ void gemm16_body(const float* __restrict__ A,
                                            const float* __restrict__ W,
                                            const float* __restrict__ bias,
                                            float* __restrict__ out, int t0,
                                            float as[16][DN]) {
    int tid = threadIdx.x;
    #pragma unroll
    for (int m = 0; m < 16; ++m) as[m][tid] = A[(size_t)(t0+m)*DN + tid];
    __syncthreads();
    int c = tid & 127, hh = tid >> 7;
    int m0 = hh * 8;
    const float4* wa = (const float4*)&W[(size_t)c * DN];
    const float4* wb = (const float4*)&W[(size_t)(c+128) * DN];
    float acc0[8] = {0,0,0,0,0,0,0,0};
    float acc1[8] = {0,0,0,0,0,0,0,0};
    for (int j4 = 0; j4 < 64; ++j4) {
        float4 w0 = wa[j4];
        float4 w1 = wb[j4];
        #pragma unroll
        for (int m = 0; m < 8; ++m) {
            float4 a = *(const float4*)&as[m0+m][j4*4];
            acc0[m] += dot4(a, w0);
            acc1[m] += dot4(a, w1);
        }
    }
    float b0 = bias[c], b1 = bias[c+128];
    #pragma unroll
    for (int m = 0; m < 8; ++m) {
        out[(size_t)(t0+m0+m)*DN + c]       = acc0[m] + b0;
        out[(size_t)(t0+m0+m)*DN + c + 128] = acc1[m] + b1;
    }
}

__global__ void gemm_qkv(const float* __restrict__ z,
                         const float* __restrict__ wq, const float* __restrict__ bq,
                         const float* __restrict__ wk, const float* __restrict__ bk,
                         const float* __restrict__ wv, const float* __restrict__ bv,
                         float* __restrict__ q, float* __restrict__ k, float* __restrict__ v) {
    __shared__ float as[16][DN];
    const float* W; const float* bias; float* out;
    if (blockIdx.y == 0)      { W = wq; bias = bq; out = q; }
    else if (blockIdx.y == 1) { W = wk; bias = bk; out = k; }
    else                      { W = wv; bias = bv; out = v; }
    gemm16_body(z, W, bias, out, blockIdx.x * 16, as);
}

__global__ void gemm16(const float* __restrict__ A, const float* __restrict__ W,
                       const float* __restrict__ bias, float* __restrict__ out) {
    __shared__ float as[16][DN];
    gemm16_body(A, W, bias, out, blockIdx.x * 16, as);
}

// ---------------- attention v2: 16 q-rows/block, reg-cached Q, XCD swizzle --------
__global__ __launch_bounds__(256)
void attn_kernel(const float* __restrict__ q, const float* __restrict__ k,
                 const float* __restrict__ v, float* __restrict__ a) {
    // XCD-aware swizzle: blk%8 -> XCD; give each XCD 2 bh's only (1 MB L2 set)
    int blk = blockIdx.x;
    int xcd = blk & 7, j = blk >> 3;
    int bh = xcd*2 + (j & 1);
    int tile = j >> 1;
    int b = bh >> 1, h = bh & 1;
    int q0 = tile * 16;
    int tid = threadIdx.x;

    __shared__ float qs[16][132];
    __shared__ float ps[16][520];
    __shared__ float pq[4][16][130];

    // stage Q tile 16x128
    for (int i = tid; i < 512; i += 256) {
        int qi = i >> 5, d4 = i & 31;
        *(float4*)&qs[qi][d4*4] =
            *(const float4*)&q[((size_t)(b*LATN + q0 + qi))*DN + h*DKN + d4*4];
    }
    __syncthreads();

    const float scale = 0.08838834764831844f;  // 1/sqrt(128)
    // ---- phase 1: scores. thread owns keys {tid, tid+256}, all 16 q rows
    {
        const float* k0p = &k[((size_t)(b*LATN + tid))*DN + h*DKN];
        const float* k1p = k0p + 256*DN;
        float acc0[16], acc1[16];
        #pragma unroll
        for (int i = 0; i < 16; ++i) { acc0[i] = 0.f; acc1[i] = 0.f; }
        for (int dc = 0; dc < 32; ++dc) {
            float4 kv0 = *(const float4*)&k0p[dc*4];
            float4 kv1 = *(const float4*)&k1p[dc*4];
            #pragma unroll
            for (int qq = 0; qq < 16; ++qq) {
                float4 qv = *(const float4*)&qs[qq][dc*4];
                acc0[qq] += dot4(kv0, qv);
                acc1[qq] += dot4(kv1, qv);
            }
        }
        #pragma unroll
        for (int qq = 0; qq < 16; ++qq) {
            ps[qq][tid]     = acc0[qq]*scale;
            ps[qq][tid+256] = acc1[qq]*scale;
        }
    }
    __syncthreads();

    // ---- phase 2: softmax, wave w owns rows 4w..4w+3
    {
        int w = tid >> 6, lane = tid & 63;
        for (int r = w*4; r < w*4 + 4; ++r) {
            float e[8]; float mx = -1e30f;
            #pragma unroll
            for (int i2 = 0; i2 < 8; ++i2) { e[i2] = ps[r][lane + 64*i2]; mx = fmaxf(mx, e[i2]); }
            #pragma unroll
            for (int off = 32; off; off >>= 1) mx = fmaxf(mx, __shfl_xor(mx, off, 64));
            float s = 0.f;
            #pragma unroll
            for (int i2 = 0; i2 < 8; ++i2) { e[i2] = __expf(e[i2] - mx); s += e[i2]; }
            #pragma unroll
            for (int off = 32; off; off >>= 1) s += __shfl_xor(s, off, 64);
            float inv = 1.0f / s;
            #pragma unroll
            for (int i2 = 0; i2 < 8; ++i2) ps[r][lane + 64*i2] = e[i2]*inv;
        }
    }
    __syncthreads();

    // ---- phase 3: PV. thread owns 2 d's x 16 q x key-quarter; P reads wave-uniform
    {
        int kq = tid >> 6, d2 = (tid & 63)*2;
        float accx[16], accy[16];
        #pragma unroll
        for (int i = 0; i < 16; ++i) { accx[i] = 0.f; accy[i] = 0.f; }
        const float* vbase = &v[((size_t)(b*LATN + kq*128))*DN + h*DKN + d2];
        for (int k4 = 0; k4 < 32; ++k4) {
            float4 pf[16];
            #pragma unroll
            for (int qq = 0; qq < 16; ++qq) pf[qq] = *(const float4*)&ps[qq][kq*128 + k4*4];
            #pragma unroll
            for (int jj = 0; jj < 4; ++jj) {
                float2 vv = *(const float2*)&vbase[(size_t)(k4*4 + jj)*DN];
                #pragma unroll
                for (int qq = 0; qq < 16; ++qq) {
                    float p = ((const float*)&pf[qq])[jj];
                    accx[qq] += p*vv.x; accy[qq] += p*vv.y;
                }
            }
        }
        #pragma unroll
        for (int qq = 0; qq < 16; ++qq) {
            pq[kq][qq][d2] = accx[qq]; pq[kq][qq][d2+1] = accy[qq];
        }
    }
    __syncthreads();

    for (int i = tid; i < 2048; i += 256) {
        int qq = i >> 7, d = i & 127;
        float s = pq[0][qq][d] + pq[1][qq][d] + pq[2][qq][d] + pq[3][qq][d];
        a[((size_t)(b*LATN + q0 + qq))*DN + h*DKN + d] = s;
    }
}

// ---------------- residual + LN (in-place on z) ----------------
__global__ void ln_residual(float* __restrict__ z, const float* __restrict__ y,
                            const float* __restrict__ g, const float* __restrict__ b) {
    int t = blockIdx.x, tid = threadIdx.x;
    __shared__ float red[8];
    float val = z[(size_t)t*DN + tid] + y[(size_t)t*DN + tid];
    float s = block_reduce_sum(val, red);
    float mu = s * (1.0f/DN);
    float dv = val - mu;
    float s2 = block_reduce_sum(dv*dv, red);
    float r = rsqrtf(s2 * (1.0f/DN) + 1e-5f);
    z[(size_t)t*DN + tid] = dv*r*g[tid] + b[tid];
}

// ---------------- router: 64 tokens/block, 4 lanes/token ----------------
__global__ void router_kernel(const float* __restrict__ z, const float* __restrict__ rw,
                              const float* __restrict__ rb, float* __restrict__ rmaxv,
                              float* __restrict__ counts, float* __restrict__ rprob,
                              int* __restrict__ ec, int* __restrict__ elist) {
    __shared__ float rws[NEXP*DN];
    __shared__ float scnt[NEXP], sprob[NEXP];
    int tid = threadIdx.x;
    for (int i = tid; i < NEXP*DN; i += 256) rws[i] = rw[i];
    if (tid < NEXP) { scnt[tid] = 0.f; sprob[tid] = 0.f; }
    __syncthreads();
    int g = tid >> 2, j = tid & 3;
    int t = blockIdx.x * 64 + g;
    const float4* z4 = (const float4*)&z[(size_t)t*DN + j*64];
    float acc[NEXP];
    #pragma unroll
    for (int e = 0; e < NEXP; ++e) acc[e] = 0.f;
    #pragma unroll 4
    for (int k4 = 0; k4 < 16; ++k4) {
        float4 zv = z4[k4];
        #pragma unroll
        for (int e = 0; e < NEXP; ++e)
            acc[e] += dot4(zv, *(const float4*)&rws[e*DN + j*64 + k4*4]);
    }
    #pragma unroll
    for (int e = 0; e < NEXP; ++e) {
        acc[e] += __shfl_xor(acc[e], 1, 64);
        acc[e] += __shfl_xor(acc[e], 2, 64);
    }
    if (j == 0) {
        float lg[NEXP];
        float m = acc[0] + rb[0]; int am = 0;
        lg[0] = m;
        #pragma unroll
        for (int e = 1; e < NEXP; ++e) {
            lg[e] = acc[e] + rb[e];
            if (lg[e] > m) { m = lg[e]; am = e; }
        }
        float p[NEXP], s = 0.f;
        #pragma unroll
        for (int e = 0; e < NEXP; ++e) { p[e] = expf(lg[e] - m); s += p[e]; }
        float inv = 1.0f / s;
        rmaxv[t] = p[am] * inv;
        atomicAdd(&scnt[am], 1.0f);
        #pragma unroll
        for (int e = 0; e < NEXP; ++e) atomicAdd(&sprob[e], p[e] * inv);
        int pos = atomicAdd(&ec[am], 1);
        elist[am*TTOT + pos] = t;
    }
    __syncthreads();
    if (tid < NEXP) {
        atomicAdd(&counts[tid], scnt[tid]);
        atomicAdd(&rprob[tid], sprob[tid]);
    }
}

// ---------------- weight pack kernels: fp32 -> bf16 MFMA-B-fragment order --------
__global__ void pack_w1(const float* __restrict__ w1l, unsigned short* __restrict__ w1p) {
    int tid = blockIdx.x*256 + threadIdx.x;   // 327680 total
    int l = tid & 63, kk = (tid >> 6) & 7, nt = (tid >> 9) & 63, e = tid >> 15;
    const float* src = w1l + (size_t)e*262144 + (size_t)(kk*32 + (l>>4)*8)*DFFN + nt*16 + (l&15);
    unsigned short o[8];
    #pragma unroll
    for (int j = 0; j < 8; ++j) o[j] = f2bf(src[(size_t)j*DFFN]);
    ulonglong2* dst = (ulonglong2*)(w1p + (size_t)tid*8);
    *dst = *(ulonglong2*)o;
}

__global__ void pack_w2(const float* __restrict__ w2l, unsigned short* __restrict__ w2p) {
    int tid = blockIdx.x*256 + threadIdx.x;   // 327680 total
    int l = tid & 63, kk = (tid >> 6) & 31, nt = (tid >> 11) & 15, e = tid >> 15;
    const float* src = w2l + (size_t)e*262144 + (size_t)(kk*32 + (l>>4)*8)*DN + nt*16 + (l&15);
    unsigned short o[8];
    #pragma unroll
    for (int j = 0; j < 8; ++j) o[j] = f2bf(src[(size_t)j*DN]);
    ulonglong2* dst = (ulonglong2*)(w2p + (size_t)tid*8);
    *dst = *(ulonglong2*)o;
}

// ---------------- MoE: bf16 MFMA grouped expert FFN + residual LN -------------
#define TM 16
__global__ __launch_bounds__(256)
void moe_kernel(float* __restrict__ z, const int* __restrict__ elist,
                const int* __restrict__ ec, const float* __restrict__ rmaxv,
                const unsigned short* __restrict__ w1p, const float* __restrict__ b1,
                const unsigned short* __restrict__ w2p, const float* __restrict__ b2,
                const float* __restrict__ g, const float* __restrict__ bb) {
    int e = blockIdx.y;
    int cnt = ec[e];
    int base = blockIdx.x * TM;
    if (base >= cnt) return;
    int n = min(TM, cnt - base);

    __shared__ __align__(16) unsigned short ts[16*264];
    __shared__ __align__(16) unsigned short hbuf[16*1032];
    __shared__ __align__(16) float ybuf[16*260];
    __shared__ int toks[16];
    __shared__ float rm[16];

    int tid = threadIdx.x;
    int w = tid >> 6, l = tid & 63;
    if (tid < 16) {
        int tt = (tid < n) ? elist[e*TTOT + base + tid] : 0;
        toks[tid] = tt;
        rm[tid] = rmaxv[tt];
    }
    __syncthreads();
    #pragma unroll
    for (int m = 0; m < 16; ++m)
        ts[m*264 + tid] = f2bf(z[(size_t)toks[m]*DN + tid]);
    __syncthreads();

    const bf16x8* w1v = (const bf16x8*)w1p;
    const float* b1e = b1 + e*DFFN;
    f32x4 acc[16];
    #pragma unroll
    for (int i = 0; i < 16; ++i) acc[i] = (f32x4){0.f,0.f,0.f,0.f};
    #pragma unroll
    for (int kk = 0; kk < 8; ++kk) {
        bf16x8 a = *(const bf16x8*)(ts + (l&15)*264 + kk*32 + (l>>4)*8);
        const bf16x8* wbp = w1v + (((size_t)e*64 + w*16)*8 + kk)*64 + l;
        #pragma unroll
        for (int nt2 = 0; nt2 < 16; ++nt2)
            acc[nt2] = __builtin_amdgcn_mfma_f32_16x16x32_bf16(a, wbp[nt2*512], acc[nt2], 0, 0, 0);
    }
    #pragma unroll
    for (int nt2 = 0; nt2 < 16; ++nt2) {
        int col = w*256 + nt2*16 + (l&15);
        float bv = b1e[col];
        #pragma unroll
        for (int r = 0; r < 4; ++r) {
            int row = (l>>4)*4 + r;
            hbuf[row*1032 + col] = f2bf(fmaxf(acc[nt2][r] + bv, 0.f));
        }
    }
    __syncthreads();

    const bf16x8* w2v = (const bf16x8*)w2p;
    const float* b2e = b2 + e*DN;
    f32x4 acc2[4];
    #pragma unroll
    for (int i = 0; i < 4; ++i) acc2[i] = (f32x4){0.f,0.f,0.f,0.f};
    for (int kk = 0; kk < 32; ++kk) {
        bf16x8 a = *(const bf16x8*)(hbuf + (l&15)*1032 + kk*32 + (l>>4)*8);
        const bf16x8* wbp = w2v + (((size_t)e*16 + w*4)*32 + kk)*64 + l;
        #pragma unroll
        for (int nt2 = 0; nt2 < 4; ++nt2)
            acc2[nt2] = __builtin_amdgcn_mfma_f32_16x16x32_bf16(a, wbp[nt2*2048], acc2[nt2], 0, 0, 0);
    }
    #pragma unroll
    for (int nt2 = 0; nt2 < 4; ++nt2) {
        int col = w*64 + nt2*16 + (l&15);
        float bv = b2e[col];
        #pragma unroll
        for (int r = 0; r < 4; ++r) {
            int row = (l>>4)*4 + r;
            ybuf[row*260 + col] = (acc2[nt2][r] + bv) * rm[row];
        }
    }
    __syncthreads();

    #pragma unroll
    for (int rr = 0; rr < 4; ++rr) {
        int row = w*4 + rr;
        if (row < n) {
            int t = toks[row];
            float v[4];
            #pragma unroll
            for (int c = 0; c < 4; ++c)
                v[c] = ybuf[row*260 + l + 64*c] + z[(size_t)t*DN + l + 64*c];
            float s = wave_sum(v[0]+v[1]+v[2]+v[3]);
            float mu = s * (1.0f/DN);
            float s2 = 0.f;
            #pragma unroll
            for (int c = 0; c < 4; ++c) { v[c] -= mu; s2 += v[c]*v[c]; }
            s2 = wave_sum(s2);
            float rs = rsqrtf(s2 * (1.0f/DN) + 1e-5f);
            #pragma unroll
            for (int c = 0; c < 4; ++c) {
                int col = l + 64*c;
                z[(size_t)t*DN + col] = v[c]*rs*g[col] + bb[col];
            }
        }
    }
}

// ---------------- deconv weight repack ----------------
__global__ void repack_deconv(const float* __restrict__ w, float* __restrict__ wt) {
    int idx = blockIdx.x*256 + threadIdx.x;
    int dout = idx & 255;
    int din = (idx >> 8) & 255;
    int t = idx >> 16;
    wt[idx] = w[((size_t)din*DN + dout)*4 + t];
}

// ---------------- deconv (ConvTranspose1d k=4 s=2 p=1) + bias -> u[b][w][dout] ----
__global__ void deconv_kernel(const float* __restrict__ z, const float* __restrict__ dwT,
                              const float* __restrict__ db, float* __restrict__ u) {
    int blk = blockIdx.x;
    int tile = blk & 63;
    int b = blk >> 6;
    int tid = threadIdx.x;
    int w0 = tile * 16;
    int lbase = tile*8 - 1;
    __shared__ float zst[DN][12];
    for (int i = tid; i < 10*DN; i += 256) {
        int rr = i >> 8, dd = i & 255;
        int l = lbase + rr;
        zst[dd][rr] = (l >= 0 && l < LATN) ? z[((size_t)b*LATN + l)*DN + dd] : 0.0f;
    }
    if (tid < DN) { zst[tid][10] = 0.f; zst[tid][11] = 0.f; }
    __syncthreads();
    float acc[16];
    #pragma unroll
    for (int i = 0; i < 16; ++i) acc[i] = 0.f;
    const float* wp0 = &dwT[0*65536 + tid];
    const float* wp1 = &dwT[1*65536 + tid];
    const float* wp2 = &dwT[2*65536 + tid];
    const float* wp3 = &dwT[3*65536 + tid];
    for (int din = 0; din < DN; ++din) {
        float4 A  = *(const float4*)&zst[din][0];
        float4 Bq = *(const float4*)&zst[din][4];
        float4 Cq = *(const float4*)&zst[din][8];
        float rr[10] = {A.x,A.y,A.z,A.w,Bq.x,Bq.y,Bq.z,Bq.w,Cq.x,Cq.y};
        float wv0 = wp0[din*DN];
        float wv1 = wp1[din*DN];
        float wv2 = wp2[din*DN];
        float wv3 = wp3[din*DN];
        #pragma unroll
        for (int jj = 0; jj < 8; ++jj) {
            acc[1+2*jj] += rr[jj+2]*wv0 + rr[jj+1]*wv2;
            acc[2*jj]   += rr[jj+1]*wv1 + rr[jj]*wv3;
        }
    }
    float bv = db[tid];
    #pragma unroll
    for (int wi = 0; wi < 16; ++wi)
        u[((size_t)b*1024 + w0 + wi)*DN + tid] = acc[wi] + bv;
}

// ---------------- head: lin1 + tanh + lin2 ----------------
__global__ void head_kernel(const float* __restrict__ u, const float* __restrict__ w1,
                            const float* __restrict__ b1, const float* __restrict__ w2,
                            const float* __restrict__ b2, float* __restrict__ out) {
    __shared__ float us[8][DN];
    __shared__ float v1[8][128];
    int r0 = blockIdx.x * 8;
    int tid = threadIdx.x;   // 128 threads
    for (int i = tid; i < 8*DN; i += 128)
        us[i >> 8][i & 255] = u[(size_t)r0*DN + i];
    __syncthreads();
    const float4* wr = (const float4*)&w1[tid*DN];
    float acc[8] = {0,0,0,0,0,0,0,0};
    for (int d4 = 0; d4 < 64; ++d4) {
        float4 w = wr[d4];
        #pragma unroll
        for (int m = 0; m < 8; ++m)
            acc[m] += dot4(w, *(const float4*)&us[m][d4*4]);
    }
    float bv = b1[tid];
    #pragma unroll
    for (int m = 0; m < 8; ++m) v1[m][tid] = tanhf(acc[m] + bv);
    __syncthreads();
    if (tid < 8) {
        float s = b2[0];
        for (int j = 0; j < 128; ++j) s += v1[tid][j] * w2[j];
        out[r0 + tid] = s;
    }
}

// ---------------- loss ----------------
__global__ void loss_kernel(const float* __restrict__ counts, const float* __restrict__ rprob,
                            float* __restrict__ out) {
    if (threadIdx.x == 0) {
        float s = 0;
        for (int i = 0; i < 20; ++i) s += counts[i] * rprob[i];
        out[8192] = 10.0f * s / (4096.0f * 4096.0f);
    }
}

extern "C" void kernel_launch(void* const* d_in, const int* in_sizes, int n_in,
                              void* d_out, int out_size, void* d_ws, size_t ws_size,
                              hipStream_t stream) {
    const float* x        = (const float*)d_in[0];
    const float* conv_w   = (const float*)d_in[1];
    const float* conv_b   = (const float*)d_in[2];
    const float* pe       = (const float*)d_in[3];
    const float* ln0_g    = (const float*)d_in[4];
    const float* ln0_b    = (const float*)d_in[5];
    const float* wq       = (const float*)d_in[6];
    const float* bq       = (const float*)d_in[7];
    const float* wk       = (const float*)d_in[8];
    const float* bk       = (const float*)d_in[9];
    const float* wv       = (const float*)d_in[10];
    const float* bv       = (const float*)d_in[11];
    const float* wo       = (const float*)d_in[12];
    const float* bo       = (const float*)d_in[13];
    const float* ln1_g    = (const float*)d_in[14];
    const float* ln1_b    = (const float*)d_in[15];
    const float* ln2_g    = (const float*)d_in[16];
    const float* ln2_b    = (const float*)d_in[17];
    const float* router_w = (const float*)d_in[18];
    const float* router_b = (const float*)d_in[19];
    const float* e_w1     = (const float*)d_in[20];
    const float* e_b1     = (const float*)d_in[21];
    const float* e_w2     = (const float*)d_in[22];
    const float* e_b2     = (const float*)d_in[23];
    const float* deconv_w = (const float*)d_in[24];
    const float* deconv_b = (const float*)d_in[25];
    const float* lin1_w   = (const float*)d_in[26];
    const float* lin1_b   = (const float*)d_in[27];
    const float* lin2_w   = (const float*)d_in[28];
    const float* lin2_b   = (const float*)d_in[29];

    float* ws = (float*)d_ws;
    const size_t M = 1048576;
    float* z    = ws;
    float* q    = ws + 1*M;
    float* k    = ws + 2*M;
    float* v    = ws + 3*M;
    float* a    = ws + 4*M;
    float* y    = ws + 5*M;
    float* rmax = ws + 6*M;
    float* counts = rmax + 4096;
    float* rprob  = counts + 32;
    int* ec     = (int*)(rprob + 32);
    int* elist  = ec + 32;                    // 2*10*4096
    unsigned short* w1p = (unsigned short*)(ws + 1*M);  // packed over q+k (dead)
    unsigned short* w2p = (unsigned short*)(ws + 3*M);  // packed over v+a (dead)
    float* u    = ws + 1*M;
    float* dwT  = ws + 3*M;
    float* out  = (float*)d_out;

    zero_kernel<<<1, 64, 0, stream>>>(counts, rprob, ec);
    tokenizer_kernel<<<TTOT, 256, 0, stream>>>(x, conv_w, conv_b, pe, ln0_g, ln0_b, z);

    for (int l = 0; l < 2; ++l) {
        dim3 qkvg(TTOT/16, 3);
        gemm_qkv<<<qkvg, 256, 0, stream>>>(z, wq + l*65536, bq + l*256,
                                           wk + l*65536, bk + l*256,
                                           wv + l*65536, bv + l*256, q, k, v);
        attn_kernel<<<512, 256, 0, stream>>>(q, k, v, a);
        gemm16<<<TTOT/16, 256, 0, stream>>>(a, wo + l*65536, bo + l*256, y);
        ln_residual<<<TTOT, 256, 0, stream>>>(z, y, ln1_g + l*256, ln1_b + l*256);
        router_kernel<<<TTOT/64, 256, 0, stream>>>(z, router_w + l*2560, router_b + l*10,
                                                   rmax, counts + l*10, rprob + l*10,
                                                   ec + l*10, elist + l*10*TTOT);
        pack_w1<<<1280, 256, 0, stream>>>(e_w1 + (size_t)l*2621440, w1p);
        pack_w2<<<1280, 256, 0, stream>>>(e_w2 + (size_t)l*2621440, w2p);
        dim3 mg(TTOT/TM, NEXP);
        moe_kernel<<<mg, 256, 0, stream>>>(z, elist + l*10*TTOT, ec + l*10, rmax,
                                           w1p, e_b1 + l*10240,
                                           w2p, e_b2 + l*2560,
                                           ln2_g + l*256, ln2_b + l*256);
    }

    repack_deconv<<<1024, 256, 0, stream>>>(deconv_w, dwT);
    deconv_kernel<<<512, 256, 0, stream>>>(z, dwT, deconv_b, u);
    head_kernel<<<1024, 128, 0, stream>>>(u, lin1_w, lin1_b, lin2_w, lin2_b, out);
    loss_kernel<<<1, 64, 0, stream>>>(counts, rprob, out);
}

// Round 5
// 438.301 us; speedup vs baseline: 4.9794x; 1.3385x over previous
//
#include <hip/hip_runtime.h>
#include <math.h>

#define LATN 512
#define DN 256
#define DKN 128
#define TTOT 4096   // B*LAT
#define NEXP 10
#define DFFN 1024

using bf16x8 = __attribute__((ext_vector_type(8))) short;
using f32x4  = __attribute__((ext_vector_type(4))) float;

__device__ __forceinline__ float dot4(float4 a, float4 b) {
    return a.x*b.x + a.y*b.y + a.z*b.z + a.w*b.w;
}

__device__ __forceinline__ unsigned short f2bf(float f) {
    union { float f; unsigned int u; } v; v.f = f;
    unsigned int u = v.u + 0x7FFFu + ((v.u >> 16) & 1u);
    return (unsigned short)(u >> 16);
}

// ---------------- reduction helpers ----------------
__device__ __forceinline__ float block_reduce_sum(float v, float* red) {
    #pragma unroll
    for (int off = 32; off; off >>= 1) v += __shfl_down(v, off, 64);
    int lane = threadIdx.x & 63, wid = threadIdx.x >> 6;
    if (lane == 0) red[wid] = v;
    __syncthreads();
    float r = red[0] + red[1] + red[2] + red[3];
    __syncthreads();
    return r;
}

__device__ __forceinline__ float wave_sum(float x) {
    #pragma unroll
    for (int off = 32; off; off >>= 1) x += __shfl_xor(x, off, 64);
    return x;
}

// ---------------- zero init ----------------
__global__ void zero_kernel(float* counts, float* rprob, int* ec) {
    int i = threadIdx.x;
    if (i < 20) { counts[i] = 0.f; rprob[i] = 0.f; ec[i] = 0; }
}

// ---------------- tokenizer: conv5 + LPpool2 + PE + LN ----------------
__global__ void tokenizer_kernel(const float* __restrict__ x, const float* __restrict__ cw,
                                 const float* __restrict__ cb, const float* __restrict__ pe,
                                 const float* __restrict__ g, const float* __restrict__ bb,
                                 float* __restrict__ z) {
    int blk = blockIdx.x;
    int l = blk & (LATN - 1);
    int b = blk >> 9;
    int d = threadIdx.x;
    __shared__ float red[8];
    const float* xb = x + (size_t)b * 1024;
    float w0 = cw[d*5+0], w1 = cw[d*5+1], w2 = cw[d*5+2], w3 = cw[d*5+3], w4 = cw[d*5+4];
    float bv = cb[d];
    int p0 = 2 * l;
    auto xc = [&](int i) { return xb[min(max(i, 0), 1023)]; };
    float h0 = bv + w0*xc(p0-2) + w1*xc(p0-1) + w2*xc(p0)   + w3*xc(p0+1) + w4*xc(p0+2);
    float h1 = bv + w0*xc(p0-1) + w1*xc(p0)   + w2*xc(p0+1) + w3*xc(p0+2) + w4*xc(p0+3);
    float pool = sqrtf(h0*h0 + h1*h1);
    float val = pool + pe[l*DN + d];
    float s = block_reduce_sum(val, red);
    float mu = s * (1.0f/DN);
    float dv = val - mu;
    float s2 = block_reduce_sum(dv*dv, red);
    float r = rsqrtf(s2 * (1.0f/DN) + 1e-5f);
    z[((size_t)b*LATN + l)*DN + d] = dv*r*g[d] + bb[d];
}

// ---------------- pack projection weights: fp32 [out,in] -> bf16 B-frag ----------
// wp[mat][nt(16)][kk(8)][lane(64)][j(8)] = W[nt*16+(l&15)][kk*32+(l>>4)*8+j]
__global__ void pack_proj(const float* __restrict__ wq, const float* __restrict__ wk,
                          const float* __restrict__ wv, const float* __restrict__ wo,
                          unsigned short* __restrict__ wp) {
    int mat = blockIdx.y;              // 0..7 : layer*4 + {q,k,v,o}
    int l0 = mat >> 2, which = mat & 3;
    const float* base = (which == 0) ? wq : (which == 1) ? wk : (which == 2) ? wv : wo;
    const float* W = base + l0*65536;
    int tid = blockIdx.x*256 + threadIdx.x;   // 0..8191
    int l = tid & 63, kk = (tid >> 6) & 7, nt = tid >> 9;
    const float* src = W + (size_t)(nt*16 + (l&15))*DN + kk*32 + (l>>4)*8;
    unsigned short o[8];
    #pragma unroll
    for (int j = 0; j < 8; ++j) o[j] = f2bf(src[j]);
    *(ulonglong2*)(wp + (size_t)mat*65536 + (size_t)tid*8) = *(ulonglong2*)o;
}

// ---------------- MFMA projection GEMM: out = A @ W^T + b, 64 tokens/block ------
__device__ __forceinline__ void proj_body(const float* __restrict__ A,
                                          const unsigned short* __restrict__ wpm,
                                          const float* __restrict__ bias,
                                          float* __restrict__ out, int t0,
                                          unsigned short* ts) {
    int tid = threadIdx.x;
    // stage A 64x256 -> bf16 LDS (padded pitch 264)
    #pragma unroll
    for (int i = 0; i < 16; ++i) {
        int f4 = i*256 + tid;
        int row = f4 >> 6, c4 = f4 & 63;
        float4 a = *(const float4*)&A[(size_t)(t0+row)*DN + c4*4];
        ushort4 o = { f2bf(a.x), f2bf(a.y), f2bf(a.z), f2bf(a.w) };
        *(ushort4*)&ts[row*264 + c4*4] = o;
    }
    __syncthreads();
    int w = tid >> 6, l = tid & 63;
    f32x4 acc[4][4];
    #pragma unroll
    for (int m = 0; m < 4; ++m)
        #pragma unroll
        for (int n = 0; n < 4; ++n) acc[m][n] = (f32x4){0.f,0.f,0.f,0.f};
    const bf16x8* wv = (const bf16x8*)wpm;
    #pragma unroll
    for (int kk = 0; kk < 8; ++kk) {
        bf16x8 af[4];
        #pragma unroll
        for (int m = 0; m < 4; ++m)
            af[m] = *(const bf16x8*)&ts[(m*16 + (l&15))*264 + kk*32 + (l>>4)*8];
        #pragma unroll
        for (int n = 0; n < 4; ++n) {
            bf16x8 bf = wv[((w*4 + n)*8 + kk)*64 + l];
            #pragma unroll
            for (int m = 0; m < 4; ++m)
                acc[m][n] = __builtin_amdgcn_mfma_f32_16x16x32_bf16(af[m], bf, acc[m][n], 0, 0, 0);
        }
    }
    #pragma unroll
    for (int n = 0; n < 4; ++n) {
        int col = w*64 + n*16 + (l&15);
        float bv2 = bias[col];
        #pragma unroll
        for (int m = 0; m < 4; ++m) {
            #pragma unroll
            for (int r = 0; r < 4; ++r) {
                int row = t0 + m*16 + (l>>4)*4 + r;
                out[(size_t)row*DN + col] = acc[m][n][r] + bv2;
            }
        }
    }
}

__global__ __launch_bounds__(256)
void proj_qkv(const float* __restrict__ z, const unsigned short* __restrict__ wp,
              const float* __restrict__ bq, const float* __restrict__ bk,
              const float* __restrict__ bv,
              float* __restrict__ q, float* __restrict__ k, float* __restrict__ v) {
    __shared__ unsigned short ts[64*264];
    int mat = blockIdx.y;
    const float* bias = (mat == 0) ? bq : (mat == 1) ? bk : bv;
    float* out = (mat == 0) ? q : (mat == 1) ? k : v;
    proj_body(z, wp + (size_t)mat*65536, bias, out, blockIdx.x*64, ts);
}

__global__ __launch_bounds__(256)
void proj_one(const float* __restrict__ A, const unsigned short* __restrict__ wpm,
              const float* __restrict__ bias, float* __restrict__ out) {
    __shared__ unsigned short ts[64*264];
    proj_body(A, wpm, bias, out, blockIdx.x*64, ts);
}

// ---------------- attention: 16 q-rows/block, reg-cached Q, XCD swizzle --------
__global__ __launch_bounds__(256)
void attn_kernel(const float* __restrict__ q, const float* __restrict__ k,
                 const float* __restrict__ v, float* __restrict__ a) {
    int blk = blockIdx.x;
    int xcd = blk & 7, j = blk >> 3;
    int bh = xcd*2 + (j & 1);
    int tile = j >> 1;
    int b = bh >> 1, h = bh & 1;
    int q0 = tile * 16;
    int tid = threadIdx.x;

    __shared__ float qs[16][132];
    __shared__ float ps[16][520];
    __shared__ float pq[4][16][130];

    for (int i = tid; i < 512; i += 256) {
        int qi = i >> 5, d4 = i & 31;
        *(float4*)&qs[qi][d4*4] =
            *(const float4*)&q[((size_t)(b*LATN + q0 + qi))*DN + h*DKN + d4*4];
    }
    __syncthreads();

    const float scale = 0.08838834764831844f;  // 1/sqrt(128)
    {
        const float* k0p = &k[((size_t)(b*LATN + tid))*DN + h*DKN];
        const float* k1p = k0p + 256*DN;
        float acc0[16], acc1[16];
        #pragma unroll
        for (int i = 0; i < 16; ++i) { acc0[i] = 0.f; acc1[i] = 0.f; }
        for (int dc = 0; dc < 32; ++dc) {
            float4 kv0 = *(const float4*)&k0p[dc*4];
            float4 kv1 = *(const float4*)&k1p[dc*4];
            #pragma unroll
            for (int qq = 0; qq < 16; ++qq) {
                float4 qv = *(const float4*)&qs[qq][dc*4];
                acc0[qq] += dot4(kv0, qv);
                acc1[qq] += dot4(kv1, qv);
            }
        }
        #pragma unroll
        for (int qq = 0; qq < 16; ++qq) {
            ps[qq][tid]     = acc0[qq]*scale;
            ps[qq][tid+256] = acc1[qq]*scale;
        }
    }
    __syncthreads();

    {
        int w = tid >> 6, lane = tid & 63;
        for (int r = w*4; r < w*4 + 4; ++r) {
            float e[8]; float mx = -1e30f;
            #pragma unroll
            for (int i2 = 0; i2 < 8; ++i2) { e[i2] = ps[r][lane + 64*i2]; mx = fmaxf(mx, e[i2]); }
            #pragma unroll
            for (int off = 32; off; off >>= 1) mx = fmaxf(mx, __shfl_xor(mx, off, 64));
            float s = 0.f;
            #pragma unroll
            for (int i2 = 0; i2 < 8; ++i2) { e[i2] = __expf(e[i2] - mx); s += e[i2]; }
            #pragma unroll
            for (int off = 32; off; off >>= 1) s += __shfl_xor(s, off, 64);
            float inv = 1.0f / s;
            #pragma unroll
            for (int i2 = 0; i2 < 8; ++i2) ps[r][lane + 64*i2] = e[i2]*inv;
        }
    }
    __syncthreads();

    {
        int kq = tid >> 6, d2 = (tid & 63)*2;
        float accx[16], accy[16];
        #pragma unroll
        for (int i = 0; i < 16; ++i) { accx[i] = 0.f; accy[i] = 0.f; }
        const float* vbase = &v[((size_t)(b*LATN + kq*128))*DN + h*DKN + d2];
        for (int k4 = 0; k4 < 32; ++k4) {
            float4 pf[16];
            #pragma unroll
            for (int qq = 0; qq < 16; ++qq) pf[qq] = *(const float4*)&ps[qq][kq*128 + k4*4];
            #pragma unroll
            for (int jj = 0; jj < 4; ++jj) {
                float2 vv = *(const float2*)&vbase[(size_t)(k4*4 + jj)*DN];
                #pragma unroll
                for (int qq = 0; qq < 16; ++qq) {
                    float p = ((const float*)&pf[qq])[jj];
                    accx[qq] += p*vv.x; accy[qq] += p*vv.y;
                }
            }
        }
        #pragma unroll
        for (int qq = 0; qq < 16; ++qq) {
            pq[kq][qq][d2] = accx[qq]; pq[kq][qq][d2+1] = accy[qq];
        }
    }
    __syncthreads();

    for (int i = tid; i < 2048; i += 256) {
        int qq = i >> 7, d = i & 127;
        float s = pq[0][qq][d] + pq[1][qq][d] + pq[2][qq][d] + pq[3][qq][d];
        a[((size_t)(b*LATN + q0 + qq))*DN + h*DKN + d] = s;
    }
}

// ---------------- residual + LN (in-place on z) ----------------
__global__ void ln_residual(float* __restrict__ z, const float* __restrict__ y,
                            const float* __restrict__ g, const float* __restrict__ b) {
    int t = blockIdx.x, tid = threadIdx.x;
    __shared__ float red[8];
    float val = z[(size_t)t*DN + tid] + y[(size_t)t*DN + tid];
    float s = block_reduce_sum(val, red);
    float mu = s * (1.0f/DN);
    float dv = val - mu;
    float s2 = block_reduce_sum(dv*dv, red);
    float r = rsqrtf(s2 * (1.0f/DN) + 1e-5f);
    z[(size_t)t*DN + tid] = dv*r*g[tid] + b[tid];
}

// ---------------- router: 64 tokens/block, 4 lanes/token ----------------
__global__ void router_kernel(const float* __restrict__ z, const float* __restrict__ rw,
                              const float* __restrict__ rb, float* __restrict__ rmaxv,
                              float* __restrict__ counts, float* __restrict__ rprob,
                              int* __restrict__ ec, int* __restrict__ elist) {
    __shared__ float rws[NEXP*DN];
    __shared__ float scnt[NEXP], sprob[NEXP];
    int tid = threadIdx.x;
    for (int i = tid; i < NEXP*DN; i += 256) rws[i] = rw[i];
    if (tid < NEXP) { scnt[tid] = 0.f; sprob[tid] = 0.f; }
    __syncthreads();
    int g = tid >> 2, j = tid & 3;
    int t = blockIdx.x * 64 + g;
    const float4* z4 = (const float4*)&z[(size_t)t*DN + j*64];
    float acc[NEXP];
    #pragma unroll
    for (int e = 0; e < NEXP; ++e) acc[e] = 0.f;
    #pragma unroll 4
    for (int k4 = 0; k4 < 16; ++k4) {
        float4 zv = z4[k4];
        #pragma unroll
        for (int e = 0; e < NEXP; ++e)
            acc[e] += dot4(zv, *(const float4*)&rws[e*DN + j*64 + k4*4]);
    }
    #pragma unroll
    for (int e = 0; e < NEXP; ++e) {
        acc[e] += __shfl_xor(acc[e], 1, 64);
        acc[e] += __shfl_xor(acc[e], 2, 64);
    }
    if (j == 0) {
        float lg[NEXP];
        float m = acc[0] + rb[0]; int am = 0;
        lg[0] = m;
        #pragma unroll
        for (int e = 1; e < NEXP; ++e) {
            lg[e] = acc[e] + rb[e];
            if (lg[e] > m) { m = lg[e]; am = e; }
        }
        float p[NEXP], s = 0.f;
        #pragma unroll
        for (int e = 0; e < NEXP; ++e) { p[e] = expf(lg[e] - m); s += p[e]; }
        float inv = 1.0f / s;
        rmaxv[t] = p[am] * inv;
        atomicAdd(&scnt[am], 1.0f);
        #pragma unroll
        for (int e = 0; e < NEXP; ++e) atomicAdd(&sprob[e], p[e] * inv);
        int pos = atomicAdd(&ec[am], 1);
        elist[am*TTOT + pos] = t;
    }
    __syncthreads();
    if (tid < NEXP) {
        atomicAdd(&counts[tid], scnt[tid]);
        atomicAdd(&rprob[tid], sprob[tid]);
    }
}

// ---------------- weight pack kernels: fp32 -> bf16 MFMA-B-fragment order --------
__global__ void pack_w1(const float* __restrict__ w1l, unsigned short* __restrict__ w1p) {
    int tid = blockIdx.x*256 + threadIdx.x;   // 327680 total
    int l = tid & 63, kk = (tid >> 6) & 7, nt = (tid >> 9) & 63, e = tid >> 15;
    const float* src = w1l + (size_t)e*262144 + (size_t)(kk*32 + (l>>4)*8)*DFFN + nt*16 + (l&15);
    unsigned short o[8];
    #pragma unroll
    for (int j = 0; j < 8; ++j) o[j] = f2bf(src[(size_t)j*DFFN]);
    ulonglong2* dst = (ulonglong2*)(w1p + (size_t)tid*8);
    *dst = *(ulonglong2*)o;
}

__global__ void pack_w2(const float* __restrict__ w2l, unsigned short* __restrict__ w2p) {
    int tid = blockIdx.x*256 + threadIdx.x;   // 327680 total
    int l = tid & 63, kk = (tid >> 6) & 31, nt = (tid >> 11) & 15, e = tid >> 15;
    const float* src = w2l + (size_t)e*262144 + (size_t)(kk*32 + (l>>4)*8)*DN + nt*16 + (l&15);
    unsigned short o[8];
    #pragma unroll
    for (int j = 0; j < 8; ++j) o[j] = f2bf(src[(size_t)j*DN]);
    ulonglong2* dst = (ulonglong2*)(w2p + (size_t)tid*8);
    *dst = *(ulonglong2*)o;
}

// ---------------- MoE: bf16 MFMA grouped expert FFN + residual LN -------------
#define TM 16
__global__ __launch_bounds__(256)
void moe_kernel(float* __restrict__ z, const int* __restrict__ elist,
                const int* __restrict__ ec, const float* __restrict__ rmaxv,
                const unsigned short* __restrict__ w1p, const float* __restrict__ b1,
                const unsigned short* __restrict__ w2p, const float* __restrict__ b2,
                const float* __restrict__ g, const float* __restrict__ bb) {
    int e = blockIdx.y;
    int cnt = ec[e];
    int base = blockIdx.x * TM;
    if (base >= cnt) return;
    int n = min(TM, cnt - base);

    __shared__ __align__(16) unsigned short ts[16*264];
    __shared__ __align__(16) unsigned short hbuf[16*1032];
    __shared__ __align__(16) float ybuf[16*260];
    __shared__ int toks[16];
    __shared__ float rm[16];

    int tid = threadIdx.x;
    int w = tid >> 6, l = tid & 63;
    if (tid < 16) {
        int tt = (tid < n) ? elist[e*TTOT + base + tid] : 0;
        toks[tid] = tt;
        rm[tid] = rmaxv[tt];
    }
    __syncthreads();
    #pragma unroll
    for (int m = 0; m < 16; ++m)
        ts[m*264 + tid] = f2bf(z[(size_t)toks[m]*DN + tid]);
    __syncthreads();

    const bf16x8* w1v = (const bf16x8*)w1p;
    const float* b1e = b1 + e*DFFN;
    f32x4 acc[16];
    #pragma unroll
    for (int i = 0; i < 16; ++i) acc[i] = (f32x4){0.f,0.f,0.f,0.f};
    #pragma unroll
    for (int kk = 0; kk < 8; ++kk) {
        bf16x8 a = *(const bf16x8*)(ts + (l&15)*264 + kk*32 + (l>>4)*8);
        const bf16x8* wbp = w1v + (((size_t)e*64 + w*16)*8 + kk)*64 + l;
        #pragma unroll
        for (int nt2 = 0; nt2 < 16; ++nt2)
            acc[nt2] = __builtin_amdgcn_mfma_f32_16x16x32_bf16(a, wbp[nt2*512], acc[nt2], 0, 0, 0);
    }
    #pragma unroll
    for (int nt2 = 0; nt2 < 16; ++nt2) {
        int col = w*256 + nt2*16 + (l&15);
        float bv = b1e[col];
        #pragma unroll
        for (int r = 0; r < 4; ++r) {
            int row = (l>>4)*4 + r;
            hbuf[row*1032 + col] = f2bf(fmaxf(acc[nt2][r] + bv, 0.f));
        }
    }
    __syncthreads();

    const bf16x8* w2v = (const bf16x8*)w2p;
    const float* b2e = b2 + e*DN;
    f32x4 acc2[4];
    #pragma unroll
    for (int i = 0; i < 4; ++i) acc2[i] = (f32x4){0.f,0.f,0.f,0.f};
    for (int kk = 0; kk < 32; ++kk) {
        bf16x8 a = *(const bf16x8*)(hbuf + (l&15)*1032 + kk*32 + (l>>4)*8);
        const bf16x8* wbp = w2v + (((size_t)e*16 + w*4)*32 + kk)*64 + l;
        #pragma unroll
        for (int nt2 = 0; nt2 < 4; ++nt2)
            acc2[nt2] = __builtin_amdgcn_mfma_f32_16x16x32_bf16(a, wbp[nt2*2048], acc2[nt2], 0, 0, 0);
    }
    #pragma unroll
    for (int nt2 = 0; nt2 < 4; ++nt2) {
        int col = w*64 + nt2*16 + (l&15);
        float bv = b2e[col];
        #pragma unroll
        for (int r = 0; r < 4; ++r) {
            int row = (l>>4)*4 + r;
            ybuf[row*260 + col] = (acc2[nt2][r] + bv) * rm[row];
        }
    }
    __syncthreads();

    #pragma unroll
    for (int rr = 0; rr < 4; ++rr) {
        int row = w*4 + rr;
        if (row < n) {
            int t = toks[row];
            float v[4];
            #pragma unroll
            for (int c = 0; c < 4; ++c)
                v[c] = ybuf[row*260 + l + 64*c] + z[(size_t)t*DN + l + 64*c];
            float s = wave_sum(v[0]+v[1]+v[2]+v[3]);
            float mu = s * (1.0f/DN);
            float s2 = 0.f;
            #pragma unroll
            for (int c = 0; c < 4; ++c) { v[c] -= mu; s2 += v[c]*v[c]; }
            s2 = wave_sum(s2);
            float rs = rsqrtf(s2 * (1.0f/DN) + 1e-5f);
            #pragma unroll
            for (int c = 0; c < 4; ++c) {
                int col = l + 64*c;
                z[(size_t)t*DN + col] = v[c]*rs*g[col] + bb[col];
            }
        }
    }
}

// ---------------- deconv weight repack ----------------
__global__ void repack_deconv(const float* __restrict__ w, float* __restrict__ wt) {
    int idx = blockIdx.x*256 + threadIdx.x;
    int dout = idx & 255;
    int din = (idx >> 8) & 255;
    int t = idx >> 16;
    wt[idx] = w[((size_t)din*DN + dout)*4 + t];
}

// ---------------- deconv (ConvTranspose1d k=4 s=2 p=1) + bias -> u[b][w][dout] ----
__global__ void deconv_kernel(const float* __restrict__ z, const float* __restrict__ dwT,
                              const float* __restrict__ db, float* __restrict__ u) {
    int blk = blockIdx.x;
    int tile = blk & 63;
    int b = blk >> 6;
    int tid = threadIdx.x;
    int w0 = tile * 16;
    int lbase = tile*8 - 1;
    __shared__ float zst[DN][12];
    for (int i = tid; i < 10*DN; i += 256) {
        int rr = i >> 8, dd = i & 255;
        int l = lbase + rr;
        zst[dd][rr] = (l >= 0 && l < LATN) ? z[((size_t)b*LATN + l)*DN + dd] : 0.0f;
    }
    if (tid < DN) { zst[tid][10] = 0.f; zst[tid][11] = 0.f; }
    __syncthreads();
    float acc[16];
    #pragma unroll
    for (int i = 0; i < 16; ++i) acc[i] = 0.f;
    const float* wp0 = &dwT[0*65536 + tid];
    const float* wp1 = &dwT[1*65536 + tid];
    const float* wp2 = &dwT[2*65536 + tid];
    const float* wp3 = &dwT[3*65536 + tid];
    for (int din = 0; din < DN; ++din) {
        float4 A  = *(const float4*)&zst[din][0];
        float4 Bq = *(const float4*)&zst[din][4];
        float4 Cq = *(const float4*)&zst[din][8];
        float rr[10] = {A.x,A.y,A.z,A.w,Bq.x,Bq.y,Bq.z,Bq.w,Cq.x,Cq.y};
        float wv0 = wp0[din*DN];
        float wv1 = wp1[din*DN];
        float wv2 = wp2[din*DN];
        float wv3 = wp3[din*DN];
        #pragma unroll
        for (int jj = 0; jj < 8; ++jj) {
            acc[1+2*jj] += rr[jj+2]*wv0 + rr[jj+1]*wv2;
            acc[2*jj]   += rr[jj+1]*wv1 + rr[jj]*wv3;
        }
    }
    float bv = db[tid];
    #pragma unroll
    for (int wi = 0; wi < 16; ++wi)
        u[((size_t)b*1024 + w0 + wi)*DN + tid] = acc[wi] + bv;
}

// ---------------- head: lin1 + tanh + lin2 ----------------
__global__ void head_kernel(const float* __restrict__ u, const float* __restrict__ w1,
                            const float* __restrict__ b1, const float* __restrict__ w2,
                            const float* __restrict__ b2, float* __restrict__ out) {
    __shared__ float us[8][DN];
    __shared__ float v1[8][128];
    int r0 = blockIdx.x * 8;
    int tid = threadIdx.x;   // 128 threads
    for (int i = tid; i < 8*DN; i += 128)
        us[i >> 8][i & 255] = u[(size_t)r0*DN + i];
    __syncthreads();
    const float4* wr = (const float4*)&w1[tid*DN];
    float acc[8] = {0,0,0,0,0,0,0,0};
    for (int d4 = 0; d4 < 64; ++d4) {
        float4 w = wr[d4];
        #pragma unroll
        for (int m = 0; m < 8; ++m)
            acc[m] += dot4(w, *(const float4*)&us[m][d4*4]);
    }
    float bv = b1[tid];
    #pragma unroll
    for (int m = 0; m < 8; ++m) v1[m][tid] = tanhf(acc[m] + bv);
    __syncthreads();
    if (tid < 8) {
        float s = b2[0];
        for (int j = 0; j < 128; ++j) s += v1[tid][j] * w2[j];
        out[r0 + tid] = s;
    }
}

// ---------------- loss ----------------
__global__ void loss_kernel(const float* __restrict__ counts, const float* __restrict__ rprob,
                            float* __restrict__ out) {
    if (threadIdx.x == 0) {
        float s = 0;
        for (int i = 0; i < 20; ++i) s += counts[i] * rprob[i];
        out[8192] = 10.0f * s / (4096.0f * 4096.0f);
    }
}

extern "C" void kernel_launch(void* const* d_in, const int* in_sizes, int n_in,
                              void* d_out, int out_size, void* d_ws, size_t ws_size,
                              hipStream_t stream) {
    const float* x        = (const float*)d_in[0];
    const float* conv_w   = (const float*)d_in[1];
    const float* conv_b   = (const float*)d_in[2];
    const float* pe       = (const float*)d_in[3];
    const float* ln0_g    = (const float*)d_in[4];
    const float* ln0_b    = (const float*)d_in[5];
    const float* wq       = (const float*)d_in[6];
    const float* bq       = (const float*)d_in[7];
    const float* wk       = (const float*)d_in[8];
    const float* bk       = (const float*)d_in[9];
    const float* wv       = (const float*)d_in[10];
    const float* bv       = (const float*)d_in[11];
    const float* wo       = (const float*)d_in[12];
    const float* bo       = (const float*)d_in[13];
    const float* ln1_g    = (const float*)d_in[14];
    const float* ln1_b    = (const float*)d_in[15];
    const float* ln2_g    = (const float*)d_in[16];
    const float* ln2_b    = (const float*)d_in[17];
    const float* router_w = (const float*)d_in[18];
    const float* router_b = (const float*)d_in[19];
    const float* e_w1     = (const float*)d_in[20];
    const float* e_b1     = (const float*)d_in[21];
    const float* e_w2     = (const float*)d_in[22];
    const float* e_b2     = (const float*)d_in[23];
    const float* deconv_w = (const float*)d_in[24];
    const float* deconv_b = (const float*)d_in[25];
    const float* lin1_w   = (const float*)d_in[26];
    const float* lin1_b   = (const float*)d_in[27];
    const float* lin2_w   = (const float*)d_in[28];
    const float* lin2_b   = (const float*)d_in[29];

    float* ws = (float*)d_ws;
    const size_t M = 1048576;
    float* z    = ws;
    float* q    = ws + 1*M;
    float* k    = ws + 2*M;
    float* v    = ws + 3*M;
    float* a    = ws + 4*M;
    float* y    = ws + 5*M;
    float* rmax = ws + 6*M;
    float* counts = rmax + 4096;
    float* rprob  = counts + 32;
    int* ec     = (int*)(rprob + 32);
    int* elist  = ec + 32;                    // 2*10*4096
    unsigned short* wproj = (unsigned short*)(ws + 6*M + 98304);  // 8 x 65536 bf16 (1 MB)
    unsigned short* w1p = (unsigned short*)(ws + 1*M);  // per-layer packed over q+k (dead)
    unsigned short* w2p = (unsigned short*)(ws + 3*M);  // per-layer packed over v+a (dead)
    float* u    = ws + 1*M;
    float* dwT  = ws + 3*M;
    float* out  = (float*)d_out;

    zero_kernel<<<1, 64, 0, stream>>>(counts, rprob, ec);
    {
        dim3 pg(32, 8);
        pack_proj<<<pg, 256, 0, stream>>>(wq, wk, wv, wo, wproj);
    }
    tokenizer_kernel<<<TTOT, 256, 0, stream>>>(x, conv_w, conv_b, pe, ln0_g, ln0_b, z);

    for (int l = 0; l < 2; ++l) {
        const unsigned short* wpl = wproj + (size_t)l*4*65536;
        dim3 qkvg(64, 3);
        proj_qkv<<<qkvg, 256, 0, stream>>>(z, wpl, bq + l*256, bk + l*256, bv + l*256,
                                           q, k, v);
        attn_kernel<<<512, 256, 0, stream>>>(q, k, v, a);
        proj_one<<<64, 256, 0, stream>>>(a, wpl + 3*65536, bo + l*256, y);
        ln_residual<<<TTOT, 256, 0, stream>>>(z, y, ln1_g + l*256, ln1_b + l*256);
        router_kernel<<<TTOT/64, 256, 0, stream>>>(z, router_w + l*2560, router_b + l*10,
                                                   rmax, counts + l*10, rprob + l*10,
                                                   ec + l*10, elist + l*10*TTOT);
        pack_w1<<<1280, 256, 0, stream>>>(e_w1 + (size_t)l*2621440, w1p);
        pack_w2<<<1280, 256, 0, stream>>>(e_w2 + (size_t)l*2621440, w2p);
        dim3 mg(TTOT/TM, NEXP);
        moe_kernel<<<mg, 256, 0, stream>>>(z, elist + l*10*TTOT, ec + l*10, rmax,
                                           w1p, e_b1 + l*10240,
                                           w2p, e_b2 + l*2560,
                                           ln2_g + l*256, ln2_b + l*256);
    }

    repack_deconv<<<1024, 256, 0, stream>>>(deconv_w, dwT);
    deconv_kernel<<<512, 256, 0, stream>>>(z, dwT, deconv_b, u);
    head_kernel<<<1024, 128, 0, stream>>>(u, lin1_w, lin1_b, lin2_w, lin2_b, out);
    loss_kernel<<<1, 64, 0, stream>>>(counts, rprob, out);
}

// Round 6
// 369.060 us; speedup vs baseline: 5.9136x; 1.1876x over previous
//
#include <hip/hip_runtime.h>
#include <math.h>

#define LATN 512
#define DN 256
#define DKN 128
#define TTOT 4096   // B*LAT
#define NEXP 10
#define DFFN 1024

using bf16x8 = __attribute__((ext_vector_type(8))) short;
using f32x4  = __attribute__((ext_vector_type(4))) float;

__device__ __forceinline__ float dot4(float4 a, float4 b) {
    return a.x*b.x + a.y*b.y + a.z*b.z + a.w*b.w;
}

__device__ __forceinline__ unsigned short f2bf(float f) {
    union { float f; unsigned int u; } v; v.f = f;
    unsigned int u = v.u + 0x7FFFu + ((v.u >> 16) & 1u);
    return (unsigned short)(u >> 16);
}

// ---------------- reduction helpers ----------------
__device__ __forceinline__ float block_reduce_sum(float v, float* red) {
    #pragma unroll
    for (int off = 32; off; off >>= 1) v += __shfl_down(v, off, 64);
    int lane = threadIdx.x & 63, wid = threadIdx.x >> 6;
    if (lane == 0) red[wid] = v;
    __syncthreads();
    float r = red[0] + red[1] + red[2] + red[3];
    __syncthreads();
    return r;
}

__device__ __forceinline__ float wave_sum(float x) {
    #pragma unroll
    for (int off = 32; off; off >>= 1) x += __shfl_xor(x, off, 64);
    return x;
}

// ---------------- zero init ----------------
__global__ void zero_kernel(float* counts, float* rprob, int* ec) {
    int i = threadIdx.x;
    if (i < 20) { counts[i] = 0.f; rprob[i] = 0.f; ec[i] = 0; }
}

// ---------------- tokenizer: conv5 + LPpool2 + PE + LN ----------------
__global__ void tokenizer_kernel(const float* __restrict__ x, const float* __restrict__ cw,
                                 const float* __restrict__ cb, const float* __restrict__ pe,
                                 const float* __restrict__ g, const float* __restrict__ bb,
                                 float* __restrict__ z) {
    int blk = blockIdx.x;
    int l = blk & (LATN - 1);
    int b = blk >> 9;
    int d = threadIdx.x;
    __shared__ float red[8];
    const float* xb = x + (size_t)b * 1024;
    float w0 = cw[d*5+0], w1 = cw[d*5+1], w2 = cw[d*5+2], w3 = cw[d*5+3], w4 = cw[d*5+4];
    float bv = cb[d];
    int p0 = 2 * l;
    auto xc = [&](int i) { return xb[min(max(i, 0), 1023)]; };
    float h0 = bv + w0*xc(p0-2) + w1*xc(p0-1) + w2*xc(p0)   + w3*xc(p0+1) + w4*xc(p0+2);
    float h1 = bv + w0*xc(p0-1) + w1*xc(p0)   + w2*xc(p0+1) + w3*xc(p0+2) + w4*xc(p0+3);
    float pool = sqrtf(h0*h0 + h1*h1);
    float val = pool + pe[l*DN + d];
    float s = block_reduce_sum(val, red);
    float mu = s * (1.0f/DN);
    float dv = val - mu;
    float s2 = block_reduce_sum(dv*dv, red);
    float r = rsqrtf(s2 * (1.0f/DN) + 1e-5f);
    z[((size_t)b*LATN + l)*DN + d] = dv*r*g[d] + bb[d];
}

// ---------------- pack projection weights: fp32 [out,in] -> bf16 B-frag ----------
__global__ void pack_proj(const float* __restrict__ wq, const float* __restrict__ wk,
                          const float* __restrict__ wv, const float* __restrict__ wo,
                          unsigned short* __restrict__ wp) {
    int mat = blockIdx.y;              // 0..7 : layer*4 + {q,k,v,o}
    int l0 = mat >> 2, which = mat & 3;
    const float* base = (which == 0) ? wq : (which == 1) ? wk : (which == 2) ? wv : wo;
    const float* W = base + l0*65536;
    int tid = blockIdx.x*256 + threadIdx.x;   // 0..8191
    int l = tid & 63, kk = (tid >> 6) & 7, nt = tid >> 9;
    const float* src = W + (size_t)(nt*16 + (l&15))*DN + kk*32 + (l>>4)*8;
    unsigned short o[8];
    #pragma unroll
    for (int j = 0; j < 8; ++j) o[j] = f2bf(src[j]);
    *(ulonglong2*)(wp + (size_t)mat*65536 + (size_t)tid*8) = *(ulonglong2*)o;
}

// ---------------- MFMA projection GEMM: out = A @ W^T + b, 64 tokens/block ------
__device__ __forceinline__ void proj_body(const float* __restrict__ A,
                                          const unsigned short* __restrict__ wpm,
                                          const float* __restrict__ bias,
                                          float* __restrict__ out, int t0,
                                          unsigned short* ts) {
    int tid = threadIdx.x;
    #pragma unroll
    for (int i = 0; i < 16; ++i) {
        int f4 = i*256 + tid;
        int row = f4 >> 6, c4 = f4 & 63;
        float4 a = *(const float4*)&A[(size_t)(t0+row)*DN + c4*4];
        ushort4 o = { f2bf(a.x), f2bf(a.y), f2bf(a.z), f2bf(a.w) };
        *(ushort4*)&ts[row*264 + c4*4] = o;
    }
    __syncthreads();
    int w = tid >> 6, l = tid & 63;
    f32x4 acc[4][4];
    #pragma unroll
    for (int m = 0; m < 4; ++m)
        #pragma unroll
        for (int n = 0; n < 4; ++n) acc[m][n] = (f32x4){0.f,0.f,0.f,0.f};
    const bf16x8* wv = (const bf16x8*)wpm;
    #pragma unroll
    for (int kk = 0; kk < 8; ++kk) {
        bf16x8 af[4];
        #pragma unroll
        for (int m = 0; m < 4; ++m)
            af[m] = *(const bf16x8*)&ts[(m*16 + (l&15))*264 + kk*32 + (l>>4)*8];
        #pragma unroll
        for (int n = 0; n < 4; ++n) {
            bf16x8 bf = wv[((w*4 + n)*8 + kk)*64 + l];
            #pragma unroll
            for (int m = 0; m < 4; ++m)
                acc[m][n] = __builtin_amdgcn_mfma_f32_16x16x32_bf16(af[m], bf, acc[m][n], 0, 0, 0);
        }
    }
    #pragma unroll
    for (int n = 0; n < 4; ++n) {
        int col = w*64 + n*16 + (l&15);
        float bv2 = bias[col];
        #pragma unroll
        for (int m = 0; m < 4; ++m) {
            #pragma unroll
            for (int r = 0; r < 4; ++r) {
                int row = t0 + m*16 + (l>>4)*4 + r;
                out[(size_t)row*DN + col] = acc[m][n][r] + bv2;
            }
        }
    }
}

__global__ __launch_bounds__(256)
void proj_qkv(const float* __restrict__ z, const unsigned short* __restrict__ wp,
              const float* __restrict__ bq, const float* __restrict__ bk,
              const float* __restrict__ bv,
              float* __restrict__ q, float* __restrict__ k, float* __restrict__ v) {
    __shared__ unsigned short ts[64*264];
    int mat = blockIdx.y;
    const float* bias = (mat == 0) ? bq : (mat == 1) ? bk : bv;
    float* out = (mat == 0) ? q : (mat == 1) ? k : v;
    proj_body(z, wp + (size_t)mat*65536, bias, out, blockIdx.x*64, ts);
}

__global__ __launch_bounds__(256)
void proj_one(const float* __restrict__ A, const unsigned short* __restrict__ wpm,
              const float* __restrict__ bias, float* __restrict__ out) {
    __shared__ unsigned short ts[64*264];
    proj_body(A, wpm, bias, out, blockIdx.x*64, ts);
}

// ---------------- attention: 16 q-rows/block, reg-cached Q, XCD swizzle --------
__global__ __launch_bounds__(256)
void attn_kernel(const float* __restrict__ q, const float* __restrict__ k,
                 const float* __restrict__ v, float* __restrict__ a) {
    int blk = blockIdx.x;
    int xcd = blk & 7, j = blk >> 3;
    int bh = xcd*2 + (j & 1);
    int tile = j >> 1;
    int b = bh >> 1, h = bh & 1;
    int q0 = tile * 16;
    int tid = threadIdx.x;

    __shared__ float qs[16][132];
    __shared__ float ps[16][520];
    __shared__ float pq[4][16][130];

    for (int i = tid; i < 512; i += 256) {
        int qi = i >> 5, d4 = i & 31;
        *(float4*)&qs[qi][d4*4] =
            *(const float4*)&q[((size_t)(b*LATN + q0 + qi))*DN + h*DKN + d4*4];
    }
    __syncthreads();

    const float scale = 0.08838834764831844f;  // 1/sqrt(128)
    {
        const float* k0p = &k[((size_t)(b*LATN + tid))*DN + h*DKN];
        const float* k1p = k0p + 256*DN;
        float acc0[16], acc1[16];
        #pragma unroll
        for (int i = 0; i < 16; ++i) { acc0[i] = 0.f; acc1[i] = 0.f; }
        for (int dc = 0; dc < 32; ++dc) {
            float4 kv0 = *(const float4*)&k0p[dc*4];
            float4 kv1 = *(const float4*)&k1p[dc*4];
            #pragma unroll
            for (int qq = 0; qq < 16; ++qq) {
                float4 qv = *(const float4*)&qs[qq][dc*4];
                acc0[qq] += dot4(kv0, qv);
                acc1[qq] += dot4(kv1, qv);
            }
        }
        #pragma unroll
        for (int qq = 0; qq < 16; ++qq) {
            ps[qq][tid]     = acc0[qq]*scale;
            ps[qq][tid+256] = acc1[qq]*scale;
        }
    }
    __syncthreads();

    {
        int w = tid >> 6, lane = tid & 63;
        for (int r = w*4; r < w*4 + 4; ++r) {
            float e[8]; float mx = -1e30f;
            #pragma unroll
            for (int i2 = 0; i2 < 8; ++i2) { e[i2] = ps[r][lane + 64*i2]; mx = fmaxf(mx, e[i2]); }
            #pragma unroll
            for (int off = 32; off; off >>= 1) mx = fmaxf(mx, __shfl_xor(mx, off, 64));
            float s = 0.f;
            #pragma unroll
            for (int i2 = 0; i2 < 8; ++i2) { e[i2] = __expf(e[i2] - mx); s += e[i2]; }
            #pragma unroll
            for (int off = 32; off; off >>= 1) s += __shfl_xor(s, off, 64);
            float inv = 1.0f / s;
            #pragma unroll
            for (int i2 = 0; i2 < 8; ++i2) ps[r][lane + 64*i2] = e[i2]*inv;
        }
    }
    __syncthreads();

    {
        int kq = tid >> 6, d2 = (tid & 63)*2;
        float accx[16], accy[16];
        #pragma unroll
        for (int i = 0; i < 16; ++i) { accx[i] = 0.f; accy[i] = 0.f; }
        const float* vbase = &v[((size_t)(b*LATN + kq*128))*DN + h*DKN + d2];
        for (int k4 = 0; k4 < 32; ++k4) {
            float4 pf[16];
            #pragma unroll
            for (int qq = 0; qq < 16; ++qq) pf[qq] = *(const float4*)&ps[qq][kq*128 + k4*4];
            #pragma unroll
            for (int jj = 0; jj < 4; ++jj) {
                float2 vv = *(const float2*)&vbase[(size_t)(k4*4 + jj)*DN];
                #pragma unroll
                for (int qq = 0; qq < 16; ++qq) {
                    float p = ((const float*)&pf[qq])[jj];
                    accx[qq] += p*vv.x; accy[qq] += p*vv.y;
                }
            }
        }
        #pragma unroll
        for (int qq = 0; qq < 16; ++qq) {
            pq[kq][qq][d2] = accx[qq]; pq[kq][qq][d2+1] = accy[qq];
        }
    }
    __syncthreads();

    for (int i = tid; i < 2048; i += 256) {
        int qq = i >> 7, d = i & 127;
        float s = pq[0][qq][d] + pq[1][qq][d] + pq[2][qq][d] + pq[3][qq][d];
        a[((size_t)(b*LATN + q0 + qq))*DN + h*DKN + d] = s;
    }
}

// ---------------- residual + LN (in-place on z) ----------------
__global__ void ln_residual(float* __restrict__ z, const float* __restrict__ y,
                            const float* __restrict__ g, const float* __restrict__ b) {
    int t = blockIdx.x, tid = threadIdx.x;
    __shared__ float red[8];
    float val = z[(size_t)t*DN + tid] + y[(size_t)t*DN + tid];
    float s = block_reduce_sum(val, red);
    float mu = s * (1.0f/DN);
    float dv = val - mu;
    float s2 = block_reduce_sum(dv*dv, red);
    float r = rsqrtf(s2 * (1.0f/DN) + 1e-5f);
    z[(size_t)t*DN + tid] = dv*r*g[tid] + b[tid];
}

// ---------------- router: 64 tokens/block, 4 lanes/token ----------------
__global__ void router_kernel(const float* __restrict__ z, const float* __restrict__ rw,
                              const float* __restrict__ rb, float* __restrict__ rmaxv,
                              float* __restrict__ counts, float* __restrict__ rprob,
                              int* __restrict__ ec, int* __restrict__ elist) {
    __shared__ float rws[NEXP*DN];
    __shared__ float scnt[NEXP], sprob[NEXP];
    int tid = threadIdx.x;
    for (int i = tid; i < NEXP*DN; i += 256) rws[i] = rw[i];
    if (tid < NEXP) { scnt[tid] = 0.f; sprob[tid] = 0.f; }
    __syncthreads();
    int g = tid >> 2, j = tid & 3;
    int t = blockIdx.x * 64 + g;
    const float4* z4 = (const float4*)&z[(size_t)t*DN + j*64];
    float acc[NEXP];
    #pragma unroll
    for (int e = 0; e < NEXP; ++e) acc[e] = 0.f;
    #pragma unroll 4
    for (int k4 = 0; k4 < 16; ++k4) {
        float4 zv = z4[k4];
        #pragma unroll
        for (int e = 0; e < NEXP; ++e)
            acc[e] += dot4(zv, *(const float4*)&rws[e*DN + j*64 + k4*4]);
    }
    #pragma unroll
    for (int e = 0; e < NEXP; ++e) {
        acc[e] += __shfl_xor(acc[e], 1, 64);
        acc[e] += __shfl_xor(acc[e], 2, 64);
    }
    if (j == 0) {
        float lg[NEXP];
        float m = acc[0] + rb[0]; int am = 0;
        lg[0] = m;
        #pragma unroll
        for (int e = 1; e < NEXP; ++e) {
            lg[e] = acc[e] + rb[e];
            if (lg[e] > m) { m = lg[e]; am = e; }
        }
        float p[NEXP], s = 0.f;
        #pragma unroll
        for (int e = 0; e < NEXP; ++e) { p[e] = expf(lg[e] - m); s += p[e]; }
        float inv = 1.0f / s;
        rmaxv[t] = p[am] * inv;
        atomicAdd(&scnt[am], 1.0f);
        #pragma unroll
        for (int e = 0; e < NEXP; ++e) atomicAdd(&sprob[e], p[e] * inv);
        int pos = atomicAdd(&ec[am], 1);
        elist[am*TTOT + pos] = t;
    }
    __syncthreads();
    if (tid < NEXP) {
        atomicAdd(&counts[tid], scnt[tid]);
        atomicAdd(&rprob[tid], sprob[tid]);
    }
}

// ---------------- weight pack kernels: fp32 -> bf16 MFMA-B-fragment order --------
__global__ void pack_w1(const float* __restrict__ w1l, unsigned short* __restrict__ w1p) {
    int tid = blockIdx.x*256 + threadIdx.x;   // 327680 total
    int l = tid & 63, kk = (tid >> 6) & 7, nt = (tid >> 9) & 63, e = tid >> 15;
    const float* src = w1l + (size_t)e*262144 + (size_t)(kk*32 + (l>>4)*8)*DFFN + nt*16 + (l&15);
    unsigned short o[8];
    #pragma unroll
    for (int j = 0; j < 8; ++j) o[j] = f2bf(src[(size_t)j*DFFN]);
    ulonglong2* dst = (ulonglong2*)(w1p + (size_t)tid*8);
    *dst = *(ulonglong2*)o;
}

__global__ void pack_w2(const float* __restrict__ w2l, unsigned short* __restrict__ w2p) {
    int tid = blockIdx.x*256 + threadIdx.x;   // 327680 total
    int l = tid & 63, kk = (tid >> 6) & 31, nt = (tid >> 11) & 15, e = tid >> 15;
    const float* src = w2l + (size_t)e*262144 + (size_t)(kk*32 + (l>>4)*8)*DN + nt*16 + (l&15);
    unsigned short o[8];
    #pragma unroll
    for (int j = 0; j < 8; ++j) o[j] = f2bf(src[(size_t)j*DN]);
    ulonglong2* dst = (ulonglong2*)(w2p + (size_t)tid*8);
    *dst = *(ulonglong2*)o;
}

// ---------------- MoE: bf16 MFMA grouped expert FFN + residual LN -------------
#define TM 16
__global__ __launch_bounds__(256)
void moe_kernel(float* __restrict__ z, const int* __restrict__ elist,
                const int* __restrict__ ec, const float* __restrict__ rmaxv,
                const unsigned short* __restrict__ w1p, const float* __restrict__ b1,
                const unsigned short* __restrict__ w2p, const float* __restrict__ b2,
                const float* __restrict__ g, const float* __restrict__ bb) {
    int e = blockIdx.y;
    int cnt = ec[e];
    int base = blockIdx.x * TM;
    if (base >= cnt) return;
    int n = min(TM, cnt - base);

    __shared__ __align__(16) unsigned short ts[16*264];
    __shared__ __align__(16) unsigned short hbuf[16*1032];
    __shared__ __align__(16) float ybuf[16*260];
    __shared__ int toks[16];
    __shared__ float rm[16];

    int tid = threadIdx.x;
    int w = tid >> 6, l = tid & 63;
    if (tid < 16) {
        int tt = (tid < n) ? elist[e*TTOT + base + tid] : 0;
        toks[tid] = tt;
        rm[tid] = rmaxv[tt];
    }
    __syncthreads();
    #pragma unroll
    for (int m = 0; m < 16; ++m)
        ts[m*264 + tid] = f2bf(z[(size_t)toks[m]*DN + tid]);
    __syncthreads();

    const bf16x8* w1v = (const bf16x8*)w1p;
    const float* b1e = b1 + e*DFFN;
    f32x4 acc[16];
    #pragma unroll
    for (int i = 0; i < 16; ++i) acc[i] = (f32x4){0.f,0.f,0.f,0.f};
    #pragma unroll
    for (int kk = 0; kk < 8; ++kk) {
        bf16x8 a = *(const bf16x8*)(ts + (l&15)*264 + kk*32 + (l>>4)*8);
        const bf16x8* wbp = w1v + (((size_t)e*64 + w*16)*8 + kk)*64 + l;
        #pragma unroll
        for (int nt2 = 0; nt2 < 16; ++nt2)
            acc[nt2] = __builtin_amdgcn_mfma_f32_16x16x32_bf16(a, wbp[nt2*512], acc[nt2], 0, 0, 0);
    }
    #pragma unroll
    for (int nt2 = 0; nt2 < 16; ++nt2) {
        int col = w*256 + nt2*16 + (l&15);
        float bv = b1e[col];
        #pragma unroll
        for (int r = 0; r < 4; ++r) {
            int row = (l>>4)*4 + r;
            hbuf[row*1032 + col] = f2bf(fmaxf(acc[nt2][r] + bv, 0.f));
        }
    }
    __syncthreads();

    const bf16x8* w2v = (const bf16x8*)w2p;
    const float* b2e = b2 + e*DN;
    f32x4 acc2[4];
    #pragma unroll
    for (int i = 0; i < 4; ++i) acc2[i] = (f32x4){0.f,0.f,0.f,0.f};
    for (int kk = 0; kk < 32; ++kk) {
        bf16x8 a = *(const bf16x8*)(hbuf + (l&15)*1032 + kk*32 + (l>>4)*8);
        const bf16x8* wbp = w2v + (((size_t)e*16 + w*4)*32 + kk)*64 + l;
        #pragma unroll
        for (int nt2 = 0; nt2 < 4; ++nt2)
            acc2[nt2] = __builtin_amdgcn_mfma_f32_16x16x32_bf16(a, wbp[nt2*2048], acc2[nt2], 0, 0, 0);
    }
    #pragma unroll
    for (int nt2 = 0; nt2 < 4; ++nt2) {
        int col = w*64 + nt2*16 + (l&15);
        float bv = b2e[col];
        #pragma unroll
        for (int r = 0; r < 4; ++r) {
            int row = (l>>4)*4 + r;
            ybuf[row*260 + col] = (acc2[nt2][r] + bv) * rm[row];
        }
    }
    __syncthreads();

    #pragma unroll
    for (int rr = 0; rr < 4; ++rr) {
        int row = w*4 + rr;
        if (row < n) {
            int t = toks[row];
            float v[4];
            #pragma unroll
            for (int c = 0; c < 4; ++c)
                v[c] = ybuf[row*260 + l + 64*c] + z[(size_t)t*DN + l + 64*c];
            float s = wave_sum(v[0]+v[1]+v[2]+v[3]);
            float mu = s * (1.0f/DN);
            float s2 = 0.f;
            #pragma unroll
            for (int c = 0; c < 4; ++c) { v[c] -= mu; s2 += v[c]*v[c]; }
            s2 = wave_sum(s2);
            float rs = rsqrtf(s2 * (1.0f/DN) + 1e-5f);
            #pragma unroll
            for (int c = 0; c < 4; ++c) {
                int col = l + 64*c;
                z[(size_t)t*DN + col] = v[c]*rs*g[col] + bb[col];
            }
        }
    }
}

// ---------------- pack deconv taps -> bf16 B-frag: tap t, K=din(256), N=dout(256)
// wdp[tap(4)][nt(16)][kk(8)][lane(64)][j(8)] = deconv_w[din][dout][tap]
__global__ void pack_deconv_mfma(const float* __restrict__ w, unsigned short* __restrict__ wdp) {
    int tid = blockIdx.x*256 + threadIdx.x;   // 32768
    int l = tid & 63, kk = (tid >> 6) & 7, nt = (tid >> 9) & 15, tap = tid >> 13;
    int dout = nt*16 + (l&15);
    int din0 = kk*32 + (l>>4)*8;
    unsigned short o[8];
    #pragma unroll
    for (int j = 0; j < 8; ++j)
        o[j] = f2bf(w[((size_t)(din0 + j)*DN + dout)*4 + tap]);
    *(ulonglong2*)(wdp + (size_t)tid*8) = *(ulonglong2*)o;
}

// wl1[nt(8)][kk(8)][lane(64)][j(8)] = lin1_w[nt*16+(l&15)][kk*32+(l>>4)*8+j]
__global__ void pack_lin1(const float* __restrict__ w, unsigned short* __restrict__ wl1) {
    int tid = blockIdx.x*256 + threadIdx.x;   // 4096
    int l = tid & 63, kk = (tid >> 6) & 7, nt = tid >> 9;
    const float* src = w + (size_t)(nt*16 + (l&15))*DN + kk*32 + (l>>4)*8;
    unsigned short o[8];
    #pragma unroll
    for (int j = 0; j < 8; ++j) o[j] = f2bf(src[j]);
    *(ulonglong2*)(wl1 + (size_t)tid*8) = *(ulonglong2*)o;
}

// ---------------- deconv as MFMA GEMM: u[2l]=z[l]w1+z[l-1]w3; u[2l+1]=z[l+1]w0+z[l]w2
__global__ __launch_bounds__(256)
void deconv_mfma(const float* __restrict__ z, const unsigned short* __restrict__ wdp,
                 const float* __restrict__ db, float* __restrict__ u) {
    int blk = blockIdx.x;
    int b = blk >> 4, lt = blk & 15;
    int l0 = lt * 32;
    __shared__ __align__(16) unsigned short zs[34*264];
    int tid = threadIdx.x;
    #pragma unroll
    for (int i = 0; i < 9; ++i) {
        int f4 = i*256 + tid;
        if (f4 < 34*64) {
            int row = f4 >> 6, c4 = f4 & 63;
            int l = l0 - 1 + row;
            float4 a = (l >= 0 && l < LATN)
                ? *(const float4*)&z[((size_t)b*LATN + l)*DN + c4*4]
                : make_float4(0.f, 0.f, 0.f, 0.f);
            ushort4 o = { f2bf(a.x), f2bf(a.y), f2bf(a.z), f2bf(a.w) };
            *(ushort4*)&zs[row*264 + c4*4] = o;
        }
    }
    __syncthreads();
    int w = tid >> 6, l = tid & 63;
    f32x4 acce[2][4], acco[2][4];
    #pragma unroll
    for (int m = 0; m < 2; ++m)
        #pragma unroll
        for (int n = 0; n < 4; ++n) {
            acce[m][n] = (f32x4){0.f,0.f,0.f,0.f};
            acco[m][n] = (f32x4){0.f,0.f,0.f,0.f};
        }
    const bf16x8* wdv = (const bf16x8*)wdp;
    #pragma unroll
    for (int kk = 0; kk < 8; ++kk) {
        bf16x8 a0[2], a1[2], a2[2];
        #pragma unroll
        for (int m = 0; m < 2; ++m) {
            int rb = (m*16 + (l&15))*264 + kk*32 + (l>>4)*8;
            a0[m] = *(const bf16x8*)&zs[rb];          // z[l-1]
            a1[m] = *(const bf16x8*)&zs[rb + 264];    // z[l]
            a2[m] = *(const bf16x8*)&zs[rb + 528];    // z[l+1]
        }
        #pragma unroll
        for (int n = 0; n < 4; ++n) {
            int nt = w*4 + n;
            bf16x8 bt0 = wdv[((0*16 + nt)*8 + kk)*64 + l];
            bf16x8 bt1 = wdv[((1*16 + nt)*8 + kk)*64 + l];
            bf16x8 bt2 = wdv[((2*16 + nt)*8 + kk)*64 + l];
            bf16x8 bt3 = wdv[((3*16 + nt)*8 + kk)*64 + l];
            #pragma unroll
            for (int m = 0; m < 2; ++m) {
                acco[m][n] = __builtin_amdgcn_mfma_f32_16x16x32_bf16(a2[m], bt0, acco[m][n], 0, 0, 0);
                acce[m][n] = __builtin_amdgcn_mfma_f32_16x16x32_bf16(a1[m], bt1, acce[m][n], 0, 0, 0);
                acco[m][n] = __builtin_amdgcn_mfma_f32_16x16x32_bf16(a1[m], bt2, acco[m][n], 0, 0, 0);
                acce[m][n] = __builtin_amdgcn_mfma_f32_16x16x32_bf16(a0[m], bt3, acce[m][n], 0, 0, 0);
            }
        }
    }
    #pragma unroll
    for (int n = 0; n < 4; ++n) {
        int col = (w*4 + n)*16 + (l&15);
        float bv = db[col];
        #pragma unroll
        for (int m = 0; m < 2; ++m) {
            #pragma unroll
            for (int r = 0; r < 4; ++r) {
                int rt = m*16 + (l>>4)*4 + r;
                int wpos = 2*(l0 + rt);
                u[((size_t)b*1024 + wpos)*DN + col]     = acce[m][n][r] + bv;
                u[((size_t)b*1024 + wpos + 1)*DN + col] = acco[m][n][r] + bv;
            }
        }
    }
}

// ---------------- head: MFMA lin1 + tanh + lin2 fused ----------------
__global__ __launch_bounds__(256)
void head_mfma(const float* __restrict__ u, const unsigned short* __restrict__ wl1,
               const float* __restrict__ b1, const float* __restrict__ w2,
               const float* __restrict__ b2, float* __restrict__ out) {
    int r0 = blockIdx.x * 64;
    __shared__ __align__(16) unsigned short us[64*264];
    __shared__ float part[4][64];
    int tid = threadIdx.x;
    #pragma unroll
    for (int i = 0; i < 16; ++i) {
        int f4 = i*256 + tid;
        int row = f4 >> 6, c4 = f4 & 63;
        float4 a = *(const float4*)&u[(size_t)(r0 + row)*DN + c4*4];
        ushort4 o = { f2bf(a.x), f2bf(a.y), f2bf(a.z), f2bf(a.w) };
        *(ushort4*)&us[row*264 + c4*4] = o;
    }
    __syncthreads();
    int w = tid >> 6, l = tid & 63;
    f32x4 acc[4][2];
    #pragma unroll
    for (int m = 0; m < 4; ++m) { acc[m][0] = (f32x4){0.f,0.f,0.f,0.f}; acc[m][1] = (f32x4){0.f,0.f,0.f,0.f}; }
    const bf16x8* wv1 = (const bf16x8*)wl1;
    #pragma unroll
    for (int kk = 0; kk < 8; ++kk) {
        bf16x8 af[4];
        #pragma unroll
        for (int m = 0; m < 4; ++m)
            af[m] = *(const bf16x8*)&us[(m*16 + (l&15))*264 + kk*32 + (l>>4)*8];
        #pragma unroll
        for (int n = 0; n < 2; ++n) {
            bf16x8 bf = wv1[((w*2 + n)*8 + kk)*64 + l];
            #pragma unroll
            for (int m = 0; m < 4; ++m)
                acc[m][n] = __builtin_amdgcn_mfma_f32_16x16x32_bf16(af[m], bf, acc[m][n], 0, 0, 0);
        }
    }
    float pm[4][4];
    #pragma unroll
    for (int m = 0; m < 4; ++m)
        #pragma unroll
        for (int r = 0; r < 4; ++r) pm[m][r] = 0.f;
    #pragma unroll
    for (int n = 0; n < 2; ++n) {
        int col = (w*2 + n)*16 + (l&15);
        float bb1 = b1[col], ww2 = w2[col];
        #pragma unroll
        for (int m = 0; m < 4; ++m)
            #pragma unroll
            for (int r = 0; r < 4; ++r)
                pm[m][r] += tanhf(acc[m][n][r] + bb1) * ww2;
    }
    #pragma unroll
    for (int off = 1; off <= 8; off <<= 1)
        #pragma unroll
        for (int m = 0; m < 4; ++m)
            #pragma unroll
            for (int r = 0; r < 4; ++r)
                pm[m][r] += __shfl_xor(pm[m][r], off, 64);
    if ((l & 15) == 0) {
        #pragma unroll
        for (int m = 0; m < 4; ++m)
            #pragma unroll
            for (int r = 0; r < 4; ++r)
                part[w][m*16 + (l>>4)*4 + r] = pm[m][r];
    }
    __syncthreads();
    if (tid < 64)
        out[r0 + tid] = part[0][tid] + part[1][tid] + part[2][tid] + part[3][tid] + b2[0];
}

// ---------------- loss ----------------
__global__ void loss_kernel(const float* __restrict__ counts, const float* __restrict__ rprob,
                            float* __restrict__ out) {
    if (threadIdx.x == 0) {
        float s = 0;
        for (int i = 0; i < 20; ++i) s += counts[i] * rprob[i];
        out[8192] = 10.0f * s / (4096.0f * 4096.0f);
    }
}

extern "C" void kernel_launch(void* const* d_in, const int* in_sizes, int n_in,
                              void* d_out, int out_size, void* d_ws, size_t ws_size,
                              hipStream_t stream) {
    const float* x        = (const float*)d_in[0];
    const float* conv_w   = (const float*)d_in[1];
    const float* conv_b   = (const float*)d_in[2];
    const float* pe       = (const float*)d_in[3];
    const float* ln0_g    = (const float*)d_in[4];
    const float* ln0_b    = (const float*)d_in[5];
    const float* wq       = (const float*)d_in[6];
    const float* bq       = (const float*)d_in[7];
    const float* wk       = (const float*)d_in[8];
    const float* bk       = (const float*)d_in[9];
    const float* wv       = (const float*)d_in[10];
    const float* bv       = (const float*)d_in[11];
    const float* wo       = (const float*)d_in[12];
    const float* bo       = (const float*)d_in[13];
    const float* ln1_g    = (const float*)d_in[14];
    const float* ln1_b    = (const float*)d_in[15];
    const float* ln2_g    = (const float*)d_in[16];
    const float* ln2_b    = (const float*)d_in[17];
    const float* router_w = (const float*)d_in[18];
    const float* router_b = (const float*)d_in[19];
    const float* e_w1     = (const float*)d_in[20];
    const float* e_b1     = (const float*)d_in[21];
    const float* e_w2     = (const float*)d_in[22];
    const float* e_b2     = (const float*)d_in[23];
    const float* deconv_w = (const float*)d_in[24];
    const float* deconv_b = (const float*)d_in[25];
    const float* lin1_w   = (const float*)d_in[26];
    const float* lin1_b   = (const float*)d_in[27];
    const float* lin2_w   = (const float*)d_in[28];
    const float* lin2_b   = (const float*)d_in[29];

    float* ws = (float*)d_ws;
    const size_t M = 1048576;
    float* z    = ws;
    float* q    = ws + 1*M;
    float* k    = ws + 2*M;
    float* v    = ws + 3*M;
    float* a    = ws + 4*M;
    float* y    = ws + 5*M;
    float* rmax = ws + 6*M;
    float* counts = rmax + 4096;
    float* rprob  = counts + 32;
    int* ec     = (int*)(rprob + 32);
    int* elist  = ec + 32;                    // 2*10*4096
    unsigned short* wproj = (unsigned short*)(ws + 6*M + 98304);  // 8 x 65536 bf16 (1 MB)
    unsigned short* w1p = (unsigned short*)(ws + 1*M);  // per-layer packed over q+k (dead)
    unsigned short* w2p = (unsigned short*)(ws + 3*M);  // per-layer packed over v+a (dead)
    float* u    = ws + 1*M;                              // after layers: q,k dead (2M floats)
    unsigned short* wdp = (unsigned short*)(ws + 3*M);   // after layers: v dead (262144 shorts)
    unsigned short* wl1 = (unsigned short*)(ws + 3*M + 131072 + 64);  // 32768 shorts
    float* out  = (float*)d_out;

    zero_kernel<<<1, 64, 0, stream>>>(counts, rprob, ec);
    {
        dim3 pg(32, 8);
        pack_proj<<<pg, 256, 0, stream>>>(wq, wk, wv, wo, wproj);
    }
    tokenizer_kernel<<<TTOT, 256, 0, stream>>>(x, conv_w, conv_b, pe, ln0_g, ln0_b, z);

    for (int l = 0; l < 2; ++l) {
        const unsigned short* wpl = wproj + (size_t)l*4*65536;
        dim3 qkvg(64, 3);
        proj_qkv<<<qkvg, 256, 0, stream>>>(z, wpl, bq + l*256, bk + l*256, bv + l*256,
                                           q, k, v);
        attn_kernel<<<512, 256, 0, stream>>>(q, k, v, a);
        proj_one<<<64, 256, 0, stream>>>(a, wpl + 3*65536, bo + l*256, y);
        ln_residual<<<TTOT, 256, 0, stream>>>(z, y, ln1_g + l*256, ln1_b + l*256);
        router_kernel<<<TTOT/64, 256, 0, stream>>>(z, router_w + l*2560, router_b + l*10,
                                                   rmax, counts + l*10, rprob + l*10,
                                                   ec + l*10, elist + l*10*TTOT);
        pack_w1<<<1280, 256, 0, stream>>>(e_w1 + (size_t)l*2621440, w1p);
        pack_w2<<<1280, 256, 0, stream>>>(e_w2 + (size_t)l*2621440, w2p);
        dim3 mg(TTOT/TM, NEXP);
        moe_kernel<<<mg, 256, 0, stream>>>(z, elist + l*10*TTOT, ec + l*10, rmax,
                                           w1p, e_b1 + l*10240,
                                           w2p, e_b2 + l*2560,
                                           ln2_g + l*256, ln2_b + l*256);
    }

    pack_deconv_mfma<<<128, 256, 0, stream>>>(deconv_w, wdp);
    pack_lin1<<<16, 256, 0, stream>>>(lin1_w, wl1);
    deconv_mfma<<<128, 256, 0, stream>>>(z, wdp, deconv_b, u);
    head_mfma<<<128, 256, 0, stream>>>(u, wl1, lin1_b, lin2_w, lin2_b, out);
    loss_kernel<<<1, 64, 0, stream>>>(counts, rprob, out);
}

// Round 7
// 337.216 us; speedup vs baseline: 6.4720x; 1.0944x over previous
//
#include <hip/hip_runtime.h>
#include <math.h>

#define LATN 512
#define DN 256
#define DKN 128
#define TTOT 4096   // B*LAT
#define NEXP 10
#define DFFN 1024

using bf16x8 = __attribute__((ext_vector_type(8))) short;
using f32x4  = __attribute__((ext_vector_type(4))) float;

__device__ __forceinline__ float dot4(float4 a, float4 b) {
    return a.x*b.x + a.y*b.y + a.z*b.z + a.w*b.w;
}

__device__ __forceinline__ unsigned short f2bf(float f) {
    union { float f; unsigned int u; } v; v.f = f;
    unsigned int u = v.u + 0x7FFFu + ((v.u >> 16) & 1u);
    return (unsigned short)(u >> 16);
}

// ---------------- reduction helpers ----------------
__device__ __forceinline__ float block_reduce_sum(float v, float* red) {
    #pragma unroll
    for (int off = 32; off; off >>= 1) v += __shfl_down(v, off, 64);
    int lane = threadIdx.x & 63, wid = threadIdx.x >> 6;
    if (lane == 0) red[wid] = v;
    __syncthreads();
    float r = red[0] + red[1] + red[2] + red[3];
    __syncthreads();
    return r;
}

__device__ __forceinline__ float wave_sum(float x) {
    #pragma unroll
    for (int off = 32; off; off >>= 1) x += __shfl_xor(x, off, 64);
    return x;
}

// ---------------- zero init ----------------
__global__ void zero_kernel(float* counts, float* rprob, int* ec) {
    int i = threadIdx.x;
    if (i < 20) { counts[i] = 0.f; rprob[i] = 0.f; ec[i] = 0; }
}

// ---------------- tokenizer: conv5 + LPpool2 + PE + LN ----------------
__global__ void tokenizer_kernel(const float* __restrict__ x, const float* __restrict__ cw,
                                 const float* __restrict__ cb, const float* __restrict__ pe,
                                 const float* __restrict__ g, const float* __restrict__ bb,
                                 float* __restrict__ z) {
    int blk = blockIdx.x;
    int l = blk & (LATN - 1);
    int b = blk >> 9;
    int d = threadIdx.x;
    __shared__ float red[8];
    const float* xb = x + (size_t)b * 1024;
    float w0 = cw[d*5+0], w1 = cw[d*5+1], w2 = cw[d*5+2], w3 = cw[d*5+3], w4 = cw[d*5+4];
    float bv = cb[d];
    int p0 = 2 * l;
    auto xc = [&](int i) { return xb[min(max(i, 0), 1023)]; };
    float h0 = bv + w0*xc(p0-2) + w1*xc(p0-1) + w2*xc(p0)   + w3*xc(p0+1) + w4*xc(p0+2);
    float h1 = bv + w0*xc(p0-1) + w1*xc(p0)   + w2*xc(p0+1) + w3*xc(p0+2) + w4*xc(p0+3);
    float pool = sqrtf(h0*h0 + h1*h1);
    float val = pool + pe[l*DN + d];
    float s = block_reduce_sum(val, red);
    float mu = s * (1.0f/DN);
    float dv = val - mu;
    float s2 = block_reduce_sum(dv*dv, red);
    float r = rsqrtf(s2 * (1.0f/DN) + 1e-5f);
    z[((size_t)b*LATN + l)*DN + d] = dv*r*g[d] + bb[d];
}

// ---------------- pack projection weights: fp32 [out,in] -> bf16 B-frag ----------
__global__ void pack_proj(const float* __restrict__ wq, const float* __restrict__ wk,
                          const float* __restrict__ wv, const float* __restrict__ wo,
                          unsigned short* __restrict__ wp) {
    int mat = blockIdx.y;              // 0..7 : layer*4 + {q,k,v,o}
    int l0 = mat >> 2, which = mat & 3;
    const float* base = (which == 0) ? wq : (which == 1) ? wk : (which == 2) ? wv : wo;
    const float* W = base + l0*65536;
    int tid = blockIdx.x*256 + threadIdx.x;   // 0..8191
    int l = tid & 63, kk = (tid >> 6) & 7, nt = tid >> 9;
    const float* src = W + (size_t)(nt*16 + (l&15))*DN + kk*32 + (l>>4)*8;
    unsigned short o[8];
    #pragma unroll
    for (int j = 0; j < 8; ++j) o[j] = f2bf(src[j]);
    *(ulonglong2*)(wp + (size_t)mat*65536 + (size_t)tid*8) = *(ulonglong2*)o;
}

// ---------------- MFMA projection GEMM body. OM: 0=f32 out, 1=bf16 out, 2=bf16 vT
template<int OM>
__device__ __forceinline__ void proj_body(const float* __restrict__ A,
                                          const unsigned short* __restrict__ wpm,
                                          const float* __restrict__ bias,
                                          void* __restrict__ outp, int t0, float oscale,
                                          unsigned short* ts) {
    int tid = threadIdx.x;
    #pragma unroll
    for (int i = 0; i < 16; ++i) {
        int f4 = i*256 + tid;
        int row = f4 >> 6, c4 = f4 & 63;
        float4 a = *(const float4*)&A[(size_t)(t0+row)*DN + c4*4];
        ushort4 o = { f2bf(a.x), f2bf(a.y), f2bf(a.z), f2bf(a.w) };
        *(ushort4*)&ts[row*264 + c4*4] = o;
    }
    __syncthreads();
    int w = tid >> 6, l = tid & 63;
    f32x4 acc[4][4];
    #pragma unroll
    for (int m = 0; m < 4; ++m)
        #pragma unroll
        for (int n = 0; n < 4; ++n) acc[m][n] = (f32x4){0.f,0.f,0.f,0.f};
    const bf16x8* wv = (const bf16x8*)wpm;
    #pragma unroll
    for (int kk = 0; kk < 8; ++kk) {
        bf16x8 af[4];
        #pragma unroll
        for (int m = 0; m < 4; ++m)
            af[m] = *(const bf16x8*)&ts[(m*16 + (l&15))*264 + kk*32 + (l>>4)*8];
        #pragma unroll
        for (int n = 0; n < 4; ++n) {
            bf16x8 bf = wv[((w*4 + n)*8 + kk)*64 + l];
            #pragma unroll
            for (int m = 0; m < 4; ++m)
                acc[m][n] = __builtin_amdgcn_mfma_f32_16x16x32_bf16(af[m], bf, acc[m][n], 0, 0, 0);
        }
    }
    #pragma unroll
    for (int n = 0; n < 4; ++n) {
        int col = w*64 + n*16 + (l&15);
        float bv2 = bias[col];
        #pragma unroll
        for (int m = 0; m < 4; ++m) {
            #pragma unroll
            for (int r = 0; r < 4; ++r) {
                int row = t0 + m*16 + (l>>4)*4 + r;
                float val = acc[m][n][r] + bv2;
                if (OM == 0)
                    ((float*)outp)[(size_t)row*DN + col] = val;
                else if (OM == 1)
                    ((unsigned short*)outp)[(size_t)row*DN + col] = f2bf(val * oscale);
                else
                    ((unsigned short*)outp)[(((size_t)(row>>9)*2 + (col>>7))*128 + (col&127))*512 + (row&511)] = f2bf(val);
            }
        }
    }
}

__global__ __launch_bounds__(256)
void proj_qkv(const float* __restrict__ z, const unsigned short* __restrict__ wp,
              const float* __restrict__ bq, const float* __restrict__ bk,
              const float* __restrict__ bv,
              unsigned short* __restrict__ qb, unsigned short* __restrict__ kb,
              unsigned short* __restrict__ vtb) {
    __shared__ unsigned short ts[64*264];
    int mat = blockIdx.y;
    if (mat == 0)      proj_body<1>(z, wp,          bq, qb,  blockIdx.x*64, 0.08838834764831844f, ts);
    else if (mat == 1) proj_body<1>(z, wp + 65536,  bk, kb,  blockIdx.x*64, 1.0f, ts);
    else               proj_body<2>(z, wp + 131072, bv, vtb, blockIdx.x*64, 1.0f, ts);
}

__global__ __launch_bounds__(256)
void proj_one(const float* __restrict__ A, const unsigned short* __restrict__ wpm,
              const float* __restrict__ bias, float* __restrict__ out) {
    __shared__ unsigned short ts[64*264];
    proj_body<0>(A, wpm, bias, out, blockIdx.x*64, 1.0f, ts);
}

// ---------------- MFMA attention: swapped QK^T (S^T), in-reg softmax, PV via LDS-P
// block: 32 q-rows of one (b,h); 4 waves each own 128 keys (QK^T) / 32 d (PV)
__global__ __launch_bounds__(256)
void attn_mfma(const unsigned short* __restrict__ qb, const unsigned short* __restrict__ kb,
               const unsigned short* __restrict__ vtb, float* __restrict__ a) {
    int blk = blockIdx.x;
    int xcd = blk & 7, idx = blk >> 3;
    int bh = xcd*2 + (idx & 1);        // 2 bh per XCD -> 1 MB L2 working set
    int qt = idx >> 1;
    int b = bh >> 1, h = bh & 1;
    int q0 = qt * 32;
    int tid = threadIdx.x;
    int w = tid >> 6, l = tid & 63;
    int c = l & 15, g = l >> 4;

    __shared__ __align__(16) unsigned short p_lds[32*512];  // [q][key] bf16, XOR-swizzled
    __shared__ float smax[4][2][16];
    __shared__ float ssum[4][2][16];

    // Q fragments (B-operand of S^T): qf_[qf][kk]  (Q pre-scaled by 1/sqrt(128))
    bf16x8 qf_[2][4];
    #pragma unroll
    for (int qf = 0; qf < 2; ++qf)
        #pragma unroll
        for (int kk = 0; kk < 4; ++kk)
            qf_[qf][kk] = *(const bf16x8*)&qb[((size_t)(b*LATN + q0 + qf*16 + c))*DN + h*DKN + kk*32 + g*8];

    // ---- QK^T: st[f][qf] holds S^T[key = w*128+f*16+g*4+r][q = qf*16+c]
    f32x4 st[8][2];
    #pragma unroll
    for (int f = 0; f < 8; ++f) { st[f][0] = (f32x4){0,0,0,0}; st[f][1] = (f32x4){0,0,0,0}; }
    #pragma unroll
    for (int f = 0; f < 8; ++f) {
        int kbase = w*128 + f*16;
        bf16x8 kf[4];
        #pragma unroll
        for (int kk = 0; kk < 4; ++kk)
            kf[kk] = *(const bf16x8*)&kb[((size_t)(b*LATN + kbase + c))*DN + h*DKN + kk*32 + g*8];
        #pragma unroll
        for (int kk = 0; kk < 4; ++kk) {
            st[f][0] = __builtin_amdgcn_mfma_f32_16x16x32_bf16(kf[kk], qf_[0][kk], st[f][0], 0, 0, 0);
            st[f][1] = __builtin_amdgcn_mfma_f32_16x16x32_bf16(kf[kk], qf_[1][kk], st[f][1], 0, 0, 0);
        }
    }

    // ---- softmax over keys (per q): in-reg + shfl + cross-wave LDS
    float gmax[2], ginv[2];
    #pragma unroll
    for (int qf = 0; qf < 2; ++qf) {
        float m = -1e30f;
        #pragma unroll
        for (int f = 0; f < 8; ++f)
            #pragma unroll
            for (int r = 0; r < 4; ++r) m = fmaxf(m, st[f][qf][r]);
        m = fmaxf(m, __shfl_xor(m, 16, 64));
        m = fmaxf(m, __shfl_xor(m, 32, 64));
        if (l < 16) smax[w][qf][l] = m;
    }
    __syncthreads();
    #pragma unroll
    for (int qf = 0; qf < 2; ++qf)
        gmax[qf] = fmaxf(fmaxf(smax[0][qf][c], smax[1][qf][c]),
                         fmaxf(smax[2][qf][c], smax[3][qf][c]));
    #pragma unroll
    for (int qf = 0; qf < 2; ++qf) {
        float s = 0.f;
        #pragma unroll
        for (int f = 0; f < 8; ++f)
            #pragma unroll
            for (int r = 0; r < 4; ++r) {
                float e = __expf(st[f][qf][r] - gmax[qf]);
                st[f][qf][r] = e; s += e;
            }
        s += __shfl_xor(s, 16, 64);
        s += __shfl_xor(s, 32, 64);
        if (l < 16) ssum[w][qf][l] = s;
    }
    __syncthreads();
    #pragma unroll
    for (int qf = 0; qf < 2; ++qf)
        ginv[qf] = 1.0f / (ssum[0][qf][c] + ssum[1][qf][c] + ssum[2][qf][c] + ssum[3][qf][c]);

    // ---- P -> bf16 -> p_lds[q][key], byte ^= ((q&7)<<4) swizzle (bank-uniform)
    #pragma unroll
    for (int qf = 0; qf < 2; ++qf) {
        int q_ = qf*16 + c;
        int rowb = q_ * 1024;
        int swz = (q_ & 7) << 4;
        float iv = ginv[qf];
        #pragma unroll
        for (int f = 0; f < 8; ++f) {
            unsigned int lo = (unsigned int)f2bf(st[f][qf][0]*iv) |
                              ((unsigned int)f2bf(st[f][qf][1]*iv) << 16);
            unsigned int hi = (unsigned int)f2bf(st[f][qf][2]*iv) |
                              ((unsigned int)f2bf(st[f][qf][3]*iv) << 16);
            int key0 = w*128 + f*16 + g*4;
            *(unsigned long long*)((char*)p_lds + rowb + ((key0*2) ^ swz)) =
                (unsigned long long)lo | ((unsigned long long)hi << 32);
        }
    }
    __syncthreads();

    // ---- PV: O^T[d][q] = mfma(V^T-frag, P-frag); wave owns d = w*32..w*32+31
    f32x4 o[2][2];
    o[0][0] = (f32x4){0,0,0,0}; o[0][1] = (f32x4){0,0,0,0};
    o[1][0] = (f32x4){0,0,0,0}; o[1][1] = (f32x4){0,0,0,0};
    #pragma unroll
    for (int kk = 0; kk < 16; ++kk) {
        bf16x8 pb[2];
        #pragma unroll
        for (int qf = 0; qf < 2; ++qf) {
            int q_ = qf*16 + c;
            pb[qf] = *(const bf16x8*)((const char*)p_lds + q_*1024 +
                                      (((kk*32 + g*8)*2) ^ ((q_&7)<<4)));
        }
        bf16x8 va[2];
        #pragma unroll
        for (int m = 0; m < 2; ++m)
            va[m] = *(const bf16x8*)&vtb[((size_t)(bh*128 + w*32 + m*16 + c))*512 + kk*32 + g*8];
        #pragma unroll
        for (int m = 0; m < 2; ++m) {
            o[m][0] = __builtin_amdgcn_mfma_f32_16x16x32_bf16(va[m], pb[0], o[m][0], 0, 0, 0);
            o[m][1] = __builtin_amdgcn_mfma_f32_16x16x32_bf16(va[m], pb[1], o[m][1], 0, 0, 0);
        }
    }
    #pragma unroll
    for (int m = 0; m < 2; ++m)
        #pragma unroll
        for (int qf = 0; qf < 2; ++qf)
            #pragma unroll
            for (int r = 0; r < 4; ++r) {
                int d = w*32 + m*16 + g*4 + r;
                a[((size_t)(b*LATN + q0 + qf*16 + c))*DN + h*DKN + d] = o[m][qf][r];
            }
}

// ---------------- residual + LN (in-place on z) ----------------
__global__ void ln_residual(float* __restrict__ z, const float* __restrict__ y,
                            const float* __restrict__ g, const float* __restrict__ b) {
    int t = blockIdx.x, tid = threadIdx.x;
    __shared__ float red[8];
    float val = z[(size_t)t*DN + tid] + y[(size_t)t*DN + tid];
    float s = block_reduce_sum(val, red);
    float mu = s * (1.0f/DN);
    float dv = val - mu;
    float s2 = block_reduce_sum(dv*dv, red);
    float r = rsqrtf(s2 * (1.0f/DN) + 1e-5f);
    z[(size_t)t*DN + tid] = dv*r*g[tid] + b[tid];
}

// ---------------- router: 64 tokens/block, 4 lanes/token ----------------
__global__ void router_kernel(const float* __restrict__ z, const float* __restrict__ rw,
                              const float* __restrict__ rb, float* __restrict__ rmaxv,
                              float* __restrict__ counts, float* __restrict__ rprob,
                              int* __restrict__ ec, int* __restrict__ elist) {
    __shared__ float rws[NEXP*DN];
    __shared__ float scnt[NEXP], sprob[NEXP];
    int tid = threadIdx.x;
    for (int i = tid; i < NEXP*DN; i += 256) rws[i] = rw[i];
    if (tid < NEXP) { scnt[tid] = 0.f; sprob[tid] = 0.f; }
    __syncthreads();
    int g = tid >> 2, j = tid & 3;
    int t = blockIdx.x * 64 + g;
    const float4* z4 = (const float4*)&z[(size_t)t*DN + j*64];
    float acc[NEXP];
    #pragma unroll
    for (int e = 0; e < NEXP; ++e) acc[e] = 0.f;
    #pragma unroll 4
    for (int k4 = 0; k4 < 16; ++k4) {
        float4 zv = z4[k4];
        #pragma unroll
        for (int e = 0; e < NEXP; ++e)
            acc[e] += dot4(zv, *(const float4*)&rws[e*DN + j*64 + k4*4]);
    }
    #pragma unroll
    for (int e = 0; e < NEXP; ++e) {
        acc[e] += __shfl_xor(acc[e], 1, 64);
        acc[e] += __shfl_xor(acc[e], 2, 64);
    }
    if (j == 0) {
        float lg[NEXP];
        float m = acc[0] + rb[0]; int am = 0;
        lg[0] = m;
        #pragma unroll
        for (int e = 1; e < NEXP; ++e) {
            lg[e] = acc[e] + rb[e];
            if (lg[e] > m) { m = lg[e]; am = e; }
        }
        float p[NEXP], s = 0.f;
        #pragma unroll
        for (int e = 0; e < NEXP; ++e) { p[e] = expf(lg[e] - m); s += p[e]; }
        float inv = 1.0f / s;
        rmaxv[t] = p[am] * inv;
        atomicAdd(&scnt[am], 1.0f);
        #pragma unroll
        for (int e = 0; e < NEXP; ++e) atomicAdd(&sprob[e], p[e] * inv);
        int pos = atomicAdd(&ec[am], 1);
        elist[am*TTOT + pos] = t;
    }
    __syncthreads();
    if (tid < NEXP) {
        atomicAdd(&counts[tid], scnt[tid]);
        atomicAdd(&rprob[tid], sprob[tid]);
    }
}

// ---------------- weight pack kernels: fp32 -> bf16 MFMA-B-fragment order --------
__global__ void pack_w1(const float* __restrict__ w1l, unsigned short* __restrict__ w1p) {
    int tid = blockIdx.x*256 + threadIdx.x;   // 327680 total
    int l = tid & 63, kk = (tid >> 6) & 7, nt = (tid >> 9) & 63, e = tid >> 15;
    const float* src = w1l + (size_t)e*262144 + (size_t)(kk*32 + (l>>4)*8)*DFFN + nt*16 + (l&15);
    unsigned short o[8];
    #pragma unroll
    for (int j = 0; j < 8; ++j) o[j] = f2bf(src[(size_t)j*DFFN]);
    ulonglong2* dst = (ulonglong2*)(w1p + (size_t)tid*8);
    *dst = *(ulonglong2*)o;
}

__global__ void pack_w2(const float* __restrict__ w2l, unsigned short* __restrict__ w2p) {
    int tid = blockIdx.x*256 + threadIdx.x;   // 327680 total
    int l = tid & 63, kk = (tid >> 6) & 31, nt = (tid >> 11) & 15, e = tid >> 15;
    const float* src = w2l + (size_t)e*262144 + (size_t)(kk*32 + (l>>4)*8)*DN + nt*16 + (l&15);
    unsigned short o[8];
    #pragma unroll
    for (int j = 0; j < 8; ++j) o[j] = f2bf(src[(size_t)j*DN]);
    ulonglong2* dst = (ulonglong2*)(w2p + (size_t)tid*8);
    *dst = *(ulonglong2*)o;
}

// ---------------- MoE: bf16 MFMA grouped expert FFN + residual LN -------------
#define TM 16
__global__ __launch_bounds__(256)
void moe_kernel(float* __restrict__ z, const int* __restrict__ elist,
                const int* __restrict__ ec, const float* __restrict__ rmaxv,
                const unsigned short* __restrict__ w1p, const float* __restrict__ b1,
                const unsigned short* __restrict__ w2p, const float* __restrict__ b2,
                const float* __restrict__ g, const float* __restrict__ bb) {
    int e = blockIdx.y;
    int cnt = ec[e];
    int base = blockIdx.x * TM;
    if (base >= cnt) return;
    int n = min(TM, cnt - base);

    __shared__ __align__(16) unsigned short ts[16*264];
    __shared__ __align__(16) unsigned short hbuf[16*1032];
    __shared__ __align__(16) float ybuf[16*260];
    __shared__ int toks[16];
    __shared__ float rm[16];

    int tid = threadIdx.x;
    int w = tid >> 6, l = tid & 63;
    if (tid < 16) {
        int tt = (tid < n) ? elist[e*TTOT + base + tid] : 0;
        toks[tid] = tt;
        rm[tid] = rmaxv[tt];
    }
    __syncthreads();
    #pragma unroll
    for (int m = 0; m < 16; ++m)
        ts[m*264 + tid] = f2bf(z[(size_t)toks[m]*DN + tid]);
    __syncthreads();

    const bf16x8* w1v = (const bf16x8*)w1p;
    const float* b1e = b1 + e*DFFN;
    f32x4 acc[16];
    #pragma unroll
    for (int i = 0; i < 16; ++i) acc[i] = (f32x4){0.f,0.f,0.f,0.f};
    #pragma unroll
    for (int kk = 0; kk < 8; ++kk) {
        bf16x8 a = *(const bf16x8*)(ts + (l&15)*264 + kk*32 + (l>>4)*8);
        const bf16x8* wbp = w1v + (((size_t)e*64 + w*16)*8 + kk)*64 + l;
        #pragma unroll
        for (int nt2 = 0; nt2 < 16; ++nt2)
            acc[nt2] = __builtin_amdgcn_mfma_f32_16x16x32_bf16(a, wbp[nt2*512], acc[nt2], 0, 0, 0);
    }
    #pragma unroll
    for (int nt2 = 0; nt2 < 16; ++nt2) {
        int col = w*256 + nt2*16 + (l&15);
        float bv = b1e[col];
        #pragma unroll
        for (int r = 0; r < 4; ++r) {
            int row = (l>>4)*4 + r;
            hbuf[row*1032 + col] = f2bf(fmaxf(acc[nt2][r] + bv, 0.f));
        }
    }
    __syncthreads();

    const bf16x8* w2v = (const bf16x8*)w2p;
    const float* b2e = b2 + e*DN;
    f32x4 acc2[4];
    #pragma unroll
    for (int i = 0; i < 4; ++i) acc2[i] = (f32x4){0.f,0.f,0.f,0.f};
    for (int kk = 0; kk < 32; ++kk) {
        bf16x8 a = *(const bf16x8*)(hbuf + (l&15)*1032 + kk*32 + (l>>4)*8);
        const bf16x8* wbp = w2v + (((size_t)e*16 + w*4)*32 + kk)*64 + l;
        #pragma unroll
        for (int nt2 = 0; nt2 < 4; ++nt2)
            acc2[nt2] = __builtin_amdgcn_mfma_f32_16x16x32_bf16(a, wbp[nt2*2048], acc2[nt2], 0, 0, 0);
    }
    #pragma unroll
    for (int nt2 = 0; nt2 < 4; ++nt2) {
        int col = w*64 + nt2*16 + (l&15);
        float bv = b2e[col];
        #pragma unroll
        for (int r = 0; r < 4; ++r) {
            int row = (l>>4)*4 + r;
            ybuf[row*260 + col] = (acc2[nt2][r] + bv) * rm[row];
        }
    }
    __syncthreads();

    #pragma unroll
    for (int rr = 0; rr < 4; ++rr) {
        int row = w*4 + rr;
        if (row < n) {
            int t = toks[row];
            float v[4];
            #pragma unroll
            for (int c = 0; c < 4; ++c)
                v[c] = ybuf[row*260 + l + 64*c] + z[(size_t)t*DN + l + 64*c];
            float s = wave_sum(v[0]+v[1]+v[2]+v[3]);
            float mu = s * (1.0f/DN);
            float s2 = 0.f;
            #pragma unroll
            for (int c = 0; c < 4; ++c) { v[c] -= mu; s2 += v[c]*v[c]; }
            s2 = wave_sum(s2);
            float rs = rsqrtf(s2 * (1.0f/DN) + 1e-5f);
            #pragma unroll
            for (int c = 0; c < 4; ++c) {
                int col = l + 64*c;
                z[(size_t)t*DN + col] = v[c]*rs*g[col] + bb[col];
            }
        }
    }
}

// ---------------- pack deconv taps -> bf16 B-frag ----------------
__global__ void pack_deconv_mfma(const float* __restrict__ w, unsigned short* __restrict__ wdp) {
    int tid = blockIdx.x*256 + threadIdx.x;   // 32768
    int l = tid & 63, kk = (tid >> 6) & 7, nt = (tid >> 9) & 15, tap = tid >> 13;
    int dout = nt*16 + (l&15);
    int din0 = kk*32 + (l>>4)*8;
    unsigned short o[8];
    #pragma unroll
    for (int j = 0; j < 8; ++j)
        o[j] = f2bf(w[((size_t)(din0 + j)*DN + dout)*4 + tap]);
    *(ulonglong2*)(wdp + (size_t)tid*8) = *(ulonglong2*)o;
}

__global__ void pack_lin1(const float* __restrict__ w, unsigned short* __restrict__ wl1) {
    int tid = blockIdx.x*256 + threadIdx.x;   // 4096
    int l = tid & 63, kk = (tid >> 6) & 7, nt = tid >> 9;
    const float* src = w + (size_t)(nt*16 + (l&15))*DN + kk*32 + (l>>4)*8;
    unsigned short o[8];
    #pragma unroll
    for (int j = 0; j < 8; ++j) o[j] = f2bf(src[j]);
    *(ulonglong2*)(wl1 + (size_t)tid*8) = *(ulonglong2*)o;
}

// ---------------- deconv as MFMA GEMM ----------------
__global__ __launch_bounds__(256)
void deconv_mfma(const float* __restrict__ z, const unsigned short* __restrict__ wdp,
                 const float* __restrict__ db, float* __restrict__ u) {
    int blk = blockIdx.x;
    int b = blk >> 4, lt = blk & 15;
    int l0 = lt * 32;
    __shared__ __align__(16) unsigned short zs[34*264];
    int tid = threadIdx.x;
    #pragma unroll
    for (int i = 0; i < 9; ++i) {
        int f4 = i*256 + tid;
        if (f4 < 34*64) {
            int row = f4 >> 6, c4 = f4 & 63;
            int l = l0 - 1 + row;
            float4 a = (l >= 0 && l < LATN)
                ? *(const float4*)&z[((size_t)b*LATN + l)*DN + c4*4]
                : make_float4(0.f, 0.f, 0.f, 0.f);
            ushort4 o = { f2bf(a.x), f2bf(a.y), f2bf(a.z), f2bf(a.w) };
            *(ushort4*)&zs[row*264 + c4*4] = o;
        }
    }
    __syncthreads();
    int w = tid >> 6, l = tid & 63;
    f32x4 acce[2][4], acco[2][4];
    #pragma unroll
    for (int m = 0; m < 2; ++m)
        #pragma unroll
        for (int n = 0; n < 4; ++n) {
            acce[m][n] = (f32x4){0.f,0.f,0.f,0.f};
            acco[m][n] = (f32x4){0.f,0.f,0.f,0.f};
        }
    const bf16x8* wdv = (const bf16x8*)wdp;
    #pragma unroll
    for (int kk = 0; kk < 8; ++kk) {
        bf16x8 a0[2], a1[2], a2[2];
        #pragma unroll
        for (int m = 0; m < 2; ++m) {
            int rb = (m*16 + (l&15))*264 + kk*32 + (l>>4)*8;
            a0[m] = *(const bf16x8*)&zs[rb];
            a1[m] = *(const bf16x8*)&zs[rb + 264];
            a2[m] = *(const bf16x8*)&zs[rb + 528];
        }
        #pragma unroll
        for (int n = 0; n < 4; ++n) {
            int nt = w*4 + n;
            bf16x8 bt0 = wdv[((0*16 + nt)*8 + kk)*64 + l];
            bf16x8 bt1 = wdv[((1*16 + nt)*8 + kk)*64 + l];
            bf16x8 bt2 = wdv[((2*16 + nt)*8 + kk)*64 + l];
            bf16x8 bt3 = wdv[((3*16 + nt)*8 + kk)*64 + l];
            #pragma unroll
            for (int m = 0; m < 2; ++m) {
                acco[m][n] = __builtin_amdgcn_mfma_f32_16x16x32_bf16(a2[m], bt0, acco[m][n], 0, 0, 0);
                acce[m][n] = __builtin_amdgcn_mfma_f32_16x16x32_bf16(a1[m], bt1, acce[m][n], 0, 0, 0);
                acco[m][n] = __builtin_amdgcn_mfma_f32_16x16x32_bf16(a1[m], bt2, acco[m][n], 0, 0, 0);
                acce[m][n] = __builtin_amdgcn_mfma_f32_16x16x32_bf16(a0[m], bt3, acce[m][n], 0, 0, 0);
            }
        }
    }
    #pragma unroll
    for (int n = 0; n < 4; ++n) {
        int col = (w*4 + n)*16 + (l&15);
        float bv = db[col];
        #pragma unroll
        for (int m = 0; m < 2; ++m) {
            #pragma unroll
            for (int r = 0; r < 4; ++r) {
                int rt = m*16 + (l>>4)*4 + r;
                int wpos = 2*(l0 + rt);
                u[((size_t)b*1024 + wpos)*DN + col]     = acce[m][n][r] + bv;
                u[((size_t)b*1024 + wpos + 1)*DN + col] = acco[m][n][r] + bv;
            }
        }
    }
}

// ---------------- head: MFMA lin1 + tanh + lin2 fused ----------------
__global__ __launch_bounds__(256)
void head_mfma(const float* __restrict__ u, const unsigned short* __restrict__ wl1,
               const float* __restrict__ b1, const float* __restrict__ w2,
               const float* __restrict__ b2, float* __restrict__ out) {
    int r0 = blockIdx.x * 64;
    __shared__ __align__(16) unsigned short us[64*264];
    __shared__ float part[4][64];
    int tid = threadIdx.x;
    #pragma unroll
    for (int i = 0; i < 16; ++i) {
        int f4 = i*256 + tid;
        int row = f4 >> 6, c4 = f4 & 63;
        float4 a = *(const float4*)&u[(size_t)(r0 + row)*DN + c4*4];
        ushort4 o = { f2bf(a.x), f2bf(a.y), f2bf(a.z), f2bf(a.w) };
        *(ushort4*)&us[row*264 + c4*4] = o;
    }
    __syncthreads();
    int w = tid >> 6, l = tid & 63;
    f32x4 acc[4][2];
    #pragma unroll
    for (int m = 0; m < 4; ++m) { acc[m][0] = (f32x4){0.f,0.f,0.f,0.f}; acc[m][1] = (f32x4){0.f,0.f,0.f,0.f}; }
    const bf16x8* wv1 = (const bf16x8*)wl1;
    #pragma unroll
    for (int kk = 0; kk < 8; ++kk) {
        bf16x8 af[4];
        #pragma unroll
        for (int m = 0; m < 4; ++m)
            af[m] = *(const bf16x8*)&us[(m*16 + (l&15))*264 + kk*32 + (l>>4)*8];
        #pragma unroll
        for (int n = 0; n < 2; ++n) {
            bf16x8 bf = wv1[((w*2 + n)*8 + kk)*64 + l];
            #pragma unroll
            for (int m = 0; m < 4; ++m)
                acc[m][n] = __builtin_amdgcn_mfma_f32_16x16x32_bf16(af[m], bf, acc[m][n], 0, 0, 0);
        }
    }
    float pm[4][4];
    #pragma unroll
    for (int m = 0; m < 4; ++m)
        #pragma unroll
        for (int r = 0; r < 4; ++r) pm[m][r] = 0.f;
    #pragma unroll
    for (int n = 0; n < 2; ++n) {
        int col = (w*2 + n)*16 + (l&15);
        float bb1 = b1[col], ww2 = w2[col];
        #pragma unroll
        for (int m = 0; m < 4; ++m)
            #pragma unroll
            for (int r = 0; r < 4; ++r)
                pm[m][r] += tanhf(acc[m][n][r] + bb1) * ww2;
    }
    #pragma unroll
    for (int off = 1; off <= 8; off <<= 1)
        #pragma unroll
        for (int m = 0; m < 4; ++m)
            #pragma unroll
            for (int r = 0; r < 4; ++r)
                pm[m][r] += __shfl_xor(pm[m][r], off, 64);
    if ((l & 15) == 0) {
        #pragma unroll
        for (int m = 0; m < 4; ++m)
            #pragma unroll
            for (int r = 0; r < 4; ++r)
                part[w][m*16 + (l>>4)*4 + r] = pm[m][r];
    }
    __syncthreads();
    if (tid < 64)
        out[r0 + tid] = part[0][tid] + part[1][tid] + part[2][tid] + part[3][tid] + b2[0];
}

// ---------------- loss ----------------
__global__ void loss_kernel(const float* __restrict__ counts, const float* __restrict__ rprob,
                            float* __restrict__ out) {
    if (threadIdx.x == 0) {
        float s = 0;
        for (int i = 0; i < 20; ++i) s += counts[i] * rprob[i];
        out[8192] = 10.0f * s / (4096.0f * 4096.0f);
    }
}

extern "C" void kernel_launch(void* const* d_in, const int* in_sizes, int n_in,
                              void* d_out, int out_size, void* d_ws, size_t ws_size,
                              hipStream_t stream) {
    const float* x        = (const float*)d_in[0];
    const float* conv_w   = (const float*)d_in[1];
    const float* conv_b   = (const float*)d_in[2];
    const float* pe       = (const float*)d_in[3];
    const float* ln0_g    = (const float*)d_in[4];
    const float* ln0_b    = (const float*)d_in[5];
    const float* wq       = (const float*)d_in[6];
    const float* bq       = (const float*)d_in[7];
    const float* wk       = (const float*)d_in[8];
    const float* bk       = (const float*)d_in[9];
    const float* wv       = (const float*)d_in[10];
    const float* bv       = (const float*)d_in[11];
    const float* wo       = (const float*)d_in[12];
    const float* bo       = (const float*)d_in[13];
    const float* ln1_g    = (const float*)d_in[14];
    const float* ln1_b    = (const float*)d_in[15];
    const float* ln2_g    = (const float*)d_in[16];
    const float* ln2_b    = (const float*)d_in[17];
    const float* router_w = (const float*)d_in[18];
    const float* router_b = (const float*)d_in[19];
    const float* e_w1     = (const float*)d_in[20];
    const float* e_b1     = (const float*)d_in[21];
    const float* e_w2     = (const float*)d_in[22];
    const float* e_b2     = (const float*)d_in[23];
    const float* deconv_w = (const float*)d_in[24];
    const float* deconv_b = (const float*)d_in[25];
    const float* lin1_w   = (const float*)d_in[26];
    const float* lin1_b   = (const float*)d_in[27];
    const float* lin2_w   = (const float*)d_in[28];
    const float* lin2_b   = (const float*)d_in[29];

    float* ws = (float*)d_ws;
    const size_t M = 1048576;
    float* z    = ws;
    unsigned short* qb  = (unsigned short*)(ws + 1*M);   // bf16 Q (pre-scaled)
    unsigned short* kb  = (unsigned short*)(ws + 2*M);   // bf16 K
    unsigned short* vtb = (unsigned short*)(ws + 3*M);   // bf16 V^T [bh][d][512]
    float* a    = ws + 4*M;
    float* y    = ws + 5*M;
    float* rmax = ws + 6*M;
    float* counts = rmax + 4096;
    float* rprob  = counts + 32;
    int* ec     = (int*)(rprob + 32);
    int* elist  = ec + 32;                    // 2*10*4096
    unsigned short* wproj = (unsigned short*)(ws + 6*M + 98304);  // 8 x 65536 bf16 (1 MB)
    unsigned short* w1p = (unsigned short*)(ws + 1*M);  // per-layer packed over qb+kb (dead)
    unsigned short* w2p = (unsigned short*)(ws + 3*M);  // per-layer packed over vtb+a (dead)
    float* u    = ws + 1*M;                              // after layers
    unsigned short* wdp = (unsigned short*)(ws + 3*M);
    unsigned short* wl1 = (unsigned short*)(ws + 3*M + 131072 + 64);
    float* out  = (float*)d_out;

    zero_kernel<<<1, 64, 0, stream>>>(counts, rprob, ec);
    {
        dim3 pg(32, 8);
        pack_proj<<<pg, 256, 0, stream>>>(wq, wk, wv, wo, wproj);
    }
    tokenizer_kernel<<<TTOT, 256, 0, stream>>>(x, conv_w, conv_b, pe, ln0_g, ln0_b, z);

    for (int l = 0; l < 2; ++l) {
        const unsigned short* wpl = wproj + (size_t)l*4*65536;
        dim3 qkvg(64, 3);
        proj_qkv<<<qkvg, 256, 0, stream>>>(z, wpl, bq + l*256, bk + l*256, bv + l*256,
                                           qb, kb, vtb);
        attn_mfma<<<256, 256, 0, stream>>>(qb, kb, vtb, a);
        proj_one<<<64, 256, 0, stream>>>(a, wpl + 3*65536, bo + l*256, y);
        ln_residual<<<TTOT, 256, 0, stream>>>(z, y, ln1_g + l*256, ln1_b + l*256);
        router_kernel<<<TTOT/64, 256, 0, stream>>>(z, router_w + l*2560, router_b + l*10,
                                                   rmax, counts + l*10, rprob + l*10,
                                                   ec + l*10, elist + l*10*TTOT);
        pack_w1<<<1280, 256, 0, stream>>>(e_w1 + (size_t)l*2621440, w1p);
        pack_w2<<<1280, 256, 0, stream>>>(e_w2 + (size_t)l*2621440, w2p);
        dim3 mg(TTOT/TM, NEXP);
        moe_kernel<<<mg, 256, 0, stream>>>(z, elist + l*10*TTOT, ec + l*10, rmax,
                                           w1p, e_b1 + l*10240,
                                           w2p, e_b2 + l*2560,
                                           ln2_g + l*256, ln2_b + l*256);
    }

    pack_deconv_mfma<<<128, 256, 0, stream>>>(deconv_w, wdp);
    pack_lin1<<<16, 256, 0, stream>>>(lin1_w, wl1);
    deconv_mfma<<<128, 256, 0, stream>>>(z, wdp, deconv_b, u);
    head_mfma<<<128, 256, 0, stream>>>(u, wl1, lin1_b, lin2_w, lin2_b, out);
    loss_kernel<<<1, 64, 0, stream>>>(counts, rprob, out);
}